// Round 12
// baseline (429.006 us; speedup 1.0000x reference)
//
#include <hip/hip_runtime.h>
#include <hip/hip_bf16.h>
#include <math.h>

__device__ __forceinline__ unsigned f2u(float f) {
    unsigned b = __float_as_uint(f);
    return b ^ ((unsigned)((int)b >> 31) | 0x80000000u);
}
__device__ __forceinline__ float u2f(unsigned u) {
    unsigned b = (u & 0x80000000u) ? (u ^ 0x80000000u) : ~u;
    return __uint_as_float(b);
}

// wave-level exact k=16 radix select over 256 values (4 per lane).
__device__ __forceinline__ void radix16(unsigned u0, unsigned u1, unsigned u2, unsigned u3,
                                        unsigned& T, int& kk) {
    unsigned prefix = 0; int k = 16;
    for (int b = 31; b >= 0; --b) {
        unsigned hi = (prefix >> b) | 1u;
        int cnt = __popcll(__ballot((u0 >> b) == hi))
                + __popcll(__ballot((u1 >> b) == hi))
                + __popcll(__ballot((u2 >> b) == hi))
                + __popcll(__ballot((u3 >> b) == hi));
        if (cnt >= k) prefix |= (1u << b); else k -= cnt;
    }
    T = prefix; kk = k;
}

// ---------------- Kernel 0: key transpose ----------------
// keys[((h*256+k)*2+p)*256+d] -> KT[((h*2+p)*256+d)*256+k]
__global__ __launch_bounds__(256) void k0_transpose(const float* __restrict__ keys,
                                                    float* __restrict__ KT) {
    int bid = blockIdx.x;               // 8h * 2p * 4kt * 4dt = 256 blocks
    int dt = bid & 3, ktile = (bid >> 2) & 3, p = (bid >> 4) & 1, h = bid >> 5;
    __shared__ float tile[64][65];
    int t = threadIdx.x;
    int row = t >> 2;      // 0..63
    int c4  = t & 3;       // 0..3
#pragma unroll
    for (int i = 0; i < 4; ++i) {
        int dloc = (c4 + 4 * i) * 4;   // 0..60
        float4 v = *(const float4*)&keys[(size_t)(((h * 256 + ktile * 64 + row) * 2 + p) * 256) + dt * 64 + dloc];
        tile[dloc + 0][row] = v.x;
        tile[dloc + 1][row] = v.y;
        tile[dloc + 2][row] = v.z;
        tile[dloc + 3][row] = v.w;
    }
    __syncthreads();
#pragma unroll
    for (int i = 0; i < 4; ++i) {
        int kloc = (c4 + 4 * i) * 4;
        float4 v;
        v.x = tile[row][kloc]; v.y = tile[row][kloc + 1];
        v.z = tile[row][kloc + 2]; v.w = tile[row][kloc + 3];
        *(float4*)&KT[(size_t)((h * 2 + p) * 256 + dt * 64 + row) * 256 + ktile * 64 + kloc] = v;
    }
}

// ---------------- Kernel 1: q = x @ Wq^T ----------------
__global__ __launch_bounds__(256) void k1_gemm(const float* __restrict__ A,
                                               const float* __restrict__ B,
                                               float* __restrict__ C) {
    __shared__ float As[16][128];
    __shared__ float Bs[16][128];
    int t  = threadIdx.x;
    int tx = t & 15, ty = t >> 4;
    int m0 = blockIdx.y * 128, n0 = blockIdx.x * 128;
    float acc[8][8] = {};
    for (int k0 = 0; k0 < 512; k0 += 16) {
#pragma unroll
        for (int i = 0; i < 2; ++i) {
            int u   = t * 2 + i;
            int row = u >> 2;
            int kc  = (u & 3) << 2;
            float4 av = *(const float4*)&A[(m0 + row) * 512 + k0 + kc];
            float4 bv = *(const float4*)&B[(n0 + row) * 512 + k0 + kc];
            As[kc + 0][row] = av.x; As[kc + 1][row] = av.y; As[kc + 2][row] = av.z; As[kc + 3][row] = av.w;
            Bs[kc + 0][row] = bv.x; Bs[kc + 1][row] = bv.y; Bs[kc + 2][row] = bv.z; Bs[kc + 3][row] = bv.w;
        }
        __syncthreads();
#pragma unroll
        for (int kk = 0; kk < 16; ++kk) {
            float4 a0 = *(const float4*)&As[kk][ty * 8];
            float4 a1 = *(const float4*)&As[kk][ty * 8 + 4];
            float4 b0 = *(const float4*)&Bs[kk][tx * 8];
            float4 b1 = *(const float4*)&Bs[kk][tx * 8 + 4];
            float a[8] = {a0.x, a0.y, a0.z, a0.w, a1.x, a1.y, a1.z, a1.w};
            float b[8] = {b0.x, b0.y, b0.z, b0.w, b1.x, b1.y, b1.z, b1.w};
#pragma unroll
            for (int i = 0; i < 8; ++i)
#pragma unroll
                for (int j = 0; j < 8; ++j) acc[i][j] += a[i] * b[j];
        }
        __syncthreads();
    }
#pragma unroll
    for (int i = 0; i < 8; ++i) {
        int m = m0 + ty * 8 + i;
        float4 o0; o0.x = acc[i][0]; o0.y = acc[i][1]; o0.z = acc[i][2]; o0.w = acc[i][3];
        float4 o1; o1.x = acc[i][4]; o1.y = acc[i][5]; o1.z = acc[i][6]; o1.w = acc[i][7];
        *(float4*)&C[m * 4096 + n0 + tx * 8]     = o0;
        *(float4*)&C[m * 4096 + n0 + tx * 8 + 4] = o1;
    }
}

// ---------------- Kernel 2: sim + radix top16 + combine + radix top16 + softmax ----------------
// (structure unchanged: barrier-free coalesced KT reads)
__global__ __launch_bounds__(256) void k2_scores(const float* __restrict__ q,
                                                 const float* __restrict__ KT,
                                                 int* __restrict__ widx,
                                                 float* __restrict__ wcoef) {
    int bid = blockIdx.x;
    int cc = bid & 1;
    int h  = (bid >> 1) & 7;
    int n0 = (bid >> 4) * 16;

    __shared__ float sx_s[2][16][16];
    __shared__ int   ix_s[2][16][16];

    int t = threadIdx.x;
    int wv = t >> 6, ln = t & 63;
    int wvu = __builtin_amdgcn_readfirstlane(wv);
    int pu  = wvu >> 1;
    int nhu = wvu & 1;
    unsigned long long lt = (1ull << ln) - 1ull;

    const float* qw = q + ((size_t)(pu * 1024 + n0 + nhu * 8) * 4096 + cc * 2048 + h * 256);
    const float* kp = KT + (size_t)((h * 2 + pu) * 256) * 256 + 4 * ln;

    float acc[8][4];
#pragma unroll
    for (int n = 0; n < 8; ++n)
#pragma unroll
        for (int j = 0; j < 4; ++j) acc[n][j] = 0.f;

    for (int d0 = 0; d0 < 256; d0 += 8) {
        float4 kt[8];
#pragma unroll
        for (int dd = 0; dd < 8; ++dd)
            kt[dd] = *(const float4*)&kp[(size_t)(d0 + dd) * 256];
#pragma unroll
        for (int n = 0; n < 8; ++n) {
            float4 qa = *(const float4*)&qw[(size_t)n * 4096 + d0];
            float4 qb = *(const float4*)&qw[(size_t)n * 4096 + d0 + 4];
            acc[n][0] += qa.x * kt[0].x + qa.y * kt[1].x + qa.z * kt[2].x + qa.w * kt[3].x
                       + qb.x * kt[4].x + qb.y * kt[5].x + qb.z * kt[6].x + qb.w * kt[7].x;
            acc[n][1] += qa.x * kt[0].y + qa.y * kt[1].y + qa.z * kt[2].y + qa.w * kt[3].y
                       + qb.x * kt[4].y + qb.y * kt[5].y + qb.z * kt[6].y + qb.w * kt[7].y;
            acc[n][2] += qa.x * kt[0].z + qa.y * kt[1].z + qa.z * kt[2].z + qa.w * kt[3].z
                       + qb.x * kt[4].z + qb.y * kt[5].z + qb.z * kt[6].z + qb.w * kt[7].z;
            acc[n][3] += qa.x * kt[0].w + qa.y * kt[1].w + qa.z * kt[2].w + qa.w * kt[3].w
                       + qb.x * kt[4].w + qb.y * kt[5].w + qb.z * kt[6].w + qb.w * kt[7].w;
        }
    }

#pragma unroll
    for (int n = 0; n < 8; ++n) {
        int nn = nhu * 8 + n;
        unsigned u0 = f2u(acc[n][0]), u1 = f2u(acc[n][1]);
        unsigned u2 = f2u(acc[n][2]), u3 = f2u(acc[n][3]);
        unsigned T; int kk;
        radix16(u0, u1, u2, u3, T, kk);
        int base = 0;
#define TK1_GT(J, UJ, VJ) { unsigned long long m = __ballot(UJ > T);            \
        if (UJ > T) { int pos = base + __popcll(m & lt);                        \
            sx_s[pu][nn][pos] = VJ; ix_s[pu][nn][pos] = ln * 4 + J; }           \
        base += __popcll(m); }
        TK1_GT(0, u0, acc[n][0]); TK1_GT(1, u1, acc[n][1]);
        TK1_GT(2, u2, acc[n][2]); TK1_GT(3, u3, acc[n][3]);
#undef TK1_GT
#define TK1_EQ(J, UJ, VJ) { unsigned long long m = __ballot(UJ == T);           \
        int r = __popcll(m & lt);                                               \
        if ((UJ == T) && r < kk) { sx_s[pu][nn][base + r] = VJ;                 \
            ix_s[pu][nn][base + r] = ln * 4 + J; }                              \
        int cn = __popcll(m); int tk = cn < kk ? cn : kk;                       \
        base += tk; kk -= tk; }
        TK1_EQ(0, u0, acc[n][0]); TK1_EQ(1, u1, acc[n][1]);
        TK1_EQ(2, u2, acc[n][2]); TK1_EQ(3, u3, acc[n][3]);
#undef TK1_EQ
    }
    __syncthreads();

    for (int task = wv * 4; task < wv * 4 + 4; ++task) {
        int n = task;
        int t0 = ln, t1 = ln + 64, t2 = ln + 128, t3 = ln + 192;
        float vc0 = sx_s[0][n][t0 >> 4] + sx_s[1][n][t0 & 15];
        float vc1 = sx_s[0][n][t1 >> 4] + sx_s[1][n][t1 & 15];
        float vc2 = sx_s[0][n][t2 >> 4] + sx_s[1][n][t2 & 15];
        float vc3 = sx_s[0][n][t3 >> 4] + sx_s[1][n][t3 & 15];
        unsigned u0 = f2u(vc0), u1 = f2u(vc1), u2 = f2u(vc2), u3 = f2u(vc3);
        unsigned T; int kk;
        radix16(u0, u1, u2, u3, T, kk);
        float Tf = u2f(T);

        bool w0 = u0 > T, w1 = u1 > T, w2 = u2 > T, w3 = u3 > T;
        int q0 = 0, q1 = 0, q2 = 0, q3 = 0;
        int base = 0;
        { unsigned long long m = __ballot(w0); q0 = base + __popcll(m & lt); base += __popcll(m); }
        { unsigned long long m = __ballot(w1); q1 = base + __popcll(m & lt); base += __popcll(m); }
        { unsigned long long m = __ballot(w2); q2 = base + __popcll(m & lt); base += __popcll(m); }
        { unsigned long long m = __ballot(w3); q3 = base + __popcll(m & lt); base += __popcll(m); }
#define CMB_EQ(UJ, WJ, QJ) { unsigned long long m = __ballot(UJ == T);          \
        int r = __popcll(m & lt);                                               \
        if ((UJ == T) && r < kk) { WJ = true; QJ = base + r; }                  \
        int cn = __popcll(m); int tk = cn < kk ? cn : kk;                       \
        base += tk; kk -= tk; }
        CMB_EQ(u0, w0, q0); CMB_EQ(u1, w1, q1); CMB_EQ(u2, w2, q2); CMB_EQ(u3, w3, q3);
#undef CMB_EQ

        float e0 = 0.f, e1 = 0.f, e2 = 0.f, e3 = 0.f;
        int id0 = 0, id1 = 0, id2 = 0, id3 = 0;
        float es = 0.f;
        if (w0) { e0 = __expf(vc0 - Tf); es += e0; id0 = ix_s[0][n][t0 >> 4] * 256 + ix_s[1][n][t0 & 15]; }
        if (w1) { e1 = __expf(vc1 - Tf); es += e1; id1 = ix_s[0][n][t1 >> 4] * 256 + ix_s[1][n][t1 & 15]; }
        if (w2) { e2 = __expf(vc2 - Tf); es += e2; id2 = ix_s[0][n][t2 >> 4] * 256 + ix_s[1][n][t2 & 15]; }
        if (w3) { e3 = __expf(vc3 - Tf); es += e3; id3 = ix_s[0][n][t3 >> 4] * 256 + ix_s[1][n][t3 & 15]; }
        for (int s = 1; s < 64; s <<= 1) es += __shfl_xor(es, s);
        float inv = 1.f / es;

        int off = ((cc * 1024 + n0 + n) * 8 + h) * 16;
        if (w0) { wcoef[off + q0] = e0 * inv; widx[off + q0] = id0; }
        if (w1) { wcoef[off + q1] = e1 * inv; widx[off + q1] = id1; }
        if (w2) { wcoef[off + q2] = e2 * inv; widx[off + q2] = id2; }
        if (w3) { wcoef[off + q3] = e3 * inv; widx[off + q3] = id3; }
    }
}

// ---------------- Kernel 3: gather experts, gelu, weighted mix (range pass) ----------------
// one block per (c,n); 4 waves x 32 selections; only selections with
// idx in [lo,hi) are processed this pass (wave-uniform test via shfl).
// Pass slice = 64 MB of expert table -> L3-resident -> intra-pass reuse free.
// first=1: write out; first=0: accumulate into out.
__global__ __launch_bounds__(256) void k3_experts(const float* __restrict__ x,
                                                  const float* __restrict__ w_down,
                                                  const float* __restrict__ w_up,
                                                  const int* __restrict__ widx,
                                                  const float* __restrict__ wcoef,
                                                  float* __restrict__ out,
                                                  int lo, int hi, int first) {
    int bid = blockIdx.x;
    int c = bid >> 10, n = bid & 1023;
    int t = threadIdx.x, wv = t >> 6, ln = t & 63;
    __shared__ float wacc[4][512];

    const float* xrow = &x[(c * 1024 + n) * 512];
    float xr[8], oacc[8];
    {
        float4 xa = *(const float4*)&xrow[ln * 8];
        float4 xb = *(const float4*)&xrow[ln * 8 + 4];
        xr[0] = xa.x; xr[1] = xa.y; xr[2] = xa.z; xr[3] = xa.w;
        xr[4] = xb.x; xr[5] = xb.y; xr[6] = xb.z; xr[7] = xb.w;
    }
#pragma unroll
    for (int j = 0; j < 8; ++j) oacc[j] = 0.f;

    const int base = (c * 1024 + n) * 128 + wv * 32;
    // hoist this wave's 32 (idx, wgt) pairs into lanes 0-31
    int   myidx = 0;
    float mywgt = 0.f;
    if (ln < 32) { myidx = widx[base + ln]; mywgt = wcoef[base + ln]; }

    for (int e = 0; e < 32; ++e) {
        int idx = __shfl(myidx, e);          // wave-uniform
        if (idx < lo || idx >= hi) continue; // uniform branch
        float wgt = __shfl(mywgt, e);
        const float* dr = &w_down[(long)idx * 512 + ln * 8];
        float4 da = *(const float4*)&dr[0];
        float4 db = *(const float4*)&dr[4];
        float part = da.x * xr[0] + da.y * xr[1] + da.z * xr[2] + da.w * xr[3]
                   + db.x * xr[4] + db.y * xr[5] + db.z * xr[6] + db.w * xr[7];
        for (int s = 1; s < 64; s <<= 1) part += __shfl_xor(part, s);
        float hv = part;
        float coef = 0.5f * hv * (1.f + erff(hv * 0.70710678118654752f)) * wgt;
        const float* ur = &w_up[(long)idx * 512 + ln * 8];
        float4 ua = *(const float4*)&ur[0];
        float4 ub = *(const float4*)&ur[4];
        oacc[0] += coef * ua.x; oacc[1] += coef * ua.y; oacc[2] += coef * ua.z; oacc[3] += coef * ua.w;
        oacc[4] += coef * ub.x; oacc[5] += coef * ub.y; oacc[6] += coef * ub.z; oacc[7] += coef * ub.w;
    }

#pragma unroll
    for (int j = 0; j < 8; ++j) wacc[wv][ln * 8 + j] = oacc[j];
    __syncthreads();

    float* orow = &out[(c * 1024 + n) * 512];
    if (first) {
        for (int d = t; d < 512; d += 256)
            orow[d] = wacc[0][d] + wacc[1][d] + wacc[2][d] + wacc[3][d];
    } else {
        for (int d = t; d < 512; d += 256)
            orow[d] += wacc[0][d] + wacc[1][d] + wacc[2][d] + wacc[3][d];
    }
}

extern "C" void kernel_launch(void* const* d_in, const int* in_sizes, int n_in,
                              void* d_out, int out_size, void* d_ws, size_t ws_size,
                              hipStream_t stream) {
    const float* x      = (const float*)d_in[0];
    const float* Wq     = (const float*)d_in[1];
    const float* keys   = (const float*)d_in[2];
    const float* w_down = (const float*)d_in[3];
    const float* w_up   = (const float*)d_in[4];
    float* out = (float*)d_out;

    char* ws = (char*)d_ws;
    float* q     = (float*)ws;                               // 32 MiB
    int*   widx  = (int*)(ws + 2048UL * 4096 * 4);           // 1 MiB
    float* wcoef = (float*)(ws + 2048UL * 4096 * 4 + 262144UL * 4);
    float* KT    = (float*)(ws + 2048UL * 4096 * 4 + 2 * 262144UL * 4);  // 4 MiB

    k0_transpose<<<256, 256, 0, stream>>>(keys, KT);
    k1_gemm<<<dim3(32, 16), 256, 0, stream>>>(x, Wq, q);
    k2_scores<<<1024, 256, 0, stream>>>(q, KT, widx, wcoef);
    k3_experts<<<2048, 256, 0, stream>>>(x, w_down, w_up, widx, wcoef, out,     0, 16384, 1);
    k3_experts<<<2048, 256, 0, stream>>>(x, w_down, w_up, widx, wcoef, out, 16384, 32768, 0);
    k3_experts<<<2048, 256, 0, stream>>>(x, w_down, w_up, widx, wcoef, out, 32768, 49152, 0);
    k3_experts<<<2048, 256, 0, stream>>>(x, w_down, w_up, widx, wcoef, out, 49152, 65536, 0);
}

// Round 13
// 407.890 us; speedup vs baseline: 1.0518x; 1.0518x over previous
//
#include <hip/hip_runtime.h>
#include <hip/hip_bf16.h>
#include <math.h>

__device__ __forceinline__ unsigned f2u(float f) {
    unsigned b = __float_as_uint(f);
    return b ^ ((unsigned)((int)b >> 31) | 0x80000000u);
}
__device__ __forceinline__ float u2f(unsigned u) {
    unsigned b = (u & 0x80000000u) ? (u ^ 0x80000000u) : ~u;
    return __uint_as_float(b);
}
__device__ __forceinline__ unsigned short f2bf(float f) {   // round-to-nearest-even
    unsigned b = __float_as_uint(f);
    return (unsigned short)((b + 0x7FFFu + ((b >> 16) & 1u)) >> 16);
}
__device__ __forceinline__ float bflo(unsigned u) { return __uint_as_float(u << 16); }
__device__ __forceinline__ float bfhi(unsigned u) { return __uint_as_float(u & 0xFFFF0000u); }

// wave-level exact k=16 radix select over 256 values (4 per lane).
__device__ __forceinline__ void radix16(unsigned u0, unsigned u1, unsigned u2, unsigned u3,
                                        unsigned& T, int& kk) {
    unsigned prefix = 0; int k = 16;
    for (int b = 31; b >= 0; --b) {
        unsigned hi = (prefix >> b) | 1u;
        int cnt = __popcll(__ballot((u0 >> b) == hi))
                + __popcll(__ballot((u1 >> b) == hi))
                + __popcll(__ballot((u2 >> b) == hi))
                + __popcll(__ballot((u3 >> b) == hi));
        if (cnt >= k) prefix |= (1u << b); else k -= cnt;
    }
    T = prefix; kk = k;
}

// ---------------- Kernel 0: key transpose ----------------
__global__ __launch_bounds__(256) void k0_transpose(const float* __restrict__ keys,
                                                    float* __restrict__ KT) {
    int bid = blockIdx.x;
    int dt = bid & 3, ktile = (bid >> 2) & 3, p = (bid >> 4) & 1, h = bid >> 5;
    __shared__ float tile[64][65];
    int t = threadIdx.x;
    int row = t >> 2;
    int c4  = t & 3;
#pragma unroll
    for (int i = 0; i < 4; ++i) {
        int dloc = (c4 + 4 * i) * 4;
        float4 v = *(const float4*)&keys[(size_t)(((h * 256 + ktile * 64 + row) * 2 + p) * 256) + dt * 64 + dloc];
        tile[dloc + 0][row] = v.x;
        tile[dloc + 1][row] = v.y;
        tile[dloc + 2][row] = v.z;
        tile[dloc + 3][row] = v.w;
    }
    __syncthreads();
#pragma unroll
    for (int i = 0; i < 4; ++i) {
        int kloc = (c4 + 4 * i) * 4;
        float4 v;
        v.x = tile[row][kloc]; v.y = tile[row][kloc + 1];
        v.z = tile[row][kloc + 2]; v.w = tile[row][kloc + 3];
        *(float4*)&KT[(size_t)((h * 2 + p) * 256 + dt * 64 + row) * 256 + ktile * 64 + kloc] = v;
    }
}

// ---------------- Kernel: f32 -> bf16 table conversion (streaming) ----------------
__global__ __launch_bounds__(256) void k_conv(const float* __restrict__ src,
                                              unsigned short* __restrict__ dst, int n8) {
    int tid = blockIdx.x * 256 + threadIdx.x;
    int stride = gridDim.x * 256;
    for (int i = tid; i < n8; i += stride) {
        float4 a = *(const float4*)&src[(size_t)i * 8];
        float4 b = *(const float4*)&src[(size_t)i * 8 + 4];
        uint4 o;
        o.x = (unsigned)f2bf(a.x) | ((unsigned)f2bf(a.y) << 16);
        o.y = (unsigned)f2bf(a.z) | ((unsigned)f2bf(a.w) << 16);
        o.z = (unsigned)f2bf(b.x) | ((unsigned)f2bf(b.y) << 16);
        o.w = (unsigned)f2bf(b.z) | ((unsigned)f2bf(b.w) << 16);
        *(uint4*)&dst[(size_t)i * 8] = o;
    }
}

// ---------------- Kernel 1: q = x @ Wq^T ----------------
__global__ __launch_bounds__(256) void k1_gemm(const float* __restrict__ A,
                                               const float* __restrict__ B,
                                               float* __restrict__ C) {
    __shared__ float As[16][128];
    __shared__ float Bs[16][128];
    int t  = threadIdx.x;
    int tx = t & 15, ty = t >> 4;
    int m0 = blockIdx.y * 128, n0 = blockIdx.x * 128;
    float acc[8][8] = {};
    for (int k0 = 0; k0 < 512; k0 += 16) {
#pragma unroll
        for (int i = 0; i < 2; ++i) {
            int u   = t * 2 + i;
            int row = u >> 2;
            int kc  = (u & 3) << 2;
            float4 av = *(const float4*)&A[(m0 + row) * 512 + k0 + kc];
            float4 bv = *(const float4*)&B[(n0 + row) * 512 + k0 + kc];
            As[kc + 0][row] = av.x; As[kc + 1][row] = av.y; As[kc + 2][row] = av.z; As[kc + 3][row] = av.w;
            Bs[kc + 0][row] = bv.x; Bs[kc + 1][row] = bv.y; Bs[kc + 2][row] = bv.z; Bs[kc + 3][row] = bv.w;
        }
        __syncthreads();
#pragma unroll
        for (int kk = 0; kk < 16; ++kk) {
            float4 a0 = *(const float4*)&As[kk][ty * 8];
            float4 a1 = *(const float4*)&As[kk][ty * 8 + 4];
            float4 b0 = *(const float4*)&Bs[kk][tx * 8];
            float4 b1 = *(const float4*)&Bs[kk][tx * 8 + 4];
            float a[8] = {a0.x, a0.y, a0.z, a0.w, a1.x, a1.y, a1.z, a1.w};
            float b[8] = {b0.x, b0.y, b0.z, b0.w, b1.x, b1.y, b1.z, b1.w};
#pragma unroll
            for (int i = 0; i < 8; ++i)
#pragma unroll
                for (int j = 0; j < 8; ++j) acc[i][j] += a[i] * b[j];
        }
        __syncthreads();
    }
#pragma unroll
    for (int i = 0; i < 8; ++i) {
        int m = m0 + ty * 8 + i;
        float4 o0; o0.x = acc[i][0]; o0.y = acc[i][1]; o0.z = acc[i][2]; o0.w = acc[i][3];
        float4 o1; o1.x = acc[i][4]; o1.y = acc[i][5]; o1.z = acc[i][6]; o1.w = acc[i][7];
        *(float4*)&C[m * 4096 + n0 + tx * 8]     = o0;
        *(float4*)&C[m * 4096 + n0 + tx * 8 + 4] = o1;
    }
}

// ---------------- Kernel 2: sim + radix top16 + combine + radix top16 + softmax ----------------
// Barrier-free coalesced KT reads, now with 2-deep ktA/ktB register pipeline:
// next d-step's 8 loads issue before the current step's 256 FMAs.
__global__ __launch_bounds__(256) void k2_scores(const float* __restrict__ q,
                                                 const float* __restrict__ KT,
                                                 int* __restrict__ widx,
                                                 float* __restrict__ wcoef) {
    int bid = blockIdx.x;
    int cc = bid & 1;
    int h  = (bid >> 1) & 7;
    int n0 = (bid >> 4) * 16;

    __shared__ float sx_s[2][16][16];
    __shared__ int   ix_s[2][16][16];

    int t = threadIdx.x;
    int wv = t >> 6, ln = t & 63;
    int wvu = __builtin_amdgcn_readfirstlane(wv);
    int pu  = wvu >> 1;
    int nhu = wvu & 1;
    unsigned long long lt = (1ull << ln) - 1ull;

    const float* qw = q + ((size_t)(pu * 1024 + n0 + nhu * 8) * 4096 + cc * 2048 + h * 256);
    const float* kp = KT + (size_t)((h * 2 + pu) * 256) * 256 + 4 * ln;

    float acc[8][4];
#pragma unroll
    for (int n = 0; n < 8; ++n)
#pragma unroll
        for (int j = 0; j < 4; ++j) acc[n][j] = 0.f;

#define FMA_STEP(KT_, D0_)                                                            \
    {                                                                                 \
        _Pragma("unroll")                                                             \
        for (int n = 0; n < 8; ++n) {                                                 \
            float4 qa = *(const float4*)&qw[(size_t)n * 4096 + (D0_)];                \
            float4 qb = *(const float4*)&qw[(size_t)n * 4096 + (D0_) + 4];            \
            acc[n][0] += qa.x * KT_[0].x + qa.y * KT_[1].x + qa.z * KT_[2].x + qa.w * KT_[3].x \
                       + qb.x * KT_[4].x + qb.y * KT_[5].x + qb.z * KT_[6].x + qb.w * KT_[7].x; \
            acc[n][1] += qa.x * KT_[0].y + qa.y * KT_[1].y + qa.z * KT_[2].y + qa.w * KT_[3].y \
                       + qb.x * KT_[4].y + qb.y * KT_[5].y + qb.z * KT_[6].y + qb.w * KT_[7].y; \
            acc[n][2] += qa.x * KT_[0].z + qa.y * KT_[1].z + qa.z * KT_[2].z + qa.w * KT_[3].z \
                       + qb.x * KT_[4].z + qb.y * KT_[5].z + qb.z * KT_[6].z + qb.w * KT_[7].z; \
            acc[n][3] += qa.x * KT_[0].w + qa.y * KT_[1].w + qa.z * KT_[2].w + qa.w * KT_[3].w \
                       + qb.x * KT_[4].w + qb.y * KT_[5].w + qb.z * KT_[6].w + qb.w * KT_[7].w; \
        }                                                                             \
    }

    float4 ktA[8], ktB[8];
#pragma unroll
    for (int dd = 0; dd < 8; ++dd) ktA[dd] = *(const float4*)&kp[(size_t)dd * 256];
    for (int d0 = 0; d0 < 256; d0 += 16) {
        // issue loads for the B half-step (d0+8) before computing A
#pragma unroll
        for (int dd = 0; dd < 8; ++dd)
            ktB[dd] = *(const float4*)&kp[(size_t)(d0 + 8 + dd) * 256];
        FMA_STEP(ktA, d0);
        // issue loads for the next A half-step (d0+16) before computing B
        if (d0 + 16 < 256) {
#pragma unroll
            for (int dd = 0; dd < 8; ++dd)
                ktA[dd] = *(const float4*)&kp[(size_t)(d0 + 16 + dd) * 256];
        }
        FMA_STEP(ktB, d0 + 8);
    }
#undef FMA_STEP

#pragma unroll
    for (int n = 0; n < 8; ++n) {
        int nn = nhu * 8 + n;
        unsigned u0 = f2u(acc[n][0]), u1 = f2u(acc[n][1]);
        unsigned u2 = f2u(acc[n][2]), u3 = f2u(acc[n][3]);
        unsigned T; int kk;
        radix16(u0, u1, u2, u3, T, kk);
        int base = 0;
#define TK1_GT(J, UJ, VJ) { unsigned long long m = __ballot(UJ > T);            \
        if (UJ > T) { int pos = base + __popcll(m & lt);                        \
            sx_s[pu][nn][pos] = VJ; ix_s[pu][nn][pos] = ln * 4 + J; }           \
        base += __popcll(m); }
        TK1_GT(0, u0, acc[n][0]); TK1_GT(1, u1, acc[n][1]);
        TK1_GT(2, u2, acc[n][2]); TK1_GT(3, u3, acc[n][3]);
#undef TK1_GT
#define TK1_EQ(J, UJ, VJ) { unsigned long long m = __ballot(UJ == T);           \
        int r = __popcll(m & lt);                                               \
        if ((UJ == T) && r < kk) { sx_s[pu][nn][base + r] = VJ;                 \
            ix_s[pu][nn][base + r] = ln * 4 + J; }                              \
        int cn = __popcll(m); int tk = cn < kk ? cn : kk;                       \
        base += tk; kk -= tk; }
        TK1_EQ(0, u0, acc[n][0]); TK1_EQ(1, u1, acc[n][1]);
        TK1_EQ(2, u2, acc[n][2]); TK1_EQ(3, u3, acc[n][3]);
#undef TK1_EQ
    }
    __syncthreads();

    for (int task = wv * 4; task < wv * 4 + 4; ++task) {
        int n = task;
        int t0 = ln, t1 = ln + 64, t2 = ln + 128, t3 = ln + 192;
        float vc0 = sx_s[0][n][t0 >> 4] + sx_s[1][n][t0 & 15];
        float vc1 = sx_s[0][n][t1 >> 4] + sx_s[1][n][t1 & 15];
        float vc2 = sx_s[0][n][t2 >> 4] + sx_s[1][n][t2 & 15];
        float vc3 = sx_s[0][n][t3 >> 4] + sx_s[1][n][t3 & 15];
        unsigned u0 = f2u(vc0), u1 = f2u(vc1), u2 = f2u(vc2), u3 = f2u(vc3);
        unsigned T; int kk;
        radix16(u0, u1, u2, u3, T, kk);
        float Tf = u2f(T);

        bool w0 = u0 > T, w1 = u1 > T, w2 = u2 > T, w3 = u3 > T;
        int q0 = 0, q1 = 0, q2 = 0, q3 = 0;
        int base = 0;
        { unsigned long long m = __ballot(w0); q0 = base + __popcll(m & lt); base += __popcll(m); }
        { unsigned long long m = __ballot(w1); q1 = base + __popcll(m & lt); base += __popcll(m); }
        { unsigned long long m = __ballot(w2); q2 = base + __popcll(m & lt); base += __popcll(m); }
        { unsigned long long m = __ballot(w3); q3 = base + __popcll(m & lt); base += __popcll(m); }
#define CMB_EQ(UJ, WJ, QJ) { unsigned long long m = __ballot(UJ == T);          \
        int r = __popcll(m & lt);                                               \
        if ((UJ == T) && r < kk) { WJ = true; QJ = base + r; }                  \
        int cn = __popcll(m); int tk = cn < kk ? cn : kk;                       \
        base += tk; kk -= tk; }
        CMB_EQ(u0, w0, q0); CMB_EQ(u1, w1, q1); CMB_EQ(u2, w2, q2); CMB_EQ(u3, w3, q3);
#undef CMB_EQ

        float e0 = 0.f, e1 = 0.f, e2 = 0.f, e3 = 0.f;
        int id0 = 0, id1 = 0, id2 = 0, id3 = 0;
        float es = 0.f;
        if (w0) { e0 = __expf(vc0 - Tf); es += e0; id0 = ix_s[0][n][t0 >> 4] * 256 + ix_s[1][n][t0 & 15]; }
        if (w1) { e1 = __expf(vc1 - Tf); es += e1; id1 = ix_s[0][n][t1 >> 4] * 256 + ix_s[1][n][t1 & 15]; }
        if (w2) { e2 = __expf(vc2 - Tf); es += e2; id2 = ix_s[0][n][t2 >> 4] * 256 + ix_s[1][n][t2 & 15]; }
        if (w3) { e3 = __expf(vc3 - Tf); es += e3; id3 = ix_s[0][n][t3 >> 4] * 256 + ix_s[1][n][t3 & 15]; }
        for (int s = 1; s < 64; s <<= 1) es += __shfl_xor(es, s);
        float inv = 1.f / es;

        int off = ((cc * 1024 + n0 + n) * 8 + h) * 16;
        if (w0) { wcoef[off + q0] = e0 * inv; widx[off + q0] = id0; }
        if (w1) { wcoef[off + q1] = e1 * inv; widx[off + q1] = id1; }
        if (w2) { wcoef[off + q2] = e2 * inv; widx[off + q2] = id2; }
        if (w3) { wcoef[off + q3] = e3 * inv; widx[off + q3] = id3; }
    }
}

// ---------------- Kernel 3 (bf16 tables): gather experts, gelu, weighted mix ----------------
__global__ __launch_bounds__(256) void k3_experts_bf16(const float* __restrict__ x,
                                                       const unsigned short* __restrict__ wd,
                                                       const unsigned short* __restrict__ wu,
                                                       const int* __restrict__ widx,
                                                       const float* __restrict__ wcoef,
                                                       float* __restrict__ out) {
    int bid = blockIdx.x;
    int c = bid >> 10, n = bid & 1023;
    int t = threadIdx.x, wv = t >> 6, ln = t & 63;
    __shared__ float wacc[4][512];

    const float* xrow = &x[(c * 1024 + n) * 512];
    float xr[8], oacc[8];
    {
        float4 xa = *(const float4*)&xrow[ln * 8];
        float4 xb = *(const float4*)&xrow[ln * 8 + 4];
        xr[0] = xa.x; xr[1] = xa.y; xr[2] = xa.z; xr[3] = xa.w;
        xr[4] = xb.x; xr[5] = xb.y; xr[6] = xb.z; xr[7] = xb.w;
    }
#pragma unroll
    for (int j = 0; j < 8; ++j) oacc[j] = 0.f;

    const int base = (c * 1024 + n) * 128;
    for (int e = wv * 32; e < wv * 32 + 32; ++e) {
        int   idx = widx[base + e];
        float wgt = wcoef[base + e];
        uint4 dv = *(const uint4*)&wd[(size_t)idx * 512 + ln * 8];
        float part = bflo(dv.x) * xr[0] + bfhi(dv.x) * xr[1]
                   + bflo(dv.y) * xr[2] + bfhi(dv.y) * xr[3]
                   + bflo(dv.z) * xr[4] + bfhi(dv.z) * xr[5]
                   + bflo(dv.w) * xr[6] + bfhi(dv.w) * xr[7];
        for (int s = 1; s < 64; s <<= 1) part += __shfl_xor(part, s);
        float hv = part;
        float coef = 0.5f * hv * (1.f + erff(hv * 0.70710678118654752f)) * wgt;
        uint4 uv = *(const uint4*)&wu[(size_t)idx * 512 + ln * 8];
        oacc[0] += coef * bflo(uv.x); oacc[1] += coef * bfhi(uv.x);
        oacc[2] += coef * bflo(uv.y); oacc[3] += coef * bfhi(uv.y);
        oacc[4] += coef * bflo(uv.z); oacc[5] += coef * bfhi(uv.z);
        oacc[6] += coef * bflo(uv.w); oacc[7] += coef * bfhi(uv.w);
    }

#pragma unroll
    for (int j = 0; j < 8; ++j) wacc[wv][ln * 8 + j] = oacc[j];
    __syncthreads();

    float* orow = &out[(c * 1024 + n) * 512];
    for (int d = t; d < 512; d += 256)
        orow[d] = wacc[0][d] + wacc[1][d] + wacc[2][d] + wacc[3][d];
}

// ---------------- Kernel 3 (f32 fallback, round-10 form) ----------------
__global__ __launch_bounds__(256) void k3_experts_f32(const float* __restrict__ x,
                                                      const float* __restrict__ w_down,
                                                      const float* __restrict__ w_up,
                                                      const int* __restrict__ widx,
                                                      const float* __restrict__ wcoef,
                                                      float* __restrict__ out) {
    int bid = blockIdx.x;
    int c = bid >> 10, n = bid & 1023;
    int t = threadIdx.x, wv = t >> 6, ln = t & 63;
    __shared__ float wacc[4][512];

    const float* xrow = &x[(c * 1024 + n) * 512];
    float xr[8], oacc[8];
    {
        float4 xa = *(const float4*)&xrow[ln * 8];
        float4 xb = *(const float4*)&xrow[ln * 8 + 4];
        xr[0] = xa.x; xr[1] = xa.y; xr[2] = xa.z; xr[3] = xa.w;
        xr[4] = xb.x; xr[5] = xb.y; xr[6] = xb.z; xr[7] = xb.w;
    }
#pragma unroll
    for (int j = 0; j < 8; ++j) oacc[j] = 0.f;

    const int base = (c * 1024 + n) * 128;
    for (int e = wv * 32; e < wv * 32 + 32; ++e) {
        int   idx = widx[base + e];
        float wgt = wcoef[base + e];
        const float* dr = &w_down[(long)idx * 512 + ln * 8];
        float4 da = *(const float4*)&dr[0];
        float4 db = *(const float4*)&dr[4];
        float part = da.x * xr[0] + da.y * xr[1] + da.z * xr[2] + da.w * xr[3]
                   + db.x * xr[4] + db.y * xr[5] + db.z * xr[6] + db.w * xr[7];
        for (int s = 1; s < 64; s <<= 1) part += __shfl_xor(part, s);
        float hv = part;
        float coef = 0.5f * hv * (1.f + erff(hv * 0.70710678118654752f)) * wgt;
        const float* ur = &w_up[(long)idx * 512 + ln * 8];
        float4 ua = *(const float4*)&ur[0];
        float4 ub = *(const float4*)&ur[4];
        oacc[0] += coef * ua.x; oacc[1] += coef * ua.y; oacc[2] += coef * ua.z; oacc[3] += coef * ua.w;
        oacc[4] += coef * ub.x; oacc[5] += coef * ub.y; oacc[6] += coef * ub.z; oacc[7] += coef * ub.w;
    }
#pragma unroll
    for (int j = 0; j < 8; ++j) wacc[wv][ln * 8 + j] = oacc[j];
    __syncthreads();

    float* orow = &out[(c * 1024 + n) * 512];
    for (int d = t; d < 512; d += 256)
        orow[d] = wacc[0][d] + wacc[1][d] + wacc[2][d] + wacc[3][d];
}

extern "C" void kernel_launch(void* const* d_in, const int* in_sizes, int n_in,
                              void* d_out, int out_size, void* d_ws, size_t ws_size,
                              hipStream_t stream) {
    const float* x      = (const float*)d_in[0];
    const float* Wq     = (const float*)d_in[1];
    const float* keys   = (const float*)d_in[2];
    const float* w_down = (const float*)d_in[3];
    const float* w_up   = (const float*)d_in[4];
    float* out = (float*)d_out;

    char* ws = (char*)d_ws;
    size_t off = 0;
    float* q     = (float*)(ws + off); off += 2048UL * 4096 * 4;      // 32 MiB
    int*   widx  = (int*)(ws + off);   off += 262144UL * 4;           // 1 MiB
    float* wcoef = (float*)(ws + off); off += 262144UL * 4;           // 1 MiB
    float* KT    = (float*)(ws + off); off += 8UL * 2 * 256 * 256 * 4; // 4 MiB
    unsigned short* wd16 = (unsigned short*)(ws + off); size_t off_wd = off; off += 65536UL * 512 * 2; // 64 MiB
    unsigned short* wu16 = (unsigned short*)(ws + off); off += 65536UL * 512 * 2;                      // 64 MiB
    bool use_bf16 = (ws_size >= off);
    (void)off_wd;

    k0_transpose<<<256, 256, 0, stream>>>(keys, KT);
    k1_gemm<<<dim3(32, 16), 256, 0, stream>>>(x, Wq, q);
    k2_scores<<<1024, 256, 0, stream>>>(q, KT, widx, wcoef);
    if (use_bf16) {
        k_conv<<<2048, 256, 0, stream>>>(w_down, wd16, 65536 * 512 / 8);
        k_conv<<<2048, 256, 0, stream>>>(w_up,   wu16, 65536 * 512 / 8);
        k3_experts_bf16<<<2048, 256, 0, stream>>>(x, wd16, wu16, widx, wcoef, out);
    } else {
        k3_experts_f32<<<2048, 256, 0, stream>>>(x, w_down, w_up, widx, wcoef, out);
    }
}

// Round 14
// 372.948 us; speedup vs baseline: 1.1503x; 1.0937x over previous
//
#include <hip/hip_runtime.h>
#include <hip/hip_bf16.h>
#include <math.h>

__device__ __forceinline__ unsigned f2u(float f) {
    unsigned b = __float_as_uint(f);
    return b ^ ((unsigned)((int)b >> 31) | 0x80000000u);
}
__device__ __forceinline__ float u2f(unsigned u) {
    unsigned b = (u & 0x80000000u) ? (u ^ 0x80000000u) : ~u;
    return __uint_as_float(b);
}
__device__ __forceinline__ unsigned short f2bf(float f) {   // round-to-nearest-even
    unsigned b = __float_as_uint(f);
    return (unsigned short)((b + 0x7FFFu + ((b >> 16) & 1u)) >> 16);
}
__device__ __forceinline__ float bflo(unsigned u) { return __uint_as_float(u << 16); }
__device__ __forceinline__ float bfhi(unsigned u) { return __uint_as_float(u & 0xFFFF0000u); }

// wave-level exact k=16 radix select over 256 values (4 per lane).
__device__ __forceinline__ void radix16(unsigned u0, unsigned u1, unsigned u2, unsigned u3,
                                        unsigned& T, int& kk) {
    unsigned prefix = 0; int k = 16;
    for (int b = 31; b >= 0; --b) {
        unsigned hi = (prefix >> b) | 1u;
        int cnt = __popcll(__ballot((u0 >> b) == hi))
                + __popcll(__ballot((u1 >> b) == hi))
                + __popcll(__ballot((u2 >> b) == hi))
                + __popcll(__ballot((u3 >> b) == hi));
        if (cnt >= k) prefix |= (1u << b); else k -= cnt;
    }
    T = prefix; kk = k;
}

// ---------------- Kernel 0: key transpose ----------------
__global__ __launch_bounds__(256) void k0_transpose(const float* __restrict__ keys,
                                                    float* __restrict__ KT) {
    int bid = blockIdx.x;
    int dt = bid & 3, ktile = (bid >> 2) & 3, p = (bid >> 4) & 1, h = bid >> 5;
    __shared__ float tile[64][65];
    int t = threadIdx.x;
    int row = t >> 2;
    int c4  = t & 3;
#pragma unroll
    for (int i = 0; i < 4; ++i) {
        int dloc = (c4 + 4 * i) * 4;
        float4 v = *(const float4*)&keys[(size_t)(((h * 256 + ktile * 64 + row) * 2 + p) * 256) + dt * 64 + dloc];
        tile[dloc + 0][row] = v.x;
        tile[dloc + 1][row] = v.y;
        tile[dloc + 2][row] = v.z;
        tile[dloc + 3][row] = v.w;
    }
    __syncthreads();
#pragma unroll
    for (int i = 0; i < 4; ++i) {
        int kloc = (c4 + 4 * i) * 4;
        float4 v;
        v.x = tile[row][kloc]; v.y = tile[row][kloc + 1];
        v.z = tile[row][kloc + 2]; v.w = tile[row][kloc + 3];
        *(float4*)&KT[(size_t)((h * 2 + p) * 256 + dt * 64 + row) * 256 + ktile * 64 + kloc] = v;
    }
}

// ---------------- Kernel: f32 -> bf16 table conversion (streaming) ----------------
__global__ __launch_bounds__(256) void k_conv(const float* __restrict__ src,
                                              unsigned short* __restrict__ dst, int n8) {
    int tid = blockIdx.x * 256 + threadIdx.x;
    int stride = gridDim.x * 256;
    for (int i = tid; i < n8; i += stride) {
        float4 a = *(const float4*)&src[(size_t)i * 8];
        float4 b = *(const float4*)&src[(size_t)i * 8 + 4];
        uint4 o;
        o.x = (unsigned)f2bf(a.x) | ((unsigned)f2bf(a.y) << 16);
        o.y = (unsigned)f2bf(a.z) | ((unsigned)f2bf(a.w) << 16);
        o.z = (unsigned)f2bf(b.x) | ((unsigned)f2bf(b.y) << 16);
        o.w = (unsigned)f2bf(b.z) | ((unsigned)f2bf(b.w) << 16);
        *(uint4*)&dst[(size_t)i * 8] = o;
    }
}

// ---------------- Kernel 1: q = x @ Wq^T ----------------
__global__ __launch_bounds__(256) void k1_gemm(const float* __restrict__ A,
                                               const float* __restrict__ B,
                                               float* __restrict__ C) {
    __shared__ float As[16][128];
    __shared__ float Bs[16][128];
    int t  = threadIdx.x;
    int tx = t & 15, ty = t >> 4;
    int m0 = blockIdx.y * 128, n0 = blockIdx.x * 128;
    float acc[8][8] = {};
    for (int k0 = 0; k0 < 512; k0 += 16) {
#pragma unroll
        for (int i = 0; i < 2; ++i) {
            int u   = t * 2 + i;
            int row = u >> 2;
            int kc  = (u & 3) << 2;
            float4 av = *(const float4*)&A[(m0 + row) * 512 + k0 + kc];
            float4 bv = *(const float4*)&B[(n0 + row) * 512 + k0 + kc];
            As[kc + 0][row] = av.x; As[kc + 1][row] = av.y; As[kc + 2][row] = av.z; As[kc + 3][row] = av.w;
            Bs[kc + 0][row] = bv.x; Bs[kc + 1][row] = bv.y; Bs[kc + 2][row] = bv.z; Bs[kc + 3][row] = bv.w;
        }
        __syncthreads();
#pragma unroll
        for (int kk = 0; kk < 16; ++kk) {
            float4 a0 = *(const float4*)&As[kk][ty * 8];
            float4 a1 = *(const float4*)&As[kk][ty * 8 + 4];
            float4 b0 = *(const float4*)&Bs[kk][tx * 8];
            float4 b1 = *(const float4*)&Bs[kk][tx * 8 + 4];
            float a[8] = {a0.x, a0.y, a0.z, a0.w, a1.x, a1.y, a1.z, a1.w};
            float b[8] = {b0.x, b0.y, b0.z, b0.w, b1.x, b1.y, b1.z, b1.w};
#pragma unroll
            for (int i = 0; i < 8; ++i)
#pragma unroll
                for (int j = 0; j < 8; ++j) acc[i][j] += a[i] * b[j];
        }
        __syncthreads();
    }
#pragma unroll
    for (int i = 0; i < 8; ++i) {
        int m = m0 + ty * 8 + i;
        float4 o0; o0.x = acc[i][0]; o0.y = acc[i][1]; o0.z = acc[i][2]; o0.w = acc[i][3];
        float4 o1; o1.x = acc[i][4]; o1.y = acc[i][5]; o1.z = acc[i][6]; o1.w = acc[i][7];
        *(float4*)&C[m * 4096 + n0 + tx * 8]     = o0;
        *(float4*)&C[m * 4096 + n0 + tx * 8 + 4] = o1;
    }
}

// ---------------- Kernel 2: sim + radix top16 + combine + radix top16 + softmax ----------------
// Round-12 form: barrier-free coalesced KT reads, NO register double-buffer
// (VGPR 44 -> occupancy; ILP-via-registers loses to TLP here, rounds 11/13).
__global__ __launch_bounds__(256) void k2_scores(const float* __restrict__ q,
                                                 const float* __restrict__ KT,
                                                 int* __restrict__ widx,
                                                 float* __restrict__ wcoef) {
    int bid = blockIdx.x;
    int cc = bid & 1;
    int h  = (bid >> 1) & 7;
    int n0 = (bid >> 4) * 16;

    __shared__ float sx_s[2][16][16];
    __shared__ int   ix_s[2][16][16];

    int t = threadIdx.x;
    int wv = t >> 6, ln = t & 63;
    int wvu = __builtin_amdgcn_readfirstlane(wv);
    int pu  = wvu >> 1;
    int nhu = wvu & 1;
    unsigned long long lt = (1ull << ln) - 1ull;

    const float* qw = q + ((size_t)(pu * 1024 + n0 + nhu * 8) * 4096 + cc * 2048 + h * 256);
    const float* kp = KT + (size_t)((h * 2 + pu) * 256) * 256 + 4 * ln;

    float acc[8][4];
#pragma unroll
    for (int n = 0; n < 8; ++n)
#pragma unroll
        for (int j = 0; j < 4; ++j) acc[n][j] = 0.f;

    for (int d0 = 0; d0 < 256; d0 += 8) {
        float4 kt[8];
#pragma unroll
        for (int dd = 0; dd < 8; ++dd)
            kt[dd] = *(const float4*)&kp[(size_t)(d0 + dd) * 256];
#pragma unroll
        for (int n = 0; n < 8; ++n) {
            float4 qa = *(const float4*)&qw[(size_t)n * 4096 + d0];
            float4 qb = *(const float4*)&qw[(size_t)n * 4096 + d0 + 4];
            acc[n][0] += qa.x * kt[0].x + qa.y * kt[1].x + qa.z * kt[2].x + qa.w * kt[3].x
                       + qb.x * kt[4].x + qb.y * kt[5].x + qb.z * kt[6].x + qb.w * kt[7].x;
            acc[n][1] += qa.x * kt[0].y + qa.y * kt[1].y + qa.z * kt[2].y + qa.w * kt[3].y
                       + qb.x * kt[4].y + qb.y * kt[5].y + qb.z * kt[6].y + qb.w * kt[7].y;
            acc[n][2] += qa.x * kt[0].z + qa.y * kt[1].z + qa.z * kt[2].z + qa.w * kt[3].z
                       + qb.x * kt[4].z + qb.y * kt[5].z + qb.z * kt[6].z + qb.w * kt[7].z;
            acc[n][3] += qa.x * kt[0].w + qa.y * kt[1].w + qa.z * kt[2].w + qa.w * kt[3].w
                       + qb.x * kt[4].w + qb.y * kt[5].w + qb.z * kt[6].w + qb.w * kt[7].w;
        }
    }

#pragma unroll
    for (int n = 0; n < 8; ++n) {
        int nn = nhu * 8 + n;
        unsigned u0 = f2u(acc[n][0]), u1 = f2u(acc[n][1]);
        unsigned u2 = f2u(acc[n][2]), u3 = f2u(acc[n][3]);
        unsigned T; int kk;
        radix16(u0, u1, u2, u3, T, kk);
        int base = 0;
#define TK1_GT(J, UJ, VJ) { unsigned long long m = __ballot(UJ > T);            \
        if (UJ > T) { int pos = base + __popcll(m & lt);                        \
            sx_s[pu][nn][pos] = VJ; ix_s[pu][nn][pos] = ln * 4 + J; }           \
        base += __popcll(m); }
        TK1_GT(0, u0, acc[n][0]); TK1_GT(1, u1, acc[n][1]);
        TK1_GT(2, u2, acc[n][2]); TK1_GT(3, u3, acc[n][3]);
#undef TK1_GT
#define TK1_EQ(J, UJ, VJ) { unsigned long long m = __ballot(UJ == T);           \
        int r = __popcll(m & lt);                                               \
        if ((UJ == T) && r < kk) { sx_s[pu][nn][base + r] = VJ;                 \
            ix_s[pu][nn][base + r] = ln * 4 + J; }                              \
        int cn = __popcll(m); int tk = cn < kk ? cn : kk;                       \
        base += tk; kk -= tk; }
        TK1_EQ(0, u0, acc[n][0]); TK1_EQ(1, u1, acc[n][1]);
        TK1_EQ(2, u2, acc[n][2]); TK1_EQ(3, u3, acc[n][3]);
#undef TK1_EQ
    }
    __syncthreads();

    for (int task = wv * 4; task < wv * 4 + 4; ++task) {
        int n = task;
        int t0 = ln, t1 = ln + 64, t2 = ln + 128, t3 = ln + 192;
        float vc0 = sx_s[0][n][t0 >> 4] + sx_s[1][n][t0 & 15];
        float vc1 = sx_s[0][n][t1 >> 4] + sx_s[1][n][t1 & 15];
        float vc2 = sx_s[0][n][t2 >> 4] + sx_s[1][n][t2 & 15];
        float vc3 = sx_s[0][n][t3 >> 4] + sx_s[1][n][t3 & 15];
        unsigned u0 = f2u(vc0), u1 = f2u(vc1), u2 = f2u(vc2), u3 = f2u(vc3);
        unsigned T; int kk;
        radix16(u0, u1, u2, u3, T, kk);
        float Tf = u2f(T);

        bool w0 = u0 > T, w1 = u1 > T, w2 = u2 > T, w3 = u3 > T;
        int q0 = 0, q1 = 0, q2 = 0, q3 = 0;
        int base = 0;
        { unsigned long long m = __ballot(w0); q0 = base + __popcll(m & lt); base += __popcll(m); }
        { unsigned long long m = __ballot(w1); q1 = base + __popcll(m & lt); base += __popcll(m); }
        { unsigned long long m = __ballot(w2); q2 = base + __popcll(m & lt); base += __popcll(m); }
        { unsigned long long m = __ballot(w3); q3 = base + __popcll(m & lt); base += __popcll(m); }
#define CMB_EQ(UJ, WJ, QJ) { unsigned long long m = __ballot(UJ == T);          \
        int r = __popcll(m & lt);                                               \
        if ((UJ == T) && r < kk) { WJ = true; QJ = base + r; }                  \
        int cn = __popcll(m); int tk = cn < kk ? cn : kk;                       \
        base += tk; kk -= tk; }
        CMB_EQ(u0, w0, q0); CMB_EQ(u1, w1, q1); CMB_EQ(u2, w2, q2); CMB_EQ(u3, w3, q3);
#undef CMB_EQ

        float e0 = 0.f, e1 = 0.f, e2 = 0.f, e3 = 0.f;
        int id0 = 0, id1 = 0, id2 = 0, id3 = 0;
        float es = 0.f;
        if (w0) { e0 = __expf(vc0 - Tf); es += e0; id0 = ix_s[0][n][t0 >> 4] * 256 + ix_s[1][n][t0 & 15]; }
        if (w1) { e1 = __expf(vc1 - Tf); es += e1; id1 = ix_s[0][n][t1 >> 4] * 256 + ix_s[1][n][t1 & 15]; }
        if (w2) { e2 = __expf(vc2 - Tf); es += e2; id2 = ix_s[0][n][t2 >> 4] * 256 + ix_s[1][n][t2 & 15]; }
        if (w3) { e3 = __expf(vc3 - Tf); es += e3; id3 = ix_s[0][n][t3 >> 4] * 256 + ix_s[1][n][t3 & 15]; }
        for (int s = 1; s < 64; s <<= 1) es += __shfl_xor(es, s);
        float inv = 1.f / es;

        int off = ((cc * 1024 + n0 + n) * 8 + h) * 16;
        if (w0) { wcoef[off + q0] = e0 * inv; widx[off + q0] = id0; }
        if (w1) { wcoef[off + q1] = e1 * inv; widx[off + q1] = id1; }
        if (w2) { wcoef[off + q2] = e2 * inv; widx[off + q2] = id2; }
        if (w3) { wcoef[off + q3] = e3 * inv; widx[off + q3] = id3; }
    }
}

// ---------------- Kernel 3 (bf16 tables): gather experts, gelu, weighted mix ----------------
__global__ __launch_bounds__(256) void k3_experts_bf16(const float* __restrict__ x,
                                                       const unsigned short* __restrict__ wd,
                                                       const unsigned short* __restrict__ wu,
                                                       const int* __restrict__ widx,
                                                       const float* __restrict__ wcoef,
                                                       float* __restrict__ out) {
    int bid = blockIdx.x;
    int c = bid >> 10, n = bid & 1023;
    int t = threadIdx.x, wv = t >> 6, ln = t & 63;
    __shared__ float wacc[4][512];

    const float* xrow = &x[(c * 1024 + n) * 512];
    float xr[8], oacc[8];
    {
        float4 xa = *(const float4*)&xrow[ln * 8];
        float4 xb = *(const float4*)&xrow[ln * 8 + 4];
        xr[0] = xa.x; xr[1] = xa.y; xr[2] = xa.z; xr[3] = xa.w;
        xr[4] = xb.x; xr[5] = xb.y; xr[6] = xb.z; xr[7] = xb.w;
    }
#pragma unroll
    for (int j = 0; j < 8; ++j) oacc[j] = 0.f;

    const int base = (c * 1024 + n) * 128;
    for (int e = wv * 32; e < wv * 32 + 32; ++e) {
        int   idx = widx[base + e];
        float wgt = wcoef[base + e];
        uint4 dv = *(const uint4*)&wd[(size_t)idx * 512 + ln * 8];
        float part = bflo(dv.x) * xr[0] + bfhi(dv.x) * xr[1]
                   + bflo(dv.y) * xr[2] + bfhi(dv.y) * xr[3]
                   + bflo(dv.z) * xr[4] + bfhi(dv.z) * xr[5]
                   + bflo(dv.w) * xr[6] + bfhi(dv.w) * xr[7];
        for (int s = 1; s < 64; s <<= 1) part += __shfl_xor(part, s);
        float hv = part;
        float coef = 0.5f * hv * (1.f + erff(hv * 0.70710678118654752f)) * wgt;
        uint4 uv = *(const uint4*)&wu[(size_t)idx * 512 + ln * 8];
        oacc[0] += coef * bflo(uv.x); oacc[1] += coef * bfhi(uv.x);
        oacc[2] += coef * bflo(uv.y); oacc[3] += coef * bfhi(uv.y);
        oacc[4] += coef * bflo(uv.z); oacc[5] += coef * bfhi(uv.z);
        oacc[6] += coef * bflo(uv.w); oacc[7] += coef * bfhi(uv.w);
    }

#pragma unroll
    for (int j = 0; j < 8; ++j) wacc[wv][ln * 8 + j] = oacc[j];
    __syncthreads();

    float* orow = &out[(c * 1024 + n) * 512];
    for (int d = t; d < 512; d += 256)
        orow[d] = wacc[0][d] + wacc[1][d] + wacc[2][d] + wacc[3][d];
}

// ---------------- Kernel 3 (f32 fallback, round-10 form) ----------------
__global__ __launch_bounds__(256) void k3_experts_f32(const float* __restrict__ x,
                                                      const float* __restrict__ w_down,
                                                      const float* __restrict__ w_up,
                                                      const int* __restrict__ widx,
                                                      const float* __restrict__ wcoef,
                                                      float* __restrict__ out) {
    int bid = blockIdx.x;
    int c = bid >> 10, n = bid & 1023;
    int t = threadIdx.x, wv = t >> 6, ln = t & 63;
    __shared__ float wacc[4][512];

    const float* xrow = &x[(c * 1024 + n) * 512];
    float xr[8], oacc[8];
    {
        float4 xa = *(const float4*)&xrow[ln * 8];
        float4 xb = *(const float4*)&xrow[ln * 8 + 4];
        xr[0] = xa.x; xr[1] = xa.y; xr[2] = xa.z; xr[3] = xa.w;
        xr[4] = xb.x; xr[5] = xb.y; xr[6] = xb.z; xr[7] = xb.w;
    }
#pragma unroll
    for (int j = 0; j < 8; ++j) oacc[j] = 0.f;

    const int base = (c * 1024 + n) * 128;
    for (int e = wv * 32; e < wv * 32 + 32; ++e) {
        int   idx = widx[base + e];
        float wgt = wcoef[base + e];
        const float* dr = &w_down[(long)idx * 512 + ln * 8];
        float4 da = *(const float4*)&dr[0];
        float4 db = *(const float4*)&dr[4];
        float part = da.x * xr[0] + da.y * xr[1] + da.z * xr[2] + da.w * xr[3]
                   + db.x * xr[4] + db.y * xr[5] + db.z * xr[6] + db.w * xr[7];
        for (int s = 1; s < 64; s <<= 1) part += __shfl_xor(part, s);
        float hv = part;
        float coef = 0.5f * hv * (1.f + erff(hv * 0.70710678118654752f)) * wgt;
        const float* ur = &w_up[(long)idx * 512 + ln * 8];
        float4 ua = *(const float4*)&ur[0];
        float4 ub = *(const float4*)&ur[4];
        oacc[0] += coef * ua.x; oacc[1] += coef * ua.y; oacc[2] += coef * ua.z; oacc[3] += coef * ua.w;
        oacc[4] += coef * ub.x; oacc[5] += coef * ub.y; oacc[6] += coef * ub.z; oacc[7] += coef * ub.w;
    }
#pragma unroll
    for (int j = 0; j < 8; ++j) wacc[wv][ln * 8 + j] = oacc[j];
    __syncthreads();

    float* orow = &out[(c * 1024 + n) * 512];
    for (int d = t; d < 512; d += 256)
        orow[d] = wacc[0][d] + wacc[1][d] + wacc[2][d] + wacc[3][d];
}

extern "C" void kernel_launch(void* const* d_in, const int* in_sizes, int n_in,
                              void* d_out, int out_size, void* d_ws, size_t ws_size,
                              hipStream_t stream) {
    const float* x      = (const float*)d_in[0];
    const float* Wq     = (const float*)d_in[1];
    const float* keys   = (const float*)d_in[2];
    const float* w_down = (const float*)d_in[3];
    const float* w_up   = (const float*)d_in[4];
    float* out = (float*)d_out;

    char* ws = (char*)d_ws;
    size_t off = 0;
    float* q     = (float*)(ws + off); off += 2048UL * 4096 * 4;      // 32 MiB
    int*   widx  = (int*)(ws + off);   off += 262144UL * 4;           // 1 MiB
    float* wcoef = (float*)(ws + off); off += 262144UL * 4;           // 1 MiB
    float* KT    = (float*)(ws + off); off += 8UL * 2 * 256 * 256 * 4; // 4 MiB
    unsigned short* wd16 = (unsigned short*)(ws + off); off += 65536UL * 512 * 2; // 64 MiB
    unsigned short* wu16 = (unsigned short*)(ws + off); off += 65536UL * 512 * 2; // 64 MiB
    bool use_bf16 = (ws_size >= off);

    k0_transpose<<<256, 256, 0, stream>>>(keys, KT);
    k1_gemm<<<dim3(32, 16), 256, 0, stream>>>(x, Wq, q);
    k2_scores<<<1024, 256, 0, stream>>>(q, KT, widx, wcoef);
    if (use_bf16) {
        k_conv<<<2048, 256, 0, stream>>>(w_down, wd16, 65536 * 512 / 8);
        k_conv<<<2048, 256, 0, stream>>>(w_up,   wu16, 65536 * 512 / 8);
        k3_experts_bf16<<<2048, 256, 0, stream>>>(x, wd16, wu16, widx, wcoef, out);
    } else {
        k3_experts_f32<<<2048, 256, 0, stream>>>(x, w_down, w_up, widx, wcoef, out);
    }
}

// Round 15
// 361.978 us; speedup vs baseline: 1.1852x; 1.0303x over previous
//
#include <hip/hip_runtime.h>
#include <hip/hip_bf16.h>
#include <math.h>

__device__ __forceinline__ unsigned f2u(float f) {
    unsigned b = __float_as_uint(f);
    return b ^ ((unsigned)((int)b >> 31) | 0x80000000u);
}
__device__ __forceinline__ float u2f(unsigned u) {
    unsigned b = (u & 0x80000000u) ? (u ^ 0x80000000u) : ~u;
    return __uint_as_float(b);
}
__device__ __forceinline__ unsigned short f2bf(float f) {   // round-to-nearest-even
    unsigned b = __float_as_uint(f);
    return (unsigned short)((b + 0x7FFFu + ((b >> 16) & 1u)) >> 16);
}
__device__ __forceinline__ float bflo(unsigned u) { return __uint_as_float(u << 16); }
__device__ __forceinline__ float bfhi(unsigned u) { return __uint_as_float(u & 0xFFFF0000u); }

// wave-level exact k=16 radix select over 256 values (4 per lane).
__device__ __forceinline__ void radix16(unsigned u0, unsigned u1, unsigned u2, unsigned u3,
                                        unsigned& T, int& kk) {
    unsigned prefix = 0; int k = 16;
    for (int b = 31; b >= 0; --b) {
        unsigned hi = (prefix >> b) | 1u;
        int cnt = __popcll(__ballot((u0 >> b) == hi))
                + __popcll(__ballot((u1 >> b) == hi))
                + __popcll(__ballot((u2 >> b) == hi))
                + __popcll(__ballot((u3 >> b) == hi));
        if (cnt >= k) prefix |= (1u << b); else k -= cnt;
    }
    T = prefix; kk = k;
}

// ---------------- Kernel 0: key transpose ----------------
__global__ __launch_bounds__(256) void k0_transpose(const float* __restrict__ keys,
                                                    float* __restrict__ KT) {
    int bid = blockIdx.x;
    int dt = bid & 3, ktile = (bid >> 2) & 3, p = (bid >> 4) & 1, h = bid >> 5;
    __shared__ float tile[64][65];
    int t = threadIdx.x;
    int row = t >> 2;
    int c4  = t & 3;
#pragma unroll
    for (int i = 0; i < 4; ++i) {
        int dloc = (c4 + 4 * i) * 4;
        float4 v = *(const float4*)&keys[(size_t)(((h * 256 + ktile * 64 + row) * 2 + p) * 256) + dt * 64 + dloc];
        tile[dloc + 0][row] = v.x;
        tile[dloc + 1][row] = v.y;
        tile[dloc + 2][row] = v.z;
        tile[dloc + 3][row] = v.w;
    }
    __syncthreads();
#pragma unroll
    for (int i = 0; i < 4; ++i) {
        int kloc = (c4 + 4 * i) * 4;
        float4 v;
        v.x = tile[row][kloc]; v.y = tile[row][kloc + 1];
        v.z = tile[row][kloc + 2]; v.w = tile[row][kloc + 3];
        *(float4*)&KT[(size_t)((h * 2 + p) * 256 + dt * 64 + row) * 256 + ktile * 64 + kloc] = v;
    }
}

// ---------------- Kernel: f32 -> bf16 table conversion (streaming) ----------------
__global__ __launch_bounds__(256) void k_conv(const float* __restrict__ src,
                                              unsigned short* __restrict__ dst, int n8) {
    int tid = blockIdx.x * 256 + threadIdx.x;
    int stride = gridDim.x * 256;
    for (int i = tid; i < n8; i += stride) {
        float4 a = *(const float4*)&src[(size_t)i * 8];
        float4 b = *(const float4*)&src[(size_t)i * 8 + 4];
        uint4 o;
        o.x = (unsigned)f2bf(a.x) | ((unsigned)f2bf(a.y) << 16);
        o.y = (unsigned)f2bf(a.z) | ((unsigned)f2bf(a.w) << 16);
        o.z = (unsigned)f2bf(b.x) | ((unsigned)f2bf(b.y) << 16);
        o.w = (unsigned)f2bf(b.z) | ((unsigned)f2bf(b.w) << 16);
        *(uint4*)&dst[(size_t)i * 8] = o;
    }
}

// ---------------- Kernel 1: q = x @ Wq^T ----------------
__global__ __launch_bounds__(256) void k1_gemm(const float* __restrict__ A,
                                               const float* __restrict__ B,
                                               float* __restrict__ C) {
    __shared__ float As[16][128];
    __shared__ float Bs[16][128];
    int t  = threadIdx.x;
    int tx = t & 15, ty = t >> 4;
    int m0 = blockIdx.y * 128, n0 = blockIdx.x * 128;
    float acc[8][8] = {};
    for (int k0 = 0; k0 < 512; k0 += 16) {
#pragma unroll
        for (int i = 0; i < 2; ++i) {
            int u   = t * 2 + i;
            int row = u >> 2;
            int kc  = (u & 3) << 2;
            float4 av = *(const float4*)&A[(m0 + row) * 512 + k0 + kc];
            float4 bv = *(const float4*)&B[(n0 + row) * 512 + k0 + kc];
            As[kc + 0][row] = av.x; As[kc + 1][row] = av.y; As[kc + 2][row] = av.z; As[kc + 3][row] = av.w;
            Bs[kc + 0][row] = bv.x; Bs[kc + 1][row] = bv.y; Bs[kc + 2][row] = bv.z; Bs[kc + 3][row] = bv.w;
        }
        __syncthreads();
#pragma unroll
        for (int kk = 0; kk < 16; ++kk) {
            float4 a0 = *(const float4*)&As[kk][ty * 8];
            float4 a1 = *(const float4*)&As[kk][ty * 8 + 4];
            float4 b0 = *(const float4*)&Bs[kk][tx * 8];
            float4 b1 = *(const float4*)&Bs[kk][tx * 8 + 4];
            float a[8] = {a0.x, a0.y, a0.z, a0.w, a1.x, a1.y, a1.z, a1.w};
            float b[8] = {b0.x, b0.y, b0.z, b0.w, b1.x, b1.y, b1.z, b1.w};
#pragma unroll
            for (int i = 0; i < 8; ++i)
#pragma unroll
                for (int j = 0; j < 8; ++j) acc[i][j] += a[i] * b[j];
        }
        __syncthreads();
    }
#pragma unroll
    for (int i = 0; i < 8; ++i) {
        int m = m0 + ty * 8 + i;
        float4 o0; o0.x = acc[i][0]; o0.y = acc[i][1]; o0.z = acc[i][2]; o0.w = acc[i][3];
        float4 o1; o1.x = acc[i][4]; o1.y = acc[i][5]; o1.z = acc[i][6]; o1.w = acc[i][7];
        *(float4*)&C[m * 4096 + n0 + tx * 8]     = o0;
        *(float4*)&C[m * 4096 + n0 + tx * 8 + 4] = o1;
    }
}

// ---------------- Kernel 2: sim + radix top16 + combine + radix top16 + softmax ----------------
// 512 threads / 8 waves per block, grid 1024 -> 4 blocks x 8 waves = 32 waves/CU (100%).
// Wave wv -> (pu = wv>>2, quad nq = wv&3): 4 q-rows per wave, acc[4][4] (low VGPR).
// Barrier-free coalesced KT reads (round-12 form), q via wave-uniform loads.
__global__ __launch_bounds__(512) void k2_scores(const float* __restrict__ q,
                                                 const float* __restrict__ KT,
                                                 int* __restrict__ widx,
                                                 float* __restrict__ wcoef) {
    int bid = blockIdx.x;
    int cc = bid & 1;
    int h  = (bid >> 1) & 7;
    int n0 = (bid >> 4) * 16;

    __shared__ float sx_s[2][16][16];
    __shared__ int   ix_s[2][16][16];

    int t = threadIdx.x;
    int wv = t >> 6, ln = t & 63;
    int wvu = __builtin_amdgcn_readfirstlane(wv);
    int pu  = wvu >> 2;        // key half / q batch row
    int nq  = wvu & 3;         // row quad: rows nq*4 .. nq*4+3
    unsigned long long lt = (1ull << ln) - 1ull;

    const float* qw = q + ((size_t)(pu * 1024 + n0 + nq * 4) * 4096 + cc * 2048 + h * 256);
    const float* kp = KT + (size_t)((h * 2 + pu) * 256) * 256 + 4 * ln;

    float acc[4][4];
#pragma unroll
    for (int n = 0; n < 4; ++n)
#pragma unroll
        for (int j = 0; j < 4; ++j) acc[n][j] = 0.f;

    for (int d0 = 0; d0 < 256; d0 += 8) {
        float4 kt[8];
#pragma unroll
        for (int dd = 0; dd < 8; ++dd)
            kt[dd] = *(const float4*)&kp[(size_t)(d0 + dd) * 256];
#pragma unroll
        for (int n = 0; n < 4; ++n) {
            float4 qa = *(const float4*)&qw[(size_t)n * 4096 + d0];
            float4 qb = *(const float4*)&qw[(size_t)n * 4096 + d0 + 4];
            acc[n][0] += qa.x * kt[0].x + qa.y * kt[1].x + qa.z * kt[2].x + qa.w * kt[3].x
                       + qb.x * kt[4].x + qb.y * kt[5].x + qb.z * kt[6].x + qb.w * kt[7].x;
            acc[n][1] += qa.x * kt[0].y + qa.y * kt[1].y + qa.z * kt[2].y + qa.w * kt[3].y
                       + qb.x * kt[4].y + qb.y * kt[5].y + qb.z * kt[6].y + qb.w * kt[7].y;
            acc[n][2] += qa.x * kt[0].z + qa.y * kt[1].z + qa.z * kt[2].z + qa.w * kt[3].z
                       + qb.x * kt[4].z + qb.y * kt[5].z + qb.z * kt[6].z + qb.w * kt[7].z;
            acc[n][3] += qa.x * kt[0].w + qa.y * kt[1].w + qa.z * kt[2].w + qa.w * kt[3].w
                       + qb.x * kt[4].w + qb.y * kt[5].w + qb.z * kt[6].w + qb.w * kt[7].w;
        }
    }

    // ---- top-16 per (pu, row): radix select + ballot compaction; key id = 4*ln + J ----
#pragma unroll
    for (int n = 0; n < 4; ++n) {
        int nn = nq * 4 + n;
        unsigned u0 = f2u(acc[n][0]), u1 = f2u(acc[n][1]);
        unsigned u2 = f2u(acc[n][2]), u3 = f2u(acc[n][3]);
        unsigned T; int kk;
        radix16(u0, u1, u2, u3, T, kk);
        int base = 0;
#define TK1_GT(J, UJ, VJ) { unsigned long long m = __ballot(UJ > T);            \
        if (UJ > T) { int pos = base + __popcll(m & lt);                        \
            sx_s[pu][nn][pos] = VJ; ix_s[pu][nn][pos] = ln * 4 + J; }           \
        base += __popcll(m); }
        TK1_GT(0, u0, acc[n][0]); TK1_GT(1, u1, acc[n][1]);
        TK1_GT(2, u2, acc[n][2]); TK1_GT(3, u3, acc[n][3]);
#undef TK1_GT
#define TK1_EQ(J, UJ, VJ) { unsigned long long m = __ballot(UJ == T);           \
        int r = __popcll(m & lt);                                               \
        if ((UJ == T) && r < kk) { sx_s[pu][nn][base + r] = VJ;                 \
            ix_s[pu][nn][base + r] = ln * 4 + J; }                              \
        int cn = __popcll(m); int tk = cn < kk ? cn : kk;                       \
        base += tk; kk -= tk; }
        TK1_EQ(0, u0, acc[n][0]); TK1_EQ(1, u1, acc[n][1]);
        TK1_EQ(2, u2, acc[n][2]); TK1_EQ(3, u3, acc[n][3]);
#undef TK1_EQ
    }
    __syncthreads();

    // ---- combine 16x16, radix top-16, softmax: 16 tasks, 2 per wave ----
    for (int task = wv * 2; task < wv * 2 + 2; ++task) {
        int n = task;
        int t0 = ln, t1 = ln + 64, t2 = ln + 128, t3 = ln + 192;
        float vc0 = sx_s[0][n][t0 >> 4] + sx_s[1][n][t0 & 15];
        float vc1 = sx_s[0][n][t1 >> 4] + sx_s[1][n][t1 & 15];
        float vc2 = sx_s[0][n][t2 >> 4] + sx_s[1][n][t2 & 15];
        float vc3 = sx_s[0][n][t3 >> 4] + sx_s[1][n][t3 & 15];
        unsigned u0 = f2u(vc0), u1 = f2u(vc1), u2 = f2u(vc2), u3 = f2u(vc3);
        unsigned T; int kk;
        radix16(u0, u1, u2, u3, T, kk);
        float Tf = u2f(T);

        bool w0 = u0 > T, w1 = u1 > T, w2 = u2 > T, w3 = u3 > T;
        int q0 = 0, q1 = 0, q2 = 0, q3 = 0;
        int base = 0;
        { unsigned long long m = __ballot(w0); q0 = base + __popcll(m & lt); base += __popcll(m); }
        { unsigned long long m = __ballot(w1); q1 = base + __popcll(m & lt); base += __popcll(m); }
        { unsigned long long m = __ballot(w2); q2 = base + __popcll(m & lt); base += __popcll(m); }
        { unsigned long long m = __ballot(w3); q3 = base + __popcll(m & lt); base += __popcll(m); }
#define CMB_EQ(UJ, WJ, QJ) { unsigned long long m = __ballot(UJ == T);          \
        int r = __popcll(m & lt);                                               \
        if ((UJ == T) && r < kk) { WJ = true; QJ = base + r; }                  \
        int cn = __popcll(m); int tk = cn < kk ? cn : kk;                       \
        base += tk; kk -= tk; }
        CMB_EQ(u0, w0, q0); CMB_EQ(u1, w1, q1); CMB_EQ(u2, w2, q2); CMB_EQ(u3, w3, q3);
#undef CMB_EQ

        float e0 = 0.f, e1 = 0.f, e2 = 0.f, e3 = 0.f;
        int id0 = 0, id1 = 0, id2 = 0, id3 = 0;
        float es = 0.f;
        if (w0) { e0 = __expf(vc0 - Tf); es += e0; id0 = ix_s[0][n][t0 >> 4] * 256 + ix_s[1][n][t0 & 15]; }
        if (w1) { e1 = __expf(vc1 - Tf); es += e1; id1 = ix_s[0][n][t1 >> 4] * 256 + ix_s[1][n][t1 & 15]; }
        if (w2) { e2 = __expf(vc2 - Tf); es += e2; id2 = ix_s[0][n][t2 >> 4] * 256 + ix_s[1][n][t2 & 15]; }
        if (w3) { e3 = __expf(vc3 - Tf); es += e3; id3 = ix_s[0][n][t3 >> 4] * 256 + ix_s[1][n][t3 & 15]; }
        for (int s = 1; s < 64; s <<= 1) es += __shfl_xor(es, s);
        float inv = 1.f / es;

        int off = ((cc * 1024 + n0 + n) * 8 + h) * 16;
        if (w0) { wcoef[off + q0] = e0 * inv; widx[off + q0] = id0; }
        if (w1) { wcoef[off + q1] = e1 * inv; widx[off + q1] = id1; }
        if (w2) { wcoef[off + q2] = e2 * inv; widx[off + q2] = id2; }
        if (w3) { wcoef[off + q3] = e3 * inv; widx[off + q3] = id3; }
    }
}

// ---------------- Kernel 3 (bf16 tables): gather experts, gelu, weighted mix ----------------
__global__ __launch_bounds__(256) void k3_experts_bf16(const float* __restrict__ x,
                                                       const unsigned short* __restrict__ wd,
                                                       const unsigned short* __restrict__ wu,
                                                       const int* __restrict__ widx,
                                                       const float* __restrict__ wcoef,
                                                       float* __restrict__ out) {
    int bid = blockIdx.x;
    int c = bid >> 10, n = bid & 1023;
    int t = threadIdx.x, wv = t >> 6, ln = t & 63;
    __shared__ float wacc[4][512];

    const float* xrow = &x[(c * 1024 + n) * 512];
    float xr[8], oacc[8];
    {
        float4 xa = *(const float4*)&xrow[ln * 8];
        float4 xb = *(const float4*)&xrow[ln * 8 + 4];
        xr[0] = xa.x; xr[1] = xa.y; xr[2] = xa.z; xr[3] = xa.w;
        xr[4] = xb.x; xr[5] = xb.y; xr[6] = xb.z; xr[7] = xb.w;
    }
#pragma unroll
    for (int j = 0; j < 8; ++j) oacc[j] = 0.f;

    const int base = (c * 1024 + n) * 128;
    for (int e = wv * 32; e < wv * 32 + 32; ++e) {
        int   idx = widx[base + e];
        float wgt = wcoef[base + e];
        uint4 dv = *(const uint4*)&wd[(size_t)idx * 512 + ln * 8];
        float part = bflo(dv.x) * xr[0] + bfhi(dv.x) * xr[1]
                   + bflo(dv.y) * xr[2] + bfhi(dv.y) * xr[3]
                   + bflo(dv.z) * xr[4] + bfhi(dv.z) * xr[5]
                   + bflo(dv.w) * xr[6] + bfhi(dv.w) * xr[7];
        for (int s = 1; s < 64; s <<= 1) part += __shfl_xor(part, s);
        float hv = part;
        float coef = 0.5f * hv * (1.f + erff(hv * 0.70710678118654752f)) * wgt;
        uint4 uv = *(const uint4*)&wu[(size_t)idx * 512 + ln * 8];
        oacc[0] += coef * bflo(uv.x); oacc[1] += coef * bfhi(uv.x);
        oacc[2] += coef * bflo(uv.y); oacc[3] += coef * bfhi(uv.y);
        oacc[4] += coef * bflo(uv.z); oacc[5] += coef * bfhi(uv.z);
        oacc[6] += coef * bflo(uv.w); oacc[7] += coef * bfhi(uv.w);
    }

#pragma unroll
    for (int j = 0; j < 8; ++j) wacc[wv][ln * 8 + j] = oacc[j];
    __syncthreads();

    float* orow = &out[(c * 1024 + n) * 512];
    for (int d = t; d < 512; d += 256)
        orow[d] = wacc[0][d] + wacc[1][d] + wacc[2][d] + wacc[3][d];
}

// ---------------- Kernel 3 (f32 fallback, round-10 form) ----------------
__global__ __launch_bounds__(256) void k3_experts_f32(const float* __restrict__ x,
                                                      const float* __restrict__ w_down,
                                                      const float* __restrict__ w_up,
                                                      const int* __restrict__ widx,
                                                      const float* __restrict__ wcoef,
                                                      float* __restrict__ out) {
    int bid = blockIdx.x;
    int c = bid >> 10, n = bid & 1023;
    int t = threadIdx.x, wv = t >> 6, ln = t & 63;
    __shared__ float wacc[4][512];

    const float* xrow = &x[(c * 1024 + n) * 512];
    float xr[8], oacc[8];
    {
        float4 xa = *(const float4*)&xrow[ln * 8];
        float4 xb = *(const float4*)&xrow[ln * 8 + 4];
        xr[0] = xa.x; xr[1] = xa.y; xr[2] = xa.z; xr[3] = xa.w;
        xr[4] = xb.x; xr[5] = xb.y; xr[6] = xb.z; xr[7] = xb.w;
    }
#pragma unroll
    for (int j = 0; j < 8; ++j) oacc[j] = 0.f;

    const int base = (c * 1024 + n) * 128;
    for (int e = wv * 32; e < wv * 32 + 32; ++e) {
        int   idx = widx[base + e];
        float wgt = wcoef[base + e];
        const float* dr = &w_down[(long)idx * 512 + ln * 8];
        float4 da = *(const float4*)&dr[0];
        float4 db = *(const float4*)&dr[4];
        float part = da.x * xr[0] + da.y * xr[1] + da.z * xr[2] + da.w * xr[3]
                   + db.x * xr[4] + db.y * xr[5] + db.z * xr[6] + db.w * xr[7];
        for (int s = 1; s < 64; s <<= 1) part += __shfl_xor(part, s);
        float hv = part;
        float coef = 0.5f * hv * (1.f + erff(hv * 0.70710678118654752f)) * wgt;
        const float* ur = &w_up[(long)idx * 512 + ln * 8];
        float4 ua = *(const float4*)&ur[0];
        float4 ub = *(const float4*)&ur[4];
        oacc[0] += coef * ua.x; oacc[1] += coef * ua.y; oacc[2] += coef * ua.z; oacc[3] += coef * ua.w;
        oacc[4] += coef * ub.x; oacc[5] += coef * ub.y; oacc[6] += coef * ub.z; oacc[7] += coef * ub.w;
    }
#pragma unroll
    for (int j = 0; j < 8; ++j) wacc[wv][ln * 8 + j] = oacc[j];
    __syncthreads();

    float* orow = &out[(c * 1024 + n) * 512];
    for (int d = t; d < 512; d += 256)
        orow[d] = wacc[0][d] + wacc[1][d] + wacc[2][d] + wacc[3][d];
}

extern "C" void kernel_launch(void* const* d_in, const int* in_sizes, int n_in,
                              void* d_out, int out_size, void* d_ws, size_t ws_size,
                              hipStream_t stream) {
    const float* x      = (const float*)d_in[0];
    const float* Wq     = (const float*)d_in[1];
    const float* keys   = (const float*)d_in[2];
    const float* w_down = (const float*)d_in[3];
    const float* w_up   = (const float*)d_in[4];
    float* out = (float*)d_out;

    char* ws = (char*)d_ws;
    size_t off = 0;
    float* q     = (float*)(ws + off); off += 2048UL * 4096 * 4;      // 32 MiB
    int*   widx  = (int*)(ws + off);   off += 262144UL * 4;           // 1 MiB
    float* wcoef = (float*)(ws + off); off += 262144UL * 4;           // 1 MiB
    float* KT    = (float*)(ws + off); off += 8UL * 2 * 256 * 256 * 4; // 4 MiB
    unsigned short* wd16 = (unsigned short*)(ws + off); off += 65536UL * 512 * 2; // 64 MiB
    unsigned short* wu16 = (unsigned short*)(ws + off); off += 65536UL * 512 * 2; // 64 MiB
    bool use_bf16 = (ws_size >= off);

    k0_transpose<<<256, 256, 0, stream>>>(keys, KT);
    k1_gemm<<<dim3(32, 16), 256, 0, stream>>>(x, Wq, q);
    k2_scores<<<1024, 512, 0, stream>>>(q, KT, widx, wcoef);
    if (use_bf16) {
        k_conv<<<2048, 256, 0, stream>>>(w_down, wd16, 65536 * 512 / 8);
        k_conv<<<2048, 256, 0, stream>>>(w_up,   wu16, 65536 * 512 / 8);
        k3_experts_bf16<<<2048, 256, 0, stream>>>(x, wd16, wu16, widx, wcoef, out);
    } else {
        k3_experts_f32<<<2048, 256, 0, stream>>>(x, w_down, w_up, widx, wcoef, out);
    }
}

// Round 16
// 347.331 us; speedup vs baseline: 1.2351x; 1.0422x over previous
//
#include <hip/hip_runtime.h>
#include <hip/hip_bf16.h>
#include <math.h>

__device__ __forceinline__ unsigned f2u(float f) {
    unsigned b = __float_as_uint(f);
    return b ^ ((unsigned)((int)b >> 31) | 0x80000000u);
}
__device__ __forceinline__ float u2f(unsigned u) {
    unsigned b = (u & 0x80000000u) ? (u ^ 0x80000000u) : ~u;
    return __uint_as_float(b);
}
__device__ __forceinline__ unsigned short f2bf(float f) {   // round-to-nearest-even
    unsigned b = __float_as_uint(f);
    return (unsigned short)((b + 0x7FFFu + ((b >> 16) & 1u)) >> 16);
}
__device__ __forceinline__ float bflo(unsigned u) { return __uint_as_float(u << 16); }
__device__ __forceinline__ float bfhi(unsigned u) { return __uint_as_float(u & 0xFFFF0000u); }

// wave-level exact k=16 radix select over 256 values (4 per lane).
__device__ __forceinline__ void radix16(unsigned u0, unsigned u1, unsigned u2, unsigned u3,
                                        unsigned& T, int& kk) {
    unsigned prefix = 0; int k = 16;
    for (int b = 31; b >= 0; --b) {
        unsigned hi = (prefix >> b) | 1u;
        int cnt = __popcll(__ballot((u0 >> b) == hi))
                + __popcll(__ballot((u1 >> b) == hi))
                + __popcll(__ballot((u2 >> b) == hi))
                + __popcll(__ballot((u3 >> b) == hi));
        if (cnt >= k) prefix |= (1u << b); else k -= cnt;
    }
    T = prefix; kk = k;
}

// ---------------- Kernel: f32 -> bf16 table conversion (streaming) ----------------
__global__ __launch_bounds__(256) void k_conv(const float* __restrict__ src,
                                              unsigned short* __restrict__ dst, int n8) {
    int tid = blockIdx.x * 256 + threadIdx.x;
    int stride = gridDim.x * 256;
    for (int i = tid; i < n8; i += stride) {
        float4 a = *(const float4*)&src[(size_t)i * 8];
        float4 b = *(const float4*)&src[(size_t)i * 8 + 4];
        uint4 o;
        o.x = (unsigned)f2bf(a.x) | ((unsigned)f2bf(a.y) << 16);
        o.y = (unsigned)f2bf(a.z) | ((unsigned)f2bf(a.w) << 16);
        o.z = (unsigned)f2bf(b.x) | ((unsigned)f2bf(b.y) << 16);
        o.w = (unsigned)f2bf(b.z) | ((unsigned)f2bf(b.w) << 16);
        *(uint4*)&dst[(size_t)i * 8] = o;
    }
}

// ---------------- Kernel K2: fold keys into Wq ----------------
// K2[p][r = c*2048 + h*256 + k][d] = sum_dk keys[((h*256+k)*2+p)*256+dk] * Wq[(c*2048+h*256+dk)*512 + d]
// grid: x = dtile(4), y = ((c*8+h)*2 + ktile) in [0,32), z = p. 128x128 tile, K=256.
__global__ __launch_bounds__(256) void kK2(const float* __restrict__ keys,
                                           const float* __restrict__ Wq,
                                           float* __restrict__ K2) {
    __shared__ float As[16][128];
    __shared__ float Bs[16][128];
    int t  = threadIdx.x;
    int tx = t & 15, ty = t >> 4;
    int p = blockIdx.z;
    int ktile = blockIdx.y & 1, ch = blockIdx.y >> 1;
    int h = ch & 7, c = ch >> 3;
    int m0 = ktile * 128;            // k offset within (h)
    int n0 = blockIdx.x * 128;       // d offset
    const float* kb = keys + ((size_t)(h * 256 + m0) * 2 + p) * 256;   // row stride 512
    const float* wb = Wq + (size_t)(c * 2048 + h * 256) * 512;         // row stride 512 (rows = dk)
    float acc[8][8] = {};
    for (int k0 = 0; k0 < 256; k0 += 16) {
#pragma unroll
        for (int i = 0; i < 2; ++i) {
            int u   = t * 2 + i;
            int row = u >> 2;            // k row 0..127
            int kc  = (u & 3) << 2;      // dk 0,4,8,12
            float4 av = *(const float4*)&kb[(size_t)row * 512 + k0 + kc];
            As[kc + 0][row] = av.x; As[kc + 1][row] = av.y; As[kc + 2][row] = av.z; As[kc + 3][row] = av.w;
            int v = u;                   // 0..511
            int dkrow = v >> 5;          // 0..15
            int dcol  = (v & 31) << 2;   // 0..124
            float4 bv = *(const float4*)&wb[(size_t)(k0 + dkrow) * 512 + n0 + dcol];
            *(float4*)&Bs[dkrow][dcol] = bv;
        }
        __syncthreads();
#pragma unroll
        for (int kk = 0; kk < 16; ++kk) {
            float4 a0 = *(const float4*)&As[kk][ty * 8];
            float4 a1 = *(const float4*)&As[kk][ty * 8 + 4];
            float4 b0 = *(const float4*)&Bs[kk][tx * 8];
            float4 b1 = *(const float4*)&Bs[kk][tx * 8 + 4];
            float a[8] = {a0.x, a0.y, a0.z, a0.w, a1.x, a1.y, a1.z, a1.w};
            float b[8] = {b0.x, b0.y, b0.z, b0.w, b1.x, b1.y, b1.z, b1.w};
#pragma unroll
            for (int i = 0; i < 8; ++i)
#pragma unroll
                for (int j = 0; j < 8; ++j) acc[i][j] += a[i] * b[j];
        }
        __syncthreads();
    }
    float* Cp = K2 + (size_t)p * 4096 * 512;
#pragma unroll
    for (int i = 0; i < 8; ++i) {
        int r = c * 2048 + h * 256 + m0 + ty * 8 + i;
        float4 o0; o0.x = acc[i][0]; o0.y = acc[i][1]; o0.z = acc[i][2]; o0.w = acc[i][3];
        float4 o1; o1.x = acc[i][4]; o1.y = acc[i][5]; o1.z = acc[i][6]; o1.w = acc[i][7];
        *(float4*)&Cp[(size_t)r * 512 + n0 + tx * 8]     = o0;
        *(float4*)&Cp[(size_t)r * 512 + n0 + tx * 8 + 4] = o1;
    }
}

// ---------------- Kernel S: S[p] = x[p] @ K2[p]^T ----------------
// A = x[p] (1024 x 512), B = K2[p] (4096 x 512), C = S[p] (1024 x 4096). k1 body.
__global__ __launch_bounds__(256) void kS_gemm(const float* __restrict__ x,
                                               const float* __restrict__ K2,
                                               float* __restrict__ S) {
    __shared__ float As[16][128];
    __shared__ float Bs[16][128];
    int t  = threadIdx.x;
    int tx = t & 15, ty = t >> 4;
    int p  = blockIdx.z;
    int m0 = blockIdx.y * 128, n0 = blockIdx.x * 128;
    const float* A = x  + (size_t)p * 1024 * 512;
    const float* B = K2 + (size_t)p * 4096 * 512;
    float* C = S + (size_t)p * 1024 * 4096;
    float acc[8][8] = {};
    for (int k0 = 0; k0 < 512; k0 += 16) {
#pragma unroll
        for (int i = 0; i < 2; ++i) {
            int u   = t * 2 + i;
            int row = u >> 2;
            int kc  = (u & 3) << 2;
            float4 av = *(const float4*)&A[(size_t)(m0 + row) * 512 + k0 + kc];
            float4 bv = *(const float4*)&B[(size_t)(n0 + row) * 512 + k0 + kc];
            As[kc + 0][row] = av.x; As[kc + 1][row] = av.y; As[kc + 2][row] = av.z; As[kc + 3][row] = av.w;
            Bs[kc + 0][row] = bv.x; Bs[kc + 1][row] = bv.y; Bs[kc + 2][row] = bv.z; Bs[kc + 3][row] = bv.w;
        }
        __syncthreads();
#pragma unroll
        for (int kk = 0; kk < 16; ++kk) {
            float4 a0 = *(const float4*)&As[kk][ty * 8];
            float4 a1 = *(const float4*)&As[kk][ty * 8 + 4];
            float4 b0 = *(const float4*)&Bs[kk][tx * 8];
            float4 b1 = *(const float4*)&Bs[kk][tx * 8 + 4];
            float a[8] = {a0.x, a0.y, a0.z, a0.w, a1.x, a1.y, a1.z, a1.w};
            float b[8] = {b0.x, b0.y, b0.z, b0.w, b1.x, b1.y, b1.z, b1.w};
#pragma unroll
            for (int i = 0; i < 8; ++i)
#pragma unroll
                for (int j = 0; j < 8; ++j) acc[i][j] += a[i] * b[j];
        }
        __syncthreads();
    }
#pragma unroll
    for (int i = 0; i < 8; ++i) {
        int m = m0 + ty * 8 + i;
        float4 o0; o0.x = acc[i][0]; o0.y = acc[i][1]; o0.z = acc[i][2]; o0.w = acc[i][3];
        float4 o1; o1.x = acc[i][4]; o1.y = acc[i][5]; o1.z = acc[i][6]; o1.w = acc[i][7];
        *(float4*)&C[(size_t)m * 4096 + n0 + tx * 8]     = o0;
        *(float4*)&C[(size_t)m * 4096 + n0 + tx * 8 + 4] = o1;
    }
}

// ---------------- Kernel topk: radix top16 x2 + combine + top16 + softmax ----------------
// One wave per (c,n,h) task; 4 waves/block; grid 4096.
__global__ __launch_bounds__(256) void k2_topk(const float* __restrict__ S,
                                               int* __restrict__ widx,
                                               float* __restrict__ wcoef) {
    __shared__ float sx_s[4][2][16];
    __shared__ int   ix_s[4][2][16];

    int t = threadIdx.x;
    int wv = t >> 6, ln = t & 63;
    int task = blockIdx.x * 4 + wv;
    int c = task >> 13;
    int n = (task >> 3) & 1023;
    int h = task & 7;
    unsigned long long lt = (1ull << ln) - 1ull;

    const float* s0p = S + (size_t)n * 4096 + c * 2048 + h * 256 + ln * 4;
    float4 s0 = *(const float4*)&s0p[0];
    float4 s1 = *(const float4*)&s0p[1024UL * 4096];

    // ---- per-half top-16; key id = 4*ln + J ----
#define TK_HALF(PIDX, V)                                                          \
    {                                                                             \
        unsigned u0 = f2u(V.x), u1 = f2u(V.y), u2 = f2u(V.z), u3 = f2u(V.w);      \
        unsigned T; int kk;                                                       \
        radix16(u0, u1, u2, u3, T, kk);                                           \
        int base = 0;                                                             \
        { unsigned long long m = __ballot(u0 > T);                                \
          if (u0 > T) { int pos = base + __popcll(m & lt);                        \
              sx_s[wv][PIDX][pos] = V.x; ix_s[wv][PIDX][pos] = ln * 4 + 0; }      \
          base += __popcll(m); }                                                  \
        { unsigned long long m = __ballot(u1 > T);                                \
          if (u1 > T) { int pos = base + __popcll(m & lt);                        \
              sx_s[wv][PIDX][pos] = V.y; ix_s[wv][PIDX][pos] = ln * 4 + 1; }      \
          base += __popcll(m); }                                                  \
        { unsigned long long m = __ballot(u2 > T);                                \
          if (u2 > T) { int pos = base + __popcll(m & lt);                        \
              sx_s[wv][PIDX][pos] = V.z; ix_s[wv][PIDX][pos] = ln * 4 + 2; }      \
          base += __popcll(m); }                                                  \
        { unsigned long long m = __ballot(u3 > T);                                \
          if (u3 > T) { int pos = base + __popcll(m & lt);                        \
              sx_s[wv][PIDX][pos] = V.w; ix_s[wv][PIDX][pos] = ln * 4 + 3; }      \
          base += __popcll(m); }                                                  \
        { unsigned long long m = __ballot(u0 == T); int r = __popcll(m & lt);     \
          if ((u0 == T) && r < kk) { sx_s[wv][PIDX][base + r] = V.x;              \
              ix_s[wv][PIDX][base + r] = ln * 4 + 0; }                            \
          int cn2 = __popcll(m); int tk = cn2 < kk ? cn2 : kk; base += tk; kk -= tk; } \
        { unsigned long long m = __ballot(u1 == T); int r = __popcll(m & lt);     \
          if ((u1 == T) && r < kk) { sx_s[wv][PIDX][base + r] = V.y;              \
              ix_s[wv][PIDX][base + r] = ln * 4 + 1; }                            \
          int cn2 = __popcll(m); int tk = cn2 < kk ? cn2 : kk; base += tk; kk -= tk; } \
        { unsigned long long m = __ballot(u2 == T); int r = __popcll(m & lt);     \
          if ((u2 == T) && r < kk) { sx_s[wv][PIDX][base + r] = V.z;              \
              ix_s[wv][PIDX][base + r] = ln * 4 + 2; }                            \
          int cn2 = __popcll(m); int tk = cn2 < kk ? cn2 : kk; base += tk; kk -= tk; } \
        { unsigned long long m = __ballot(u3 == T); int r = __popcll(m & lt);     \
          if ((u3 == T) && r < kk) { sx_s[wv][PIDX][base + r] = V.w;              \
              ix_s[wv][PIDX][base + r] = ln * 4 + 3; }                            \
          int cn2 = __popcll(m); int tk = cn2 < kk ? cn2 : kk; base += tk; kk -= tk; } \
    }
    TK_HALF(0, s0);
    TK_HALF(1, s1);
#undef TK_HALF
    __syncthreads();

    // ---- combine 16x16, radix top-16, softmax ----
    int t0 = ln, t1 = ln + 64, t2 = ln + 128, t3 = ln + 192;
    float vc0 = sx_s[wv][0][t0 >> 4] + sx_s[wv][1][t0 & 15];
    float vc1 = sx_s[wv][0][t1 >> 4] + sx_s[wv][1][t1 & 15];
    float vc2 = sx_s[wv][0][t2 >> 4] + sx_s[wv][1][t2 & 15];
    float vc3 = sx_s[wv][0][t3 >> 4] + sx_s[wv][1][t3 & 15];
    unsigned u0 = f2u(vc0), u1 = f2u(vc1), u2 = f2u(vc2), u3 = f2u(vc3);
    unsigned T; int kk;
    radix16(u0, u1, u2, u3, T, kk);
    float Tf = u2f(T);

    bool w0 = u0 > T, w1 = u1 > T, w2 = u2 > T, w3 = u3 > T;
    int q0 = 0, q1 = 0, q2 = 0, q3 = 0;
    int base = 0;
    { unsigned long long m = __ballot(w0); q0 = base + __popcll(m & lt); base += __popcll(m); }
    { unsigned long long m = __ballot(w1); q1 = base + __popcll(m & lt); base += __popcll(m); }
    { unsigned long long m = __ballot(w2); q2 = base + __popcll(m & lt); base += __popcll(m); }
    { unsigned long long m = __ballot(w3); q3 = base + __popcll(m & lt); base += __popcll(m); }
#define CMB_EQ(UJ, WJ, QJ) { unsigned long long m = __ballot(UJ == T);          \
    int r = __popcll(m & lt);                                                   \
    if ((UJ == T) && r < kk) { WJ = true; QJ = base + r; }                      \
    int cn2 = __popcll(m); int tk = cn2 < kk ? cn2 : kk;                        \
    base += tk; kk -= tk; }
    CMB_EQ(u0, w0, q0); CMB_EQ(u1, w1, q1); CMB_EQ(u2, w2, q2); CMB_EQ(u3, w3, q3);
#undef CMB_EQ

    float e0 = 0.f, e1 = 0.f, e2 = 0.f, e3 = 0.f;
    int id0 = 0, id1 = 0, id2 = 0, id3 = 0;
    float es = 0.f;
    if (w0) { e0 = __expf(vc0 - Tf); es += e0; id0 = ix_s[wv][0][t0 >> 4] * 256 + ix_s[wv][1][t0 & 15]; }
    if (w1) { e1 = __expf(vc1 - Tf); es += e1; id1 = ix_s[wv][0][t1 >> 4] * 256 + ix_s[wv][1][t1 & 15]; }
    if (w2) { e2 = __expf(vc2 - Tf); es += e2; id2 = ix_s[wv][0][t2 >> 4] * 256 + ix_s[wv][1][t2 & 15]; }
    if (w3) { e3 = __expf(vc3 - Tf); es += e3; id3 = ix_s[wv][0][t3 >> 4] * 256 + ix_s[wv][1][t3 & 15]; }
    for (int s = 1; s < 64; s <<= 1) es += __shfl_xor(es, s);
    float inv = 1.f / es;

    int off = ((c * 1024 + n) * 8 + h) * 16;
    if (w0) { wcoef[off + q0] = e0 * inv; widx[off + q0] = id0; }
    if (w1) { wcoef[off + q1] = e1 * inv; widx[off + q1] = id1; }
    if (w2) { wcoef[off + q2] = e2 * inv; widx[off + q2] = id2; }
    if (w3) { wcoef[off + q3] = e3 * inv; widx[off + q3] = id3; }
}

// ---------------- Kernel 3 (bf16 tables): gather experts, gelu, weighted mix ----------------
__global__ __launch_bounds__(256) void k3_experts_bf16(const float* __restrict__ x,
                                                       const unsigned short* __restrict__ wd,
                                                       const unsigned short* __restrict__ wu,
                                                       const int* __restrict__ widx,
                                                       const float* __restrict__ wcoef,
                                                       float* __restrict__ out) {
    int bid = blockIdx.x;
    int c = bid >> 10, n = bid & 1023;
    int t = threadIdx.x, wv = t >> 6, ln = t & 63;
    __shared__ float wacc[4][512];

    const float* xrow = &x[(c * 1024 + n) * 512];
    float xr[8], oacc[8];
    {
        float4 xa = *(const float4*)&xrow[ln * 8];
        float4 xb = *(const float4*)&xrow[ln * 8 + 4];
        xr[0] = xa.x; xr[1] = xa.y; xr[2] = xa.z; xr[3] = xa.w;
        xr[4] = xb.x; xr[5] = xb.y; xr[6] = xb.z; xr[7] = xb.w;
    }
#pragma unroll
    for (int j = 0; j < 8; ++j) oacc[j] = 0.f;

    const int base = (c * 1024 + n) * 128;
    for (int e = wv * 32; e < wv * 32 + 32; ++e) {
        int   idx = widx[base + e];
        float wgt = wcoef[base + e];
        uint4 dv = *(const uint4*)&wd[(size_t)idx * 512 + ln * 8];
        float part = bflo(dv.x) * xr[0] + bfhi(dv.x) * xr[1]
                   + bflo(dv.y) * xr[2] + bfhi(dv.y) * xr[3]
                   + bflo(dv.z) * xr[4] + bfhi(dv.z) * xr[5]
                   + bflo(dv.w) * xr[6] + bfhi(dv.w) * xr[7];
        for (int s = 1; s < 64; s <<= 1) part += __shfl_xor(part, s);
        float hv = part;
        float coef = 0.5f * hv * (1.f + erff(hv * 0.70710678118654752f)) * wgt;
        uint4 uv = *(const uint4*)&wu[(size_t)idx * 512 + ln * 8];
        oacc[0] += coef * bflo(uv.x); oacc[1] += coef * bfhi(uv.x);
        oacc[2] += coef * bflo(uv.y); oacc[3] += coef * bfhi(uv.y);
        oacc[4] += coef * bflo(uv.z); oacc[5] += coef * bfhi(uv.z);
        oacc[6] += coef * bflo(uv.w); oacc[7] += coef * bfhi(uv.w);
    }

#pragma unroll
    for (int j = 0; j < 8; ++j) wacc[wv][ln * 8 + j] = oacc[j];
    __syncthreads();

    float* orow = &out[(c * 1024 + n) * 512];
    for (int d = t; d < 512; d += 256)
        orow[d] = wacc[0][d] + wacc[1][d] + wacc[2][d] + wacc[3][d];
}

// ---------------- Kernel 3 (f32 fallback) ----------------
__global__ __launch_bounds__(256) void k3_experts_f32(const float* __restrict__ x,
                                                      const float* __restrict__ w_down,
                                                      const float* __restrict__ w_up,
                                                      const int* __restrict__ widx,
                                                      const float* __restrict__ wcoef,
                                                      float* __restrict__ out) {
    int bid = blockIdx.x;
    int c = bid >> 10, n = bid & 1023;
    int t = threadIdx.x, wv = t >> 6, ln = t & 63;
    __shared__ float wacc[4][512];

    const float* xrow = &x[(c * 1024 + n) * 512];
    float xr[8], oacc[8];
    {
        float4 xa = *(const float4*)&xrow[ln * 8];
        float4 xb = *(const float4*)&xrow[ln * 8 + 4];
        xr[0] = xa.x; xr[1] = xa.y; xr[2] = xa.z; xr[3] = xa.w;
        xr[4] = xb.x; xr[5] = xb.y; xr[6] = xb.z; xr[7] = xb.w;
    }
#pragma unroll
    for (int j = 0; j < 8; ++j) oacc[j] = 0.f;

    const int base = (c * 1024 + n) * 128;
    for (int e = wv * 32; e < wv * 32 + 32; ++e) {
        int   idx = widx[base + e];
        float wgt = wcoef[base + e];
        const float* dr = &w_down[(long)idx * 512 + ln * 8];
        float4 da = *(const float4*)&dr[0];
        float4 db = *(const float4*)&dr[4];
        float part = da.x * xr[0] + da.y * xr[1] + da.z * xr[2] + da.w * xr[3]
                   + db.x * xr[4] + db.y * xr[5] + db.z * xr[6] + db.w * xr[7];
        for (int s = 1; s < 64; s <<= 1) part += __shfl_xor(part, s);
        float hv = part;
        float coef = 0.5f * hv * (1.f + erff(hv * 0.70710678118654752f)) * wgt;
        const float* ur = &w_up[(long)idx * 512 + ln * 8];
        float4 ua = *(const float4*)&ur[0];
        float4 ub = *(const float4*)&ur[4];
        oacc[0] += coef * ua.x; oacc[1] += coef * ua.y; oacc[2] += coef * ua.z; oacc[3] += coef * ua.w;
        oacc[4] += coef * ub.x; oacc[5] += coef * ub.y; oacc[6] += coef * ub.z; oacc[7] += coef * ub.w;
    }
#pragma unroll
    for (int j = 0; j < 8; ++j) wacc[wv][ln * 8 + j] = oacc[j];
    __syncthreads();

    float* orow = &out[(c * 1024 + n) * 512];
    for (int d = t; d < 512; d += 256)
        orow[d] = wacc[0][d] + wacc[1][d] + wacc[2][d] + wacc[3][d];
}

extern "C" void kernel_launch(void* const* d_in, const int* in_sizes, int n_in,
                              void* d_out, int out_size, void* d_ws, size_t ws_size,
                              hipStream_t stream) {
    const float* x      = (const float*)d_in[0];
    const float* Wq     = (const float*)d_in[1];
    const float* keys   = (const float*)d_in[2];
    const float* w_down = (const float*)d_in[3];
    const float* w_up   = (const float*)d_in[4];
    float* out = (float*)d_out;

    char* ws = (char*)d_ws;
    size_t off = 0;
    float* S     = (float*)(ws + off); off += 2048UL * 4096 * 4;       // 32 MiB (2 planes of 1024x4096)
    int*   widx  = (int*)(ws + off);   off += 262144UL * 4;            // 1 MiB
    float* wcoef = (float*)(ws + off); off += 262144UL * 4;            // 1 MiB
    float* K2    = (float*)(ws + off); off += 2UL * 4096 * 512 * 4;    // 16 MiB
    unsigned short* wd16 = (unsigned short*)(ws + off); off += 65536UL * 512 * 2; // 64 MiB
    unsigned short* wu16 = (unsigned short*)(ws + off); off += 65536UL * 512 * 2; // 64 MiB
    bool use_bf16 = (ws_size >= off);

    kK2<<<dim3(4, 32, 2), 256, 0, stream>>>(keys, Wq, K2);
    kS_gemm<<<dim3(32, 8, 2), 256, 0, stream>>>(x, K2, S);
    k2_topk<<<4096, 256, 0, stream>>>(S, widx, wcoef);
    if (use_bf16) {
        k_conv<<<2048, 256, 0, stream>>>(w_down, wd16, 65536 * 512 / 8);
        k_conv<<<2048, 256, 0, stream>>>(w_up,   wu16, 65536 * 512 / 8);
        k3_experts_bf16<<<2048, 256, 0, stream>>>(x, wd16, wu16, widx, wcoef, out);
    } else {
        k3_experts_f32<<<2048, 256, 0, stream>>>(x, w_down, w_up, widx, wcoef, out);
    }
}

// Round 17
// 345.423 us; speedup vs baseline: 1.2420x; 1.0055x over previous
//
#include <hip/hip_runtime.h>
#include <hip/hip_bf16.h>
#include <math.h>

__device__ __forceinline__ unsigned f2u(float f) {
    unsigned b = __float_as_uint(f);
    return b ^ ((unsigned)((int)b >> 31) | 0x80000000u);
}
__device__ __forceinline__ float u2f(unsigned u) {
    unsigned b = (u & 0x80000000u) ? (u ^ 0x80000000u) : ~u;
    return __uint_as_float(b);
}
__device__ __forceinline__ unsigned short f2bf(float f) {   // round-to-nearest-even
    unsigned b = __float_as_uint(f);
    return (unsigned short)((b + 0x7FFFu + ((b >> 16) & 1u)) >> 16);
}
__device__ __forceinline__ float bflo(unsigned u) { return __uint_as_float(u << 16); }
__device__ __forceinline__ float bfhi(unsigned u) { return __uint_as_float(u & 0xFFFF0000u); }

// wave-level exact k=16 radix select over 256 values (4 per lane).
__device__ __forceinline__ void radix16(unsigned u0, unsigned u1, unsigned u2, unsigned u3,
                                        unsigned& T, int& kk) {
    unsigned prefix = 0; int k = 16;
    for (int b = 31; b >= 0; --b) {
        unsigned hi = (prefix >> b) | 1u;
        int cnt = __popcll(__ballot((u0 >> b) == hi))
                + __popcll(__ballot((u1 >> b) == hi))
                + __popcll(__ballot((u2 >> b) == hi))
                + __popcll(__ballot((u3 >> b) == hi));
        if (cnt >= k) prefix |= (1u << b); else k -= cnt;
    }
    T = prefix; kk = k;
}

// ---------------- Kernel: f32 -> bf16 table conversion (streaming) ----------------
__global__ __launch_bounds__(256) void k_conv(const float* __restrict__ src,
                                              unsigned short* __restrict__ dst, int n8) {
    int tid = blockIdx.x * 256 + threadIdx.x;
    int stride = gridDim.x * 256;
    for (int i = tid; i < n8; i += stride) {
        float4 a = *(const float4*)&src[(size_t)i * 8];
        float4 b = *(const float4*)&src[(size_t)i * 8 + 4];
        uint4 o;
        o.x = (unsigned)f2bf(a.x) | ((unsigned)f2bf(a.y) << 16);
        o.y = (unsigned)f2bf(a.z) | ((unsigned)f2bf(a.w) << 16);
        o.z = (unsigned)f2bf(b.x) | ((unsigned)f2bf(b.y) << 16);
        o.w = (unsigned)f2bf(b.z) | ((unsigned)f2bf(b.w) << 16);
        *(uint4*)&dst[(size_t)i * 8] = o;
    }
}

// ---------------- Kernel K2: fold keys into Wq ----------------
// K2[p][r = c*2048 + h*256 + k][d] = sum_dk keys[((h*256+k)*2+p)*256+dk] * Wq[(c*2048+h*256+dk)*512 + d]
// Conflict-free column map: thread owns cols tx*4..+3 and 64+tx*4..+3.
__global__ __launch_bounds__(256) void kK2(const float* __restrict__ keys,
                                           const float* __restrict__ Wq,
                                           float* __restrict__ K2) {
    __shared__ float As[16][128];
    __shared__ float Bs[16][128];
    int t  = threadIdx.x;
    int tx = t & 15, ty = t >> 4;
    int p = blockIdx.z;
    int ktile = blockIdx.y & 1, ch = blockIdx.y >> 1;
    int h = ch & 7, c = ch >> 3;
    int m0 = ktile * 128;
    int n0 = blockIdx.x * 128;
    const float* kb = keys + ((size_t)(h * 256 + m0) * 2 + p) * 256;
    const float* wb = Wq + (size_t)(c * 2048 + h * 256) * 512;
    float acc[8][8] = {};
    for (int k0 = 0; k0 < 256; k0 += 16) {
#pragma unroll
        for (int i = 0; i < 2; ++i) {
            int u   = t * 2 + i;
            int row = u >> 2;
            int kc  = (u & 3) << 2;
            float4 av = *(const float4*)&kb[(size_t)row * 512 + k0 + kc];
            As[kc + 0][row] = av.x; As[kc + 1][row] = av.y; As[kc + 2][row] = av.z; As[kc + 3][row] = av.w;
            int v = u;
            int dkrow = v >> 5;
            int dcol  = (v & 31) << 2;
            float4 bv = *(const float4*)&wb[(size_t)(k0 + dkrow) * 512 + n0 + dcol];
            *(float4*)&Bs[dkrow][dcol] = bv;
        }
        __syncthreads();
#pragma unroll
        for (int kk = 0; kk < 16; ++kk) {
            float4 a0 = *(const float4*)&As[kk][ty * 8];
            float4 a1 = *(const float4*)&As[kk][ty * 8 + 4];
            float4 b0 = *(const float4*)&Bs[kk][tx * 4];
            float4 b1 = *(const float4*)&Bs[kk][tx * 4 + 64];
            float a[8] = {a0.x, a0.y, a0.z, a0.w, a1.x, a1.y, a1.z, a1.w};
            float b[8] = {b0.x, b0.y, b0.z, b0.w, b1.x, b1.y, b1.z, b1.w};
#pragma unroll
            for (int i = 0; i < 8; ++i)
#pragma unroll
                for (int j = 0; j < 8; ++j) acc[i][j] += a[i] * b[j];
        }
        __syncthreads();
    }
    float* Cp = K2 + (size_t)p * 4096 * 512;
#pragma unroll
    for (int i = 0; i < 8; ++i) {
        int r = c * 2048 + h * 256 + m0 + ty * 8 + i;
        float4 o0; o0.x = acc[i][0]; o0.y = acc[i][1]; o0.z = acc[i][2]; o0.w = acc[i][3];
        float4 o1; o1.x = acc[i][4]; o1.y = acc[i][5]; o1.z = acc[i][6]; o1.w = acc[i][7];
        *(float4*)&Cp[(size_t)r * 512 + n0 + tx * 4]      = o0;
        *(float4*)&Cp[(size_t)r * 512 + n0 + 64 + tx * 4] = o1;
    }
}

// ---------------- Kernel S: S[p] = x[p] @ K2[p]^T ----------------
// Conflict-free column map: thread owns cols tx*4..+3 and 64+tx*4..+3.
__global__ __launch_bounds__(256) void kS_gemm(const float* __restrict__ x,
                                               const float* __restrict__ K2,
                                               float* __restrict__ S) {
    __shared__ float As[16][128];
    __shared__ float Bs[16][128];
    int t  = threadIdx.x;
    int tx = t & 15, ty = t >> 4;
    int p  = blockIdx.z;
    int m0 = blockIdx.y * 128, n0 = blockIdx.x * 128;
    const float* A = x  + (size_t)p * 1024 * 512;
    const float* B = K2 + (size_t)p * 4096 * 512;
    float* C = S + (size_t)p * 1024 * 4096;
    float acc[8][8] = {};
    for (int k0 = 0; k0 < 512; k0 += 16) {
#pragma unroll
        for (int i = 0; i < 2; ++i) {
            int u   = t * 2 + i;
            int row = u >> 2;
            int kc  = (u & 3) << 2;
            float4 av = *(const float4*)&A[(size_t)(m0 + row) * 512 + k0 + kc];
            float4 bv = *(const float4*)&B[(size_t)(n0 + row) * 512 + k0 + kc];
            As[kc + 0][row] = av.x; As[kc + 1][row] = av.y; As[kc + 2][row] = av.z; As[kc + 3][row] = av.w;
            Bs[kc + 0][row] = bv.x; Bs[kc + 1][row] = bv.y; Bs[kc + 2][row] = bv.z; Bs[kc + 3][row] = bv.w;
        }
        __syncthreads();
#pragma unroll
        for (int kk = 0; kk < 16; ++kk) {
            float4 a0 = *(const float4*)&As[kk][ty * 8];
            float4 a1 = *(const float4*)&As[kk][ty * 8 + 4];
            float4 b0 = *(const float4*)&Bs[kk][tx * 4];
            float4 b1 = *(const float4*)&Bs[kk][tx * 4 + 64];
            float a[8] = {a0.x, a0.y, a0.z, a0.w, a1.x, a1.y, a1.z, a1.w};
            float b[8] = {b0.x, b0.y, b0.z, b0.w, b1.x, b1.y, b1.z, b1.w};
#pragma unroll
            for (int i = 0; i < 8; ++i)
#pragma unroll
                for (int j = 0; j < 8; ++j) acc[i][j] += a[i] * b[j];
        }
        __syncthreads();
    }
#pragma unroll
    for (int i = 0; i < 8; ++i) {
        int m = m0 + ty * 8 + i;
        float4 o0; o0.x = acc[i][0]; o0.y = acc[i][1]; o0.z = acc[i][2]; o0.w = acc[i][3];
        float4 o1; o1.x = acc[i][4]; o1.y = acc[i][5]; o1.z = acc[i][6]; o1.w = acc[i][7];
        *(float4*)&C[(size_t)m * 4096 + n0 + tx * 4]      = o0;
        *(float4*)&C[(size_t)m * 4096 + n0 + 64 + tx * 4] = o1;
    }
}

// ---------------- Kernel topk: radix top16 x2 + combine + top16 + softmax ----------------
__global__ __launch_bounds__(256) void k2_topk(const float* __restrict__ S,
                                               int* __restrict__ widx,
                                               float* __restrict__ wcoef) {
    __shared__ float sx_s[4][2][16];
    __shared__ int   ix_s[4][2][16];

    int t = threadIdx.x;
    int wv = t >> 6, ln = t & 63;
    int task = blockIdx.x * 4 + wv;
    int c = task >> 13;
    int n = (task >> 3) & 1023;
    int h = task & 7;
    unsigned long long lt = (1ull << ln) - 1ull;

    const float* s0p = S + (size_t)n * 4096 + c * 2048 + h * 256 + ln * 4;
    float4 s0 = *(const float4*)&s0p[0];
    float4 s1 = *(const float4*)&s0p[1024UL * 4096];

#define TK_HALF(PIDX, V)                                                          \
    {                                                                             \
        unsigned u0 = f2u(V.x), u1 = f2u(V.y), u2 = f2u(V.z), u3 = f2u(V.w);      \
        unsigned T; int kk;                                                       \
        radix16(u0, u1, u2, u3, T, kk);                                           \
        int base = 0;                                                             \
        { unsigned long long m = __ballot(u0 > T);                                \
          if (u0 > T) { int pos = base + __popcll(m & lt);                        \
              sx_s[wv][PIDX][pos] = V.x; ix_s[wv][PIDX][pos] = ln * 4 + 0; }      \
          base += __popcll(m); }                                                  \
        { unsigned long long m = __ballot(u1 > T);                                \
          if (u1 > T) { int pos = base + __popcll(m & lt);                        \
              sx_s[wv][PIDX][pos] = V.y; ix_s[wv][PIDX][pos] = ln * 4 + 1; }      \
          base += __popcll(m); }                                                  \
        { unsigned long long m = __ballot(u2 > T);                                \
          if (u2 > T) { int pos = base + __popcll(m & lt);                        \
              sx_s[wv][PIDX][pos] = V.z; ix_s[wv][PIDX][pos] = ln * 4 + 2; }      \
          base += __popcll(m); }                                                  \
        { unsigned long long m = __ballot(u3 > T);                                \
          if (u3 > T) { int pos = base + __popcll(m & lt);                        \
              sx_s[wv][PIDX][pos] = V.w; ix_s[wv][PIDX][pos] = ln * 4 + 3; }      \
          base += __popcll(m); }                                                  \
        { unsigned long long m = __ballot(u0 == T); int r = __popcll(m & lt);     \
          if ((u0 == T) && r < kk) { sx_s[wv][PIDX][base + r] = V.x;              \
              ix_s[wv][PIDX][base + r] = ln * 4 + 0; }                            \
          int cn2 = __popcll(m); int tk = cn2 < kk ? cn2 : kk; base += tk; kk -= tk; } \
        { unsigned long long m = __ballot(u1 == T); int r = __popcll(m & lt);     \
          if ((u1 == T) && r < kk) { sx_s[wv][PIDX][base + r] = V.y;              \
              ix_s[wv][PIDX][base + r] = ln * 4 + 1; }                            \
          int cn2 = __popcll(m); int tk = cn2 < kk ? cn2 : kk; base += tk; kk -= tk; } \
        { unsigned long long m = __ballot(u2 == T); int r = __popcll(m & lt);     \
          if ((u2 == T) && r < kk) { sx_s[wv][PIDX][base + r] = V.z;              \
              ix_s[wv][PIDX][base + r] = ln * 4 + 2; }                            \
          int cn2 = __popcll(m); int tk = cn2 < kk ? cn2 : kk; base += tk; kk -= tk; } \
        { unsigned long long m = __ballot(u3 == T); int r = __popcll(m & lt);     \
          if ((u3 == T) && r < kk) { sx_s[wv][PIDX][base + r] = V.w;              \
              ix_s[wv][PIDX][base + r] = ln * 4 + 3; }                            \
          int cn2 = __popcll(m); int tk = cn2 < kk ? cn2 : kk; base += tk; kk -= tk; } \
    }
    TK_HALF(0, s0);
    TK_HALF(1, s1);
#undef TK_HALF
    __syncthreads();

    int t0 = ln, t1 = ln + 64, t2 = ln + 128, t3 = ln + 192;
    float vc0 = sx_s[wv][0][t0 >> 4] + sx_s[wv][1][t0 & 15];
    float vc1 = sx_s[wv][0][t1 >> 4] + sx_s[wv][1][t1 & 15];
    float vc2 = sx_s[wv][0][t2 >> 4] + sx_s[wv][1][t2 & 15];
    float vc3 = sx_s[wv][0][t3 >> 4] + sx_s[wv][1][t3 & 15];
    unsigned u0 = f2u(vc0), u1 = f2u(vc1), u2 = f2u(vc2), u3 = f2u(vc3);
    unsigned T; int kk;
    radix16(u0, u1, u2, u3, T, kk);
    float Tf = u2f(T);

    bool w0 = u0 > T, w1 = u1 > T, w2 = u2 > T, w3 = u3 > T;
    int q0 = 0, q1 = 0, q2 = 0, q3 = 0;
    int base = 0;
    { unsigned long long m = __ballot(w0); q0 = base + __popcll(m & lt); base += __popcll(m); }
    { unsigned long long m = __ballot(w1); q1 = base + __popcll(m & lt); base += __popcll(m); }
    { unsigned long long m = __ballot(w2); q2 = base + __popcll(m & lt); base += __popcll(m); }
    { unsigned long long m = __ballot(w3); q3 = base + __popcll(m & lt); base += __popcll(m); }
#define CMB_EQ(UJ, WJ, QJ) { unsigned long long m = __ballot(UJ == T);          \
    int r = __popcll(m & lt);                                                   \
    if ((UJ == T) && r < kk) { WJ = true; QJ = base + r; }                      \
    int cn2 = __popcll(m); int tk = cn2 < kk ? cn2 : kk;                        \
    base += tk; kk -= tk; }
    CMB_EQ(u0, w0, q0); CMB_EQ(u1, w1, q1); CMB_EQ(u2, w2, q2); CMB_EQ(u3, w3, q3);
#undef CMB_EQ

    float e0 = 0.f, e1 = 0.f, e2 = 0.f, e3 = 0.f;
    int id0 = 0, id1 = 0, id2 = 0, id3 = 0;
    float es = 0.f;
    if (w0) { e0 = __expf(vc0 - Tf); es += e0; id0 = ix_s[wv][0][t0 >> 4] * 256 + ix_s[wv][1][t0 & 15]; }
    if (w1) { e1 = __expf(vc1 - Tf); es += e1; id1 = ix_s[wv][0][t1 >> 4] * 256 + ix_s[wv][1][t1 & 15]; }
    if (w2) { e2 = __expf(vc2 - Tf); es += e2; id2 = ix_s[wv][0][t2 >> 4] * 256 + ix_s[wv][1][t2 & 15]; }
    if (w3) { e3 = __expf(vc3 - Tf); es += e3; id3 = ix_s[wv][0][t3 >> 4] * 256 + ix_s[wv][1][t3 & 15]; }
    for (int s = 1; s < 64; s <<= 1) es += __shfl_xor(es, s);
    float inv = 1.f / es;

    int off = ((c * 1024 + n) * 8 + h) * 16;
    if (w0) { wcoef[off + q0] = e0 * inv; widx[off + q0] = id0; }
    if (w1) { wcoef[off + q1] = e1 * inv; widx[off + q1] = id1; }
    if (w2) { wcoef[off + q2] = e2 * inv; widx[off + q2] = id2; }
    if (w3) { wcoef[off + q3] = e3 * inv; widx[off + q3] = id3; }
}

// ---------------- Kernel 3 (bf16 tables): gather experts, gelu, weighted mix ----------------
__global__ __launch_bounds__(256) void k3_experts_bf16(const float* __restrict__ x,
                                                       const unsigned short* __restrict__ wd,
                                                       const unsigned short* __restrict__ wu,
                                                       const int* __restrict__ widx,
                                                       const float* __restrict__ wcoef,
                                                       float* __restrict__ out) {
    int bid = blockIdx.x;
    int c = bid >> 10, n = bid & 1023;
    int t = threadIdx.x, wv = t >> 6, ln = t & 63;
    __shared__ float wacc[4][512];

    const float* xrow = &x[(c * 1024 + n) * 512];
    float xr[8], oacc[8];
    {
        float4 xa = *(const float4*)&xrow[ln * 8];
        float4 xb = *(const float4*)&xrow[ln * 8 + 4];
        xr[0] = xa.x; xr[1] = xa.y; xr[2] = xa.z; xr[3] = xa.w;
        xr[4] = xb.x; xr[5] = xb.y; xr[6] = xb.z; xr[7] = xb.w;
    }
#pragma unroll
    for (int j = 0; j < 8; ++j) oacc[j] = 0.f;

    const int base = (c * 1024 + n) * 128;
    for (int e = wv * 32; e < wv * 32 + 32; ++e) {
        int   idx = widx[base + e];
        float wgt = wcoef[base + e];
        uint4 dv = *(const uint4*)&wd[(size_t)idx * 512 + ln * 8];
        float part = bflo(dv.x) * xr[0] + bfhi(dv.x) * xr[1]
                   + bflo(dv.y) * xr[2] + bfhi(dv.y) * xr[3]
                   + bflo(dv.z) * xr[4] + bfhi(dv.z) * xr[5]
                   + bflo(dv.w) * xr[6] + bfhi(dv.w) * xr[7];
        for (int s = 1; s < 64; s <<= 1) part += __shfl_xor(part, s);
        float hv = part;
        float coef = 0.5f * hv * (1.f + erff(hv * 0.70710678118654752f)) * wgt;
        uint4 uv = *(const uint4*)&wu[(size_t)idx * 512 + ln * 8];
        oacc[0] += coef * bflo(uv.x); oacc[1] += coef * bfhi(uv.x);
        oacc[2] += coef * bflo(uv.y); oacc[3] += coef * bfhi(uv.y);
        oacc[4] += coef * bflo(uv.z); oacc[5] += coef * bfhi(uv.z);
        oacc[6] += coef * bflo(uv.w); oacc[7] += coef * bfhi(uv.w);
    }

#pragma unroll
    for (int j = 0; j < 8; ++j) wacc[wv][ln * 8 + j] = oacc[j];
    __syncthreads();

    float* orow = &out[(c * 1024 + n) * 512];
    for (int d = t; d < 512; d += 256)
        orow[d] = wacc[0][d] + wacc[1][d] + wacc[2][d] + wacc[3][d];
}

// ---------------- Kernel 3 (f32 fallback) ----------------
__global__ __launch_bounds__(256) void k3_experts_f32(const float* __restrict__ x,
                                                      const float* __restrict__ w_down,
                                                      const float* __restrict__ w_up,
                                                      const int* __restrict__ widx,
                                                      const float* __restrict__ wcoef,
                                                      float* __restrict__ out) {
    int bid = blockIdx.x;
    int c = bid >> 10, n = bid & 1023;
    int t = threadIdx.x, wv = t >> 6, ln = t & 63;
    __shared__ float wacc[4][512];

    const float* xrow = &x[(c * 1024 + n) * 512];
    float xr[8], oacc[8];
    {
        float4 xa = *(const float4*)&xrow[ln * 8];
        float4 xb = *(const float4*)&xrow[ln * 8 + 4];
        xr[0] = xa.x; xr[1] = xa.y; xr[2] = xa.z; xr[3] = xa.w;
        xr[4] = xb.x; xr[5] = xb.y; xr[6] = xb.z; xr[7] = xb.w;
    }
#pragma unroll
    for (int j = 0; j < 8; ++j) oacc[j] = 0.f;

    const int base = (c * 1024 + n) * 128;
    for (int e = wv * 32; e < wv * 32 + 32; ++e) {
        int   idx = widx[base + e];
        float wgt = wcoef[base + e];
        const float* dr = &w_down[(long)idx * 512 + ln * 8];
        float4 da = *(const float4*)&dr[0];
        float4 db = *(const float4*)&dr[4];
        float part = da.x * xr[0] + da.y * xr[1] + da.z * xr[2] + da.w * xr[3]
                   + db.x * xr[4] + db.y * xr[5] + db.z * xr[6] + db.w * xr[7];
        for (int s = 1; s < 64; s <<= 1) part += __shfl_xor(part, s);
        float hv = part;
        float coef = 0.5f * hv * (1.f + erff(hv * 0.70710678118654752f)) * wgt;
        const float* ur = &w_up[(long)idx * 512 + ln * 8];
        float4 ua = *(const float4*)&ur[0];
        float4 ub = *(const float4*)&ur[4];
        oacc[0] += coef * ua.x; oacc[1] += coef * ua.y; oacc[2] += coef * ua.z; oacc[3] += coef * ua.w;
        oacc[4] += coef * ub.x; oacc[5] += coef * ub.y; oacc[6] += coef * ub.z; oacc[7] += coef * ub.w;
    }
#pragma unroll
    for (int j = 0; j < 8; ++j) wacc[wv][ln * 8 + j] = oacc[j];
    __syncthreads();

    float* orow = &out[(c * 1024 + n) * 512];
    for (int d = t; d < 512; d += 256)
        orow[d] = wacc[0][d] + wacc[1][d] + wacc[2][d] + wacc[3][d];
}

extern "C" void kernel_launch(void* const* d_in, const int* in_sizes, int n_in,
                              void* d_out, int out_size, void* d_ws, size_t ws_size,
                              hipStream_t stream) {
    const float* x      = (const float*)d_in[0];
    const float* Wq     = (const float*)d_in[1];
    const float* keys   = (const float*)d_in[2];
    const float* w_down = (const float*)d_in[3];
    const float* w_up   = (const float*)d_in[4];
    float* out = (float*)d_out;

    char* ws = (char*)d_ws;
    size_t off = 0;
    float* S     = (float*)(ws + off); off += 2048UL * 4096 * 4;       // 32 MiB
    int*   widx  = (int*)(ws + off);   off += 262144UL * 4;            // 1 MiB
    float* wcoef = (float*)(ws + off); off += 262144UL * 4;            // 1 MiB
    float* K2    = (float*)(ws + off); off += 2UL * 4096 * 512 * 4;    // 16 MiB
    unsigned short* wd16 = (unsigned short*)(ws + off); off += 65536UL * 512 * 2; // 64 MiB
    unsigned short* wu16 = (unsigned short*)(ws + off); off += 65536UL * 512 * 2; // 64 MiB
    bool use_bf16 = (ws_size >= off);

    kK2<<<dim3(4, 32, 2), 256, 0, stream>>>(keys, Wq, K2);
    kS_gemm<<<dim3(32, 8, 2), 256, 0, stream>>>(x, K2, S);
    k2_topk<<<4096, 256, 0, stream>>>(S, widx, wcoef);
    if (use_bf16) {
        k_conv<<<2048, 256, 0, stream>>>(w_down, wd16, 65536 * 512 / 8);
        k_conv<<<2048, 256, 0, stream>>>(w_up,   wu16, 65536 * 512 / 8);
        k3_experts_bf16<<<2048, 256, 0, stream>>>(x, wd16, wu16, widx, wcoef, out);
    } else {
        k3_experts_f32<<<2048, 256, 0, stream>>>(x, w_down, w_up, widx, wcoef, out);
    }
}

// Round 18
// 294.396 us; speedup vs baseline: 1.4572x; 1.1733x over previous
//
#include <hip/hip_runtime.h>
#include <hip/hip_bf16.h>
#include <math.h>

typedef __attribute__((ext_vector_type(8))) short bf16x8;
typedef __attribute__((ext_vector_type(4))) float f32x4;

__device__ __forceinline__ unsigned f2u(float f) {
    unsigned b = __float_as_uint(f);
    return b ^ ((unsigned)((int)b >> 31) | 0x80000000u);
}
__device__ __forceinline__ float u2f(unsigned u) {
    unsigned b = (u & 0x80000000u) ? (u ^ 0x80000000u) : ~u;
    return __uint_as_float(b);
}
__device__ __forceinline__ unsigned short f2bf(float f) {   // round-to-nearest-even
    unsigned b = __float_as_uint(f);
    return (unsigned short)((b + 0x7FFFu + ((b >> 16) & 1u)) >> 16);
}
__device__ __forceinline__ float bflo(unsigned u) { return __uint_as_float(u << 16); }
__device__ __forceinline__ float bfhi(unsigned u) { return __uint_as_float(u & 0xFFFF0000u); }

// wave-level exact k=16 radix select over 256 values (4 per lane).
__device__ __forceinline__ void radix16(unsigned u0, unsigned u1, unsigned u2, unsigned u3,
                                        unsigned& T, int& kk) {
    unsigned prefix = 0; int k = 16;
    for (int b = 31; b >= 0; --b) {
        unsigned hi = (prefix >> b) | 1u;
        int cnt = __popcll(__ballot((u0 >> b) == hi))
                + __popcll(__ballot((u1 >> b) == hi))
                + __popcll(__ballot((u2 >> b) == hi))
                + __popcll(__ballot((u3 >> b) == hi));
        if (cnt >= k) prefix |= (1u << b); else k -= cnt;
    }
    T = prefix; kk = k;
}

// ---------------- Kernel: f32 -> bf16 conversion (streaming) ----------------
__global__ __launch_bounds__(256) void k_conv(const float* __restrict__ src,
                                              unsigned short* __restrict__ dst, int n8) {
    int tid = blockIdx.x * 256 + threadIdx.x;
    int stride = gridDim.x * 256;
    for (int i = tid; i < n8; i += stride) {
        float4 a = *(const float4*)&src[(size_t)i * 8];
        float4 b = *(const float4*)&src[(size_t)i * 8 + 4];
        uint4 o;
        o.x = (unsigned)f2bf(a.x) | ((unsigned)f2bf(a.y) << 16);
        o.y = (unsigned)f2bf(a.z) | ((unsigned)f2bf(a.w) << 16);
        o.z = (unsigned)f2bf(b.x) | ((unsigned)f2bf(b.y) << 16);
        o.w = (unsigned)f2bf(b.z) | ((unsigned)f2bf(b.w) << 16);
        *(uint4*)&dst[(size_t)i * 8] = o;
    }
}

// ---------------- Kernel K2: fold keys into Wq, output bf16 ----------------
// K2b[p][r = c*2048 + h*256 + k][d] = bf16( sum_dk keys[((h*256+k)*2+p)*256+dk] * Wq[(c*2048+h*256+dk)*512 + d] )
__global__ __launch_bounds__(256) void kK2(const float* __restrict__ keys,
                                           const float* __restrict__ Wq,
                                           unsigned short* __restrict__ K2b) {
    __shared__ float As[16][128];
    __shared__ float Bs[16][128];
    int t  = threadIdx.x;
    int tx = t & 15, ty = t >> 4;
    int p = blockIdx.z;
    int ktile = blockIdx.y & 1, ch = blockIdx.y >> 1;
    int h = ch & 7, c = ch >> 3;
    int m0 = ktile * 128;
    int n0 = blockIdx.x * 128;
    const float* kb = keys + ((size_t)(h * 256 + m0) * 2 + p) * 256;
    const float* wb = Wq + (size_t)(c * 2048 + h * 256) * 512;
    float acc[8][8] = {};
    for (int k0 = 0; k0 < 256; k0 += 16) {
#pragma unroll
        for (int i = 0; i < 2; ++i) {
            int u   = t * 2 + i;
            int row = u >> 2;
            int kc  = (u & 3) << 2;
            float4 av = *(const float4*)&kb[(size_t)row * 512 + k0 + kc];
            As[kc + 0][row] = av.x; As[kc + 1][row] = av.y; As[kc + 2][row] = av.z; As[kc + 3][row] = av.w;
            int v = u;
            int dkrow = v >> 5;
            int dcol  = (v & 31) << 2;
            float4 bv = *(const float4*)&wb[(size_t)(k0 + dkrow) * 512 + n0 + dcol];
            *(float4*)&Bs[dkrow][dcol] = bv;
        }
        __syncthreads();
#pragma unroll
        for (int kk = 0; kk < 16; ++kk) {
            float4 a0 = *(const float4*)&As[kk][ty * 8];
            float4 a1 = *(const float4*)&As[kk][ty * 8 + 4];
            float4 b0 = *(const float4*)&Bs[kk][tx * 4];
            float4 b1 = *(const float4*)&Bs[kk][tx * 4 + 64];
            float a[8] = {a0.x, a0.y, a0.z, a0.w, a1.x, a1.y, a1.z, a1.w};
            float b[8] = {b0.x, b0.y, b0.z, b0.w, b1.x, b1.y, b1.z, b1.w};
#pragma unroll
            for (int i = 0; i < 8; ++i)
#pragma unroll
                for (int j = 0; j < 8; ++j) acc[i][j] += a[i] * b[j];
        }
        __syncthreads();
    }
    unsigned short* Cp = K2b + (size_t)p * 4096 * 512;
#pragma unroll
    for (int i = 0; i < 8; ++i) {
        int r = c * 2048 + h * 256 + m0 + ty * 8 + i;
        uint2 o0, o1;
        o0.x = (unsigned)f2bf(acc[i][0]) | ((unsigned)f2bf(acc[i][1]) << 16);
        o0.y = (unsigned)f2bf(acc[i][2]) | ((unsigned)f2bf(acc[i][3]) << 16);
        o1.x = (unsigned)f2bf(acc[i][4]) | ((unsigned)f2bf(acc[i][5]) << 16);
        o1.y = (unsigned)f2bf(acc[i][6]) | ((unsigned)f2bf(acc[i][7]) << 16);
        *(uint2*)&Cp[(size_t)r * 512 + n0 + tx * 4]      = o0;
        *(uint2*)&Cp[(size_t)r * 512 + n0 + 64 + tx * 4] = o1;
    }
}

// ---------------- Kernel S (MFMA): S[p] = xb[p] @ K2b[p]^T ----------------
// Per-wave 32n x 64e tile via mfma_f32_16x16x32_bf16; fragments loaded directly
// from global row-major (A: lane l -> x[n0+(l&15)][k0+(l>>4)*8+j];
// B: lane l -> K2[e0+(l&15)][k0+(l>>4)*8+j]); no LDS, no barriers.
// Block = 4 waves stacked on n (128n x 64e). grid = (64, 8, 2).
__global__ __launch_bounds__(256) void kS_mfma(const unsigned short* __restrict__ xb,
                                               const unsigned short* __restrict__ k2b,
                                               float* __restrict__ S) {
    int t = threadIdx.x;
    int wv = t >> 6, ln = t & 63;
    int p  = blockIdx.z;
    int n0 = blockIdx.y * 128 + wv * 32;
    int e0 = blockIdx.x * 64;
    const unsigned short* A = xb  + (size_t)p * 1024 * 512;
    const unsigned short* B = k2b + (size_t)p * 4096 * 512;
    int lr = ln & 15;
    int lk = (ln >> 4) * 8;

    f32x4 acc00 = {}, acc01 = {}, acc02 = {}, acc03 = {};
    f32x4 acc10 = {}, acc11 = {}, acc12 = {}, acc13 = {};

    for (int k0 = 0; k0 < 512; k0 += 32) {
        bf16x8 a0 = *(const bf16x8*)&A[(size_t)(n0 + lr) * 512 + k0 + lk];
        bf16x8 a1 = *(const bf16x8*)&A[(size_t)(n0 + 16 + lr) * 512 + k0 + lk];
        bf16x8 b0 = *(const bf16x8*)&B[(size_t)(e0 + lr) * 512 + k0 + lk];
        bf16x8 b1 = *(const bf16x8*)&B[(size_t)(e0 + 16 + lr) * 512 + k0 + lk];
        bf16x8 b2 = *(const bf16x8*)&B[(size_t)(e0 + 32 + lr) * 512 + k0 + lk];
        bf16x8 b3 = *(const bf16x8*)&B[(size_t)(e0 + 48 + lr) * 512 + k0 + lk];
        acc00 = __builtin_amdgcn_mfma_f32_16x16x32_bf16(a0, b0, acc00, 0, 0, 0);
        acc01 = __builtin_amdgcn_mfma_f32_16x16x32_bf16(a0, b1, acc01, 0, 0, 0);
        acc02 = __builtin_amdgcn_mfma_f32_16x16x32_bf16(a0, b2, acc02, 0, 0, 0);
        acc03 = __builtin_amdgcn_mfma_f32_16x16x32_bf16(a0, b3, acc03, 0, 0, 0);
        acc10 = __builtin_amdgcn_mfma_f32_16x16x32_bf16(a1, b0, acc10, 0, 0, 0);
        acc11 = __builtin_amdgcn_mfma_f32_16x16x32_bf16(a1, b1, acc11, 0, 0, 0);
        acc12 = __builtin_amdgcn_mfma_f32_16x16x32_bf16(a1, b2, acc12, 0, 0, 0);
        acc13 = __builtin_amdgcn_mfma_f32_16x16x32_bf16(a1, b3, acc13, 0, 0, 0);
    }

    // C/D layout (verified m89): col = lane&15, row = (lane>>4)*4 + reg
    float* C = S + (size_t)p * 1024 * 4096;
    int rbase = (ln >> 4) * 4;
    int cw = ln & 15;
#define STORE_FRAG(ACC, AF, BF)                                                   \
    {                                                                             \
        _Pragma("unroll")                                                         \
        for (int r = 0; r < 4; ++r)                                               \
            C[(size_t)(n0 + (AF)*16 + rbase + r) * 4096 + e0 + (BF)*16 + cw] = ACC[r]; \
    }
    STORE_FRAG(acc00, 0, 0); STORE_FRAG(acc01, 0, 1); STORE_FRAG(acc02, 0, 2); STORE_FRAG(acc03, 0, 3);
    STORE_FRAG(acc10, 1, 0); STORE_FRAG(acc11, 1, 1); STORE_FRAG(acc12, 1, 2); STORE_FRAG(acc13, 1, 3);
#undef STORE_FRAG
}

// ---------------- Kernel topk: radix top16 x2 + combine + top16 + softmax ----------------
__global__ __launch_bounds__(256) void k2_topk(const float* __restrict__ S,
                                               int* __restrict__ widx,
                                               float* __restrict__ wcoef) {
    __shared__ float sx_s[4][2][16];
    __shared__ int   ix_s[4][2][16];

    int t = threadIdx.x;
    int wv = t >> 6, ln = t & 63;
    int task = blockIdx.x * 4 + wv;
    int c = task >> 13;
    int n = (task >> 3) & 1023;
    int h = task & 7;
    unsigned long long lt = (1ull << ln) - 1ull;

    const float* s0p = S + (size_t)n * 4096 + c * 2048 + h * 256 + ln * 4;
    float4 s0 = *(const float4*)&s0p[0];
    float4 s1 = *(const float4*)&s0p[1024UL * 4096];

#define TK_HALF(PIDX, V)                                                          \
    {                                                                             \
        unsigned u0 = f2u(V.x), u1 = f2u(V.y), u2 = f2u(V.z), u3 = f2u(V.w);      \
        unsigned T; int kk;                                                       \
        radix16(u0, u1, u2, u3, T, kk);                                           \
        int base = 0;                                                             \
        { unsigned long long m = __ballot(u0 > T);                                \
          if (u0 > T) { int pos = base + __popcll(m & lt);                        \
              sx_s[wv][PIDX][pos] = V.x; ix_s[wv][PIDX][pos] = ln * 4 + 0; }      \
          base += __popcll(m); }                                                  \
        { unsigned long long m = __ballot(u1 > T);                                \
          if (u1 > T) { int pos = base + __popcll(m & lt);                        \
              sx_s[wv][PIDX][pos] = V.y; ix_s[wv][PIDX][pos] = ln * 4 + 1; }      \
          base += __popcll(m); }                                                  \
        { unsigned long long m = __ballot(u2 > T);                                \
          if (u2 > T) { int pos = base + __popcll(m & lt);                        \
              sx_s[wv][PIDX][pos] = V.z; ix_s[wv][PIDX][pos] = ln * 4 + 2; }      \
          base += __popcll(m); }                                                  \
        { unsigned long long m = __ballot(u3 > T);                                \
          if (u3 > T) { int pos = base + __popcll(m & lt);                        \
              sx_s[wv][PIDX][pos] = V.w; ix_s[wv][PIDX][pos] = ln * 4 + 3; }      \
          base += __popcll(m); }                                                  \
        { unsigned long long m = __ballot(u0 == T); int r = __popcll(m & lt);     \
          if ((u0 == T) && r < kk) { sx_s[wv][PIDX][base + r] = V.x;              \
              ix_s[wv][PIDX][base + r] = ln * 4 + 0; }                            \
          int cn2 = __popcll(m); int tk = cn2 < kk ? cn2 : kk; base += tk; kk -= tk; } \
        { unsigned long long m = __ballot(u1 == T); int r = __popcll(m & lt);     \
          if ((u1 == T) && r < kk) { sx_s[wv][PIDX][base + r] = V.y;              \
              ix_s[wv][PIDX][base + r] = ln * 4 + 1; }                            \
          int cn2 = __popcll(m); int tk = cn2 < kk ? cn2 : kk; base += tk; kk -= tk; } \
        { unsigned long long m = __ballot(u2 == T); int r = __popcll(m & lt);     \
          if ((u2 == T) && r < kk) { sx_s[wv][PIDX][base + r] = V.z;              \
              ix_s[wv][PIDX][base + r] = ln * 4 + 2; }                            \
          int cn2 = __popcll(m); int tk = cn2 < kk ? cn2 : kk; base += tk; kk -= tk; } \
        { unsigned long long m = __ballot(u3 == T); int r = __popcll(m & lt);     \
          if ((u3 == T) && r < kk) { sx_s[wv][PIDX][base + r] = V.w;              \
              ix_s[wv][PIDX][base + r] = ln * 4 + 3; }                            \
          int cn2 = __popcll(m); int tk = cn2 < kk ? cn2 : kk; base += tk; kk -= tk; } \
    }
    TK_HALF(0, s0);
    TK_HALF(1, s1);
#undef TK_HALF
    __syncthreads();

    int t0 = ln, t1 = ln + 64, t2 = ln + 128, t3 = ln + 192;
    float vc0 = sx_s[wv][0][t0 >> 4] + sx_s[wv][1][t0 & 15];
    float vc1 = sx_s[wv][0][t1 >> 4] + sx_s[wv][1][t1 & 15];
    float vc2 = sx_s[wv][0][t2 >> 4] + sx_s[wv][1][t2 & 15];
    float vc3 = sx_s[wv][0][t3 >> 4] + sx_s[wv][1][t3 & 15];
    unsigned u0 = f2u(vc0), u1 = f2u(vc1), u2 = f2u(vc2), u3 = f2u(vc3);
    unsigned T; int kk;
    radix16(u0, u1, u2, u3, T, kk);
    float Tf = u2f(T);

    bool w0 = u0 > T, w1 = u1 > T, w2 = u2 > T, w3 = u3 > T;
    int q0 = 0, q1 = 0, q2 = 0, q3 = 0;
    int base = 0;
    { unsigned long long m = __ballot(w0); q0 = base + __popcll(m & lt); base += __popcll(m); }
    { unsigned long long m = __ballot(w1); q1 = base + __popcll(m & lt); base += __popcll(m); }
    { unsigned long long m = __ballot(w2); q2 = base + __popcll(m & lt); base += __popcll(m); }
    { unsigned long long m = __ballot(w3); q3 = base + __popcll(m & lt); base += __popcll(m); }
#define CMB_EQ(UJ, WJ, QJ) { unsigned long long m = __ballot(UJ == T);          \
    int r = __popcll(m & lt);                                                   \
    if ((UJ == T) && r < kk) { WJ = true; QJ = base + r; }                      \
    int cn2 = __popcll(m); int tk = cn2 < kk ? cn2 : kk;                        \
    base += tk; kk -= tk; }
    CMB_EQ(u0, w0, q0); CMB_EQ(u1, w1, q1); CMB_EQ(u2, w2, q2); CMB_EQ(u3, w3, q3);
#undef CMB_EQ

    float e0 = 0.f, e1 = 0.f, e2 = 0.f, e3 = 0.f;
    int id0 = 0, id1 = 0, id2 = 0, id3 = 0;
    float es = 0.f;
    if (w0) { e0 = __expf(vc0 - Tf); es += e0; id0 = ix_s[wv][0][t0 >> 4] * 256 + ix_s[wv][1][t0 & 15]; }
    if (w1) { e1 = __expf(vc1 - Tf); es += e1; id1 = ix_s[wv][0][t1 >> 4] * 256 + ix_s[wv][1][t1 & 15]; }
    if (w2) { e2 = __expf(vc2 - Tf); es += e2; id2 = ix_s[wv][0][t2 >> 4] * 256 + ix_s[wv][1][t2 & 15]; }
    if (w3) { e3 = __expf(vc3 - Tf); es += e3; id3 = ix_s[wv][0][t3 >> 4] * 256 + ix_s[wv][1][t3 & 15]; }
    for (int s = 1; s < 64; s <<= 1) es += __shfl_xor(es, s);
    float inv = 1.f / es;

    int off = ((c * 1024 + n) * 8 + h) * 16;
    if (w0) { wcoef[off + q0] = e0 * inv; widx[off + q0] = id0; }
    if (w1) { wcoef[off + q1] = e1 * inv; widx[off + q1] = id1; }
    if (w2) { wcoef[off + q2] = e2 * inv; widx[off + q2] = id2; }
    if (w3) { wcoef[off + q3] = e3 * inv; widx[off + q3] = id3; }
}

// ---------------- Kernel 3 (bf16 tables): gather experts, gelu, weighted mix ----------------
__global__ __launch_bounds__(256) void k3_experts_bf16(const float* __restrict__ x,
                                                       const unsigned short* __restrict__ wd,
                                                       const unsigned short* __restrict__ wu,
                                                       const int* __restrict__ widx,
                                                       const float* __restrict__ wcoef,
                                                       float* __restrict__ out) {
    int bid = blockIdx.x;
    int c = bid >> 10, n = bid & 1023;
    int t = threadIdx.x, wv = t >> 6, ln = t & 63;
    __shared__ float wacc[4][512];

    const float* xrow = &x[(c * 1024 + n) * 512];
    float xr[8], oacc[8];
    {
        float4 xa = *(const float4*)&xrow[ln * 8];
        float4 xb = *(const float4*)&xrow[ln * 8 + 4];
        xr[0] = xa.x; xr[1] = xa.y; xr[2] = xa.z; xr[3] = xa.w;
        xr[4] = xb.x; xr[5] = xb.y; xr[6] = xb.z; xr[7] = xb.w;
    }
#pragma unroll
    for (int j = 0; j < 8; ++j) oacc[j] = 0.f;

    const int base = (c * 1024 + n) * 128;
    for (int e = wv * 32; e < wv * 32 + 32; ++e) {
        int   idx = widx[base + e];
        float wgt = wcoef[base + e];
        uint4 dv = *(const uint4*)&wd[(size_t)idx * 512 + ln * 8];
        float part = bflo(dv.x) * xr[0] + bfhi(dv.x) * xr[1]
                   + bflo(dv.y) * xr[2] + bfhi(dv.y) * xr[3]
                   + bflo(dv.z) * xr[4] + bfhi(dv.z) * xr[5]
                   + bflo(dv.w) * xr[6] + bfhi(dv.w) * xr[7];
        for (int s = 1; s < 64; s <<= 1) part += __shfl_xor(part, s);
        float hv = part;
        float coef = 0.5f * hv * (1.f + erff(hv * 0.70710678118654752f)) * wgt;
        uint4 uv = *(const uint4*)&wu[(size_t)idx * 512 + ln * 8];
        oacc[0] += coef * bflo(uv.x); oacc[1] += coef * bfhi(uv.x);
        oacc[2] += coef * bflo(uv.y); oacc[3] += coef * bfhi(uv.y);
        oacc[4] += coef * bflo(uv.z); oacc[5] += coef * bfhi(uv.z);
        oacc[6] += coef * bflo(uv.w); oacc[7] += coef * bfhi(uv.w);
    }

#pragma unroll
    for (int j = 0; j < 8; ++j) wacc[wv][ln * 8 + j] = oacc[j];
    __syncthreads();

    float* orow = &out[(c * 1024 + n) * 512];
    for (int d = t; d < 512; d += 256)
        orow[d] = wacc[0][d] + wacc[1][d] + wacc[2][d] + wacc[3][d];
}

// ---------------- Kernel 3 (f32 fallback) ----------------
__global__ __launch_bounds__(256) void k3_experts_f32(const float* __restrict__ x,
                                                      const float* __restrict__ w_down,
                                                      const float* __restrict__ w_up,
                                                      const int* __restrict__ widx,
                                                      const float* __restrict__ wcoef,
                                                      float* __restrict__ out) {
    int bid = blockIdx.x;
    int c = bid >> 10, n = bid & 1023;
    int t = threadIdx.x, wv = t >> 6, ln = t & 63;
    __shared__ float wacc[4][512];

    const float* xrow = &x[(c * 1024 + n) * 512];
    float xr[8], oacc[8];
    {
        float4 xa = *(const float4*)&xrow[ln * 8];
        float4 xb = *(const float4*)&xrow[ln * 8 + 4];
        xr[0] = xa.x; xr[1] = xa.y; xr[2] = xa.z; xr[3] = xa.w;
        xr[4] = xb.x; xr[5] = xb.y; xr[6] = xb.z; xr[7] = xb.w;
    }
#pragma unroll
    for (int j = 0; j < 8; ++j) oacc[j] = 0.f;

    const int base = (c * 1024 + n) * 128;
    for (int e = wv * 32; e < wv * 32 + 32; ++e) {
        int   idx = widx[base + e];
        float wgt = wcoef[base + e];
        const float* dr = &w_down[(long)idx * 512 + ln * 8];
        float4 da = *(const float4*)&dr[0];
        float4 db = *(const float4*)&dr[4];
        float part = da.x * xr[0] + da.y * xr[1] + da.z * xr[2] + da.w * xr[3]
                   + db.x * xr[4] + db.y * xr[5] + db.z * xr[6] + db.w * xr[7];
        for (int s = 1; s < 64; s <<= 1) part += __shfl_xor(part, s);
        float hv = part;
        float coef = 0.5f * hv * (1.f + erff(hv * 0.70710678118654752f)) * wgt;
        const float* ur = &w_up[(long)idx * 512 + ln * 8];
        float4 ua = *(const float4*)&ur[0];
        float4 ub = *(const float4*)&ur[4];
        oacc[0] += coef * ua.x; oacc[1] += coef * ua.y; oacc[2] += coef * ua.z; oacc[3] += coef * ua.w;
        oacc[4] += coef * ub.x; oacc[5] += coef * ub.y; oacc[6] += coef * ub.z; oacc[7] += coef * ub.w;
    }
#pragma unroll
    for (int j = 0; j < 8; ++j) wacc[wv][ln * 8 + j] = oacc[j];
    __syncthreads();

    float* orow = &out[(c * 1024 + n) * 512];
    for (int d = t; d < 512; d += 256)
        orow[d] = wacc[0][d] + wacc[1][d] + wacc[2][d] + wacc[3][d];
}

extern "C" void kernel_launch(void* const* d_in, const int* in_sizes, int n_in,
                              void* d_out, int out_size, void* d_ws, size_t ws_size,
                              hipStream_t stream) {
    const float* x      = (const float*)d_in[0];
    const float* Wq     = (const float*)d_in[1];
    const float* keys   = (const float*)d_in[2];
    const float* w_down = (const float*)d_in[3];
    const float* w_up   = (const float*)d_in[4];
    float* out = (float*)d_out;

    char* ws = (char*)d_ws;
    size_t off = 0;
    float* S     = (float*)(ws + off); off += 2048UL * 4096 * 4;        // 32 MiB
    int*   widx  = (int*)(ws + off);   off += 262144UL * 4;             // 1 MiB
    float* wcoef = (float*)(ws + off); off += 262144UL * 4;             // 1 MiB
    unsigned short* K2b = (unsigned short*)(ws + off); off += 2UL * 4096 * 512 * 2; // 8 MiB
    unsigned short* xb  = (unsigned short*)(ws + off); off += 2048UL * 512 * 2;     // 2 MiB
    unsigned short* wd16 = (unsigned short*)(ws + off); off += 65536UL * 512 * 2;   // 64 MiB
    unsigned short* wu16 = (unsigned short*)(ws + off); off += 65536UL * 512 * 2;   // 64 MiB
    bool use_bf16 = (ws_size >= off);

    k_conv<<<512, 256, 0, stream>>>(x, xb, 2048 * 512 / 8);
    kK2<<<dim3(4, 32, 2), 256, 0, stream>>>(keys, Wq, K2b);
    kS_mfma<<<dim3(64, 8, 2), 256, 0, stream>>>(xb, K2b, S);
    k2_topk<<<4096, 256, 0, stream>>>(S, widx, wcoef);
    if (use_bf16) {
        k_conv<<<2048, 256, 0, stream>>>(w_down, wd16, 65536 * 512 / 8);
        k_conv<<<2048, 256, 0, stream>>>(w_up,   wu16, 65536 * 512 / 8);
        k3_experts_bf16<<<2048, 256, 0, stream>>>(x, wd16, wu16, widx, wcoef, out);
    } else {
        k3_experts_f32<<<2048, 256, 0, stream>>>(x, w_down, w_up, widx, wcoef, out);
    }
}

// Round 19
// 293.749 us; speedup vs baseline: 1.4605x; 1.0022x over previous
//
#include <hip/hip_runtime.h>
#include <hip/hip_bf16.h>
#include <math.h>

typedef __attribute__((ext_vector_type(8))) short bf16x8;
typedef __attribute__((ext_vector_type(4))) float f32x4;

__device__ __forceinline__ unsigned f2u(float f) {
    unsigned b = __float_as_uint(f);
    return b ^ ((unsigned)((int)b >> 31) | 0x80000000u);
}
__device__ __forceinline__ float u2f(unsigned u) {
    unsigned b = (u & 0x80000000u) ? (u ^ 0x80000000u) : ~u;
    return __uint_as_float(b);
}
__device__ __forceinline__ unsigned short f2bf(float f) {   // round-to-nearest-even
    unsigned b = __float_as_uint(f);
    return (unsigned short)((b + 0x7FFFu + ((b >> 16) & 1u)) >> 16);
}
__device__ __forceinline__ float bflo(unsigned u) { return __uint_as_float(u << 16); }
__device__ __forceinline__ float bfhi(unsigned u) { return __uint_as_float(u & 0xFFFF0000u); }

// wave-level exact k=16 radix select over 256 values (4 per lane).
__device__ __forceinline__ void radix16(unsigned u0, unsigned u1, unsigned u2, unsigned u3,
                                        unsigned& T, int& kk) {
    unsigned prefix = 0; int k = 16;
    for (int b = 31; b >= 0; --b) {
        unsigned hi = (prefix >> b) | 1u;
        int cnt = __popcll(__ballot((u0 >> b) == hi))
                + __popcll(__ballot((u1 >> b) == hi))
                + __popcll(__ballot((u2 >> b) == hi))
                + __popcll(__ballot((u3 >> b) == hi));
        if (cnt >= k) prefix |= (1u << b); else k -= cnt;
    }
    T = prefix; kk = k;
}

// ---------------- Kernel: f32 -> bf16 conversion (streaming, for x) ----------------
__global__ __launch_bounds__(256) void k_conv(const float* __restrict__ src,
                                              unsigned short* __restrict__ dst, int n8) {
    int tid = blockIdx.x * 256 + threadIdx.x;
    int stride = gridDim.x * 256;
    for (int i = tid; i < n8; i += stride) {
        float4 a = *(const float4*)&src[(size_t)i * 8];
        float4 b = *(const float4*)&src[(size_t)i * 8 + 4];
        uint4 o;
        o.x = (unsigned)f2bf(a.x) | ((unsigned)f2bf(a.y) << 16);
        o.y = (unsigned)f2bf(a.z) | ((unsigned)f2bf(a.w) << 16);
        o.z = (unsigned)f2bf(b.x) | ((unsigned)f2bf(b.y) << 16);
        o.w = (unsigned)f2bf(b.z) | ((unsigned)f2bf(b.w) << 16);
        *(uint4*)&dst[(size_t)i * 8] = o;
    }
}

// ---------------- Kernel: interleaved bf16 expert table ----------------
// wdu[e] = [ bf16(w_down[e]) (512) | bf16(w_up[e]) (512) ]  -> 2 KB per expert.
// One wave per expert iteration; lane ln handles elems ln*8..ln*8+7 of each row.
__global__ __launch_bounds__(256) void k_convi(const float* __restrict__ wd,
                                               const float* __restrict__ wu,
                                               unsigned short* __restrict__ wdu) {
    int gid = blockIdx.x * 256 + threadIdx.x;
    int wave = gid >> 6, ln = gid & 63;
    int nw = (gridDim.x * 256) >> 6;
    for (int e = wave; e < 65536; e += nw) {
        {
            const float* s = wd + (size_t)e * 512 + ln * 8;
            float4 a = *(const float4*)&s[0];
            float4 b = *(const float4*)&s[4];
            uint4 o;
            o.x = (unsigned)f2bf(a.x) | ((unsigned)f2bf(a.y) << 16);
            o.y = (unsigned)f2bf(a.z) | ((unsigned)f2bf(a.w) << 16);
            o.z = (unsigned)f2bf(b.x) | ((unsigned)f2bf(b.y) << 16);
            o.w = (unsigned)f2bf(b.z) | ((unsigned)f2bf(b.w) << 16);
            *(uint4*)&wdu[(size_t)e * 1024 + ln * 8] = o;
        }
        {
            const float* s = wu + (size_t)e * 512 + ln * 8;
            float4 a = *(const float4*)&s[0];
            float4 b = *(const float4*)&s[4];
            uint4 o;
            o.x = (unsigned)f2bf(a.x) | ((unsigned)f2bf(a.y) << 16);
            o.y = (unsigned)f2bf(a.z) | ((unsigned)f2bf(a.w) << 16);
            o.z = (unsigned)f2bf(b.x) | ((unsigned)f2bf(b.y) << 16);
            o.w = (unsigned)f2bf(b.z) | ((unsigned)f2bf(b.w) << 16);
            *(uint4*)&wdu[(size_t)e * 1024 + 512 + ln * 8] = o;
        }
    }
}

// ---------------- Kernel K2: fold keys into Wq, output bf16 ----------------
__global__ __launch_bounds__(256) void kK2(const float* __restrict__ keys,
                                           const float* __restrict__ Wq,
                                           unsigned short* __restrict__ K2b) {
    __shared__ float As[16][128];
    __shared__ float Bs[16][128];
    int t  = threadIdx.x;
    int tx = t & 15, ty = t >> 4;
    int p = blockIdx.z;
    int ktile = blockIdx.y & 1, ch = blockIdx.y >> 1;
    int h = ch & 7, c = ch >> 3;
    int m0 = ktile * 128;
    int n0 = blockIdx.x * 128;
    const float* kb = keys + ((size_t)(h * 256 + m0) * 2 + p) * 256;
    const float* wb = Wq + (size_t)(c * 2048 + h * 256) * 512;
    float acc[8][8] = {};
    for (int k0 = 0; k0 < 256; k0 += 16) {
#pragma unroll
        for (int i = 0; i < 2; ++i) {
            int u   = t * 2 + i;
            int row = u >> 2;
            int kc  = (u & 3) << 2;
            float4 av = *(const float4*)&kb[(size_t)row * 512 + k0 + kc];
            As[kc + 0][row] = av.x; As[kc + 1][row] = av.y; As[kc + 2][row] = av.z; As[kc + 3][row] = av.w;
            int v = u;
            int dkrow = v >> 5;
            int dcol  = (v & 31) << 2;
            float4 bv = *(const float4*)&wb[(size_t)(k0 + dkrow) * 512 + n0 + dcol];
            *(float4*)&Bs[dkrow][dcol] = bv;
        }
        __syncthreads();
#pragma unroll
        for (int kk = 0; kk < 16; ++kk) {
            float4 a0 = *(const float4*)&As[kk][ty * 8];
            float4 a1 = *(const float4*)&As[kk][ty * 8 + 4];
            float4 b0 = *(const float4*)&Bs[kk][tx * 4];
            float4 b1 = *(const float4*)&Bs[kk][tx * 4 + 64];
            float a[8] = {a0.x, a0.y, a0.z, a0.w, a1.x, a1.y, a1.z, a1.w};
            float b[8] = {b0.x, b0.y, b0.z, b0.w, b1.x, b1.y, b1.z, b1.w};
#pragma unroll
            for (int i = 0; i < 8; ++i)
#pragma unroll
                for (int j = 0; j < 8; ++j) acc[i][j] += a[i] * b[j];
        }
        __syncthreads();
    }
    unsigned short* Cp = K2b + (size_t)p * 4096 * 512;
#pragma unroll
    for (int i = 0; i < 8; ++i) {
        int r = c * 2048 + h * 256 + m0 + ty * 8 + i;
        uint2 o0, o1;
        o0.x = (unsigned)f2bf(acc[i][0]) | ((unsigned)f2bf(acc[i][1]) << 16);
        o0.y = (unsigned)f2bf(acc[i][2]) | ((unsigned)f2bf(acc[i][3]) << 16);
        o1.x = (unsigned)f2bf(acc[i][4]) | ((unsigned)f2bf(acc[i][5]) << 16);
        o1.y = (unsigned)f2bf(acc[i][6]) | ((unsigned)f2bf(acc[i][7]) << 16);
        *(uint2*)&Cp[(size_t)r * 512 + n0 + tx * 4]      = o0;
        *(uint2*)&Cp[(size_t)r * 512 + n0 + 64 + tx * 4] = o1;
    }
}

// ---------------- Kernel S (MFMA): S[p] = xb[p] @ K2b[p]^T ----------------
__global__ __launch_bounds__(256) void kS_mfma(const unsigned short* __restrict__ xb,
                                               const unsigned short* __restrict__ k2b,
                                               float* __restrict__ S) {
    int t = threadIdx.x;
    int wv = t >> 6, ln = t & 63;
    int p  = blockIdx.z;
    int n0 = blockIdx.y * 128 + wv * 32;
    int e0 = blockIdx.x * 64;
    const unsigned short* A = xb  + (size_t)p * 1024 * 512;
    const unsigned short* B = k2b + (size_t)p * 4096 * 512;
    int lr = ln & 15;
    int lk = (ln >> 4) * 8;

    f32x4 acc00 = {}, acc01 = {}, acc02 = {}, acc03 = {};
    f32x4 acc10 = {}, acc11 = {}, acc12 = {}, acc13 = {};

    for (int k0 = 0; k0 < 512; k0 += 32) {
        bf16x8 a0 = *(const bf16x8*)&A[(size_t)(n0 + lr) * 512 + k0 + lk];
        bf16x8 a1 = *(const bf16x8*)&A[(size_t)(n0 + 16 + lr) * 512 + k0 + lk];
        bf16x8 b0 = *(const bf16x8*)&B[(size_t)(e0 + lr) * 512 + k0 + lk];
        bf16x8 b1 = *(const bf16x8*)&B[(size_t)(e0 + 16 + lr) * 512 + k0 + lk];
        bf16x8 b2 = *(const bf16x8*)&B[(size_t)(e0 + 32 + lr) * 512 + k0 + lk];
        bf16x8 b3 = *(const bf16x8*)&B[(size_t)(e0 + 48 + lr) * 512 + k0 + lk];
        acc00 = __builtin_amdgcn_mfma_f32_16x16x32_bf16(a0, b0, acc00, 0, 0, 0);
        acc01 = __builtin_amdgcn_mfma_f32_16x16x32_bf16(a0, b1, acc01, 0, 0, 0);
        acc02 = __builtin_amdgcn_mfma_f32_16x16x32_bf16(a0, b2, acc02, 0, 0, 0);
        acc03 = __builtin_amdgcn_mfma_f32_16x16x32_bf16(a0, b3, acc03, 0, 0, 0);
        acc10 = __builtin_amdgcn_mfma_f32_16x16x32_bf16(a1, b0, acc10, 0, 0, 0);
        acc11 = __builtin_amdgcn_mfma_f32_16x16x32_bf16(a1, b1, acc11, 0, 0, 0);
        acc12 = __builtin_amdgcn_mfma_f32_16x16x32_bf16(a1, b2, acc12, 0, 0, 0);
        acc13 = __builtin_amdgcn_mfma_f32_16x16x32_bf16(a1, b3, acc13, 0, 0, 0);
    }

    // C/D layout (verified m89): col = lane&15, row = (lane>>4)*4 + reg
    float* C = S + (size_t)p * 1024 * 4096;
    int rbase = (ln >> 4) * 4;
    int cw = ln & 15;
#define STORE_FRAG(ACC, AF, BF)                                                   \
    {                                                                             \
        _Pragma("unroll")                                                         \
        for (int r = 0; r < 4; ++r)                                               \
            C[(size_t)(n0 + (AF)*16 + rbase + r) * 4096 + e0 + (BF)*16 + cw] = ACC[r]; \
    }
    STORE_FRAG(acc00, 0, 0); STORE_FRAG(acc01, 0, 1); STORE_FRAG(acc02, 0, 2); STORE_FRAG(acc03, 0, 3);
    STORE_FRAG(acc10, 1, 0); STORE_FRAG(acc11, 1, 1); STORE_FRAG(acc12, 1, 2); STORE_FRAG(acc13, 1, 3);
#undef STORE_FRAG
}

// ---------------- Kernel topk: radix top16 x2 + combine + top16 + softmax ----------------
__global__ __launch_bounds__(256) void k2_topk(const float* __restrict__ S,
                                               int* __restrict__ widx,
                                               float* __restrict__ wcoef) {
    __shared__ float sx_s[4][2][16];
    __shared__ int   ix_s[4][2][16];

    int t = threadIdx.x;
    int wv = t >> 6, ln = t & 63;
    int task = blockIdx.x * 4 + wv;
    int c = task >> 13;
    int n = (task >> 3) & 1023;
    int h = task & 7;
    unsigned long long lt = (1ull << ln) - 1ull;

    const float* s0p = S + (size_t)n * 4096 + c * 2048 + h * 256 + ln * 4;
    float4 s0 = *(const float4*)&s0p[0];
    float4 s1 = *(const float4*)&s0p[1024UL * 4096];

#define TK_HALF(PIDX, V)                                                          \
    {                                                                             \
        unsigned u0 = f2u(V.x), u1 = f2u(V.y), u2 = f2u(V.z), u3 = f2u(V.w);      \
        unsigned T; int kk;                                                       \
        radix16(u0, u1, u2, u3, T, kk);                                           \
        int base = 0;                                                             \
        { unsigned long long m = __ballot(u0 > T);                                \
          if (u0 > T) { int pos = base + __popcll(m & lt);                        \
              sx_s[wv][PIDX][pos] = V.x; ix_s[wv][PIDX][pos] = ln * 4 + 0; }      \
          base += __popcll(m); }                                                  \
        { unsigned long long m = __ballot(u1 > T);                                \
          if (u1 > T) { int pos = base + __popcll(m & lt);                        \
              sx_s[wv][PIDX][pos] = V.y; ix_s[wv][PIDX][pos] = ln * 4 + 1; }      \
          base += __popcll(m); }                                                  \
        { unsigned long long m = __ballot(u2 > T);                                \
          if (u2 > T) { int pos = base + __popcll(m & lt);                        \
              sx_s[wv][PIDX][pos] = V.z; ix_s[wv][PIDX][pos] = ln * 4 + 2; }      \
          base += __popcll(m); }                                                  \
        { unsigned long long m = __ballot(u3 > T);                                \
          if (u3 > T) { int pos = base + __popcll(m & lt);                        \
              sx_s[wv][PIDX][pos] = V.w; ix_s[wv][PIDX][pos] = ln * 4 + 3; }      \
          base += __popcll(m); }                                                  \
        { unsigned long long m = __ballot(u0 == T); int r = __popcll(m & lt);     \
          if ((u0 == T) && r < kk) { sx_s[wv][PIDX][base + r] = V.x;              \
              ix_s[wv][PIDX][base + r] = ln * 4 + 0; }                            \
          int cn2 = __popcll(m); int tk = cn2 < kk ? cn2 : kk; base += tk; kk -= tk; } \
        { unsigned long long m = __ballot(u1 == T); int r = __popcll(m & lt);     \
          if ((u1 == T) && r < kk) { sx_s[wv][PIDX][base + r] = V.y;              \
              ix_s[wv][PIDX][base + r] = ln * 4 + 1; }                            \
          int cn2 = __popcll(m); int tk = cn2 < kk ? cn2 : kk; base += tk; kk -= tk; } \
        { unsigned long long m = __ballot(u2 == T); int r = __popcll(m & lt);     \
          if ((u2 == T) && r < kk) { sx_s[wv][PIDX][base + r] = V.z;              \
              ix_s[wv][PIDX][base + r] = ln * 4 + 2; }                            \
          int cn2 = __popcll(m); int tk = cn2 < kk ? cn2 : kk; base += tk; kk -= tk; } \
        { unsigned long long m = __ballot(u3 == T); int r = __popcll(m & lt);     \
          if ((u3 == T) && r < kk) { sx_s[wv][PIDX][base + r] = V.w;              \
              ix_s[wv][PIDX][base + r] = ln * 4 + 3; }                            \
          int cn2 = __popcll(m); int tk = cn2 < kk ? cn2 : kk; base += tk; kk -= tk; } \
    }
    TK_HALF(0, s0);
    TK_HALF(1, s1);
#undef TK_HALF
    __syncthreads();

    int t0 = ln, t1 = ln + 64, t2 = ln + 128, t3 = ln + 192;
    float vc0 = sx_s[wv][0][t0 >> 4] + sx_s[wv][1][t0 & 15];
    float vc1 = sx_s[wv][0][t1 >> 4] + sx_s[wv][1][t1 & 15];
    float vc2 = sx_s[wv][0][t2 >> 4] + sx_s[wv][1][t2 & 15];
    float vc3 = sx_s[wv][0][t3 >> 4] + sx_s[wv][1][t3 & 15];
    unsigned u0 = f2u(vc0), u1 = f2u(vc1), u2 = f2u(vc2), u3 = f2u(vc3);
    unsigned T; int kk;
    radix16(u0, u1, u2, u3, T, kk);
    float Tf = u2f(T);

    bool w0 = u0 > T, w1 = u1 > T, w2 = u2 > T, w3 = u3 > T;
    int q0 = 0, q1 = 0, q2 = 0, q3 = 0;
    int base = 0;
    { unsigned long long m = __ballot(w0); q0 = base + __popcll(m & lt); base += __popcll(m); }
    { unsigned long long m = __ballot(w1); q1 = base + __popcll(m & lt); base += __popcll(m); }
    { unsigned long long m = __ballot(w2); q2 = base + __popcll(m & lt); base += __popcll(m); }
    { unsigned long long m = __ballot(w3); q3 = base + __popcll(m & lt); base += __popcll(m); }
#define CMB_EQ(UJ, WJ, QJ) { unsigned long long m = __ballot(UJ == T);          \
    int r = __popcll(m & lt);                                                   \
    if ((UJ == T) && r < kk) { WJ = true; QJ = base + r; }                      \
    int cn2 = __popcll(m); int tk = cn2 < kk ? cn2 : kk;                        \
    base += tk; kk -= tk; }
    CMB_EQ(u0, w0, q0); CMB_EQ(u1, w1, q1); CMB_EQ(u2, w2, q2); CMB_EQ(u3, w3, q3);
#undef CMB_EQ

    float e0 = 0.f, e1 = 0.f, e2 = 0.f, e3 = 0.f;
    int id0 = 0, id1 = 0, id2 = 0, id3 = 0;
    float es = 0.f;
    if (w0) { e0 = __expf(vc0 - Tf); es += e0; id0 = ix_s[wv][0][t0 >> 4] * 256 + ix_s[wv][1][t0 & 15]; }
    if (w1) { e1 = __expf(vc1 - Tf); es += e1; id1 = ix_s[wv][0][t1 >> 4] * 256 + ix_s[wv][1][t1 & 15]; }
    if (w2) { e2 = __expf(vc2 - Tf); es += e2; id2 = ix_s[wv][0][t2 >> 4] * 256 + ix_s[wv][1][t2 & 15]; }
    if (w3) { e3 = __expf(vc3 - Tf); es += e3; id3 = ix_s[wv][0][t3 >> 4] * 256 + ix_s[wv][1][t3 & 15]; }
    for (int s = 1; s < 64; s <<= 1) es += __shfl_xor(es, s);
    float inv = 1.f / es;

    int off = ((c * 1024 + n) * 8 + h) * 16;
    if (w0) { wcoef[off + q0] = e0 * inv; widx[off + q0] = id0; }
    if (w1) { wcoef[off + q1] = e1 * inv; widx[off + q1] = id1; }
    if (w2) { wcoef[off + q2] = e2 * inv; widx[off + q2] = id2; }
    if (w3) { wcoef[off + q3] = e3 * inv; widx[off + q3] = id3; }
}

// ---------------- Kernel 3 (interleaved bf16 table): gather, gelu, mix ----------------
__global__ __launch_bounds__(256) void k3_experts_bf16(const float* __restrict__ x,
                                                       const unsigned short* __restrict__ wdu,
                                                       const int* __restrict__ widx,
                                                       const float* __restrict__ wcoef,
                                                       float* __restrict__ out) {
    int bid = blockIdx.x;
    int c = bid >> 10, n = bid & 1023;
    int t = threadIdx.x, wv = t >> 6, ln = t & 63;
    __shared__ float wacc[4][512];

    const float* xrow = &x[(c * 1024 + n) * 512];
    float xr[8], oacc[8];
    {
        float4 xa = *(const float4*)&xrow[ln * 8];
        float4 xb = *(const float4*)&xrow[ln * 8 + 4];
        xr[0] = xa.x; xr[1] = xa.y; xr[2] = xa.z; xr[3] = xa.w;
        xr[4] = xb.x; xr[5] = xb.y; xr[6] = xb.z; xr[7] = xb.w;
    }
#pragma unroll
    for (int j = 0; j < 8; ++j) oacc[j] = 0.f;

    const int base = (c * 1024 + n) * 128;
    for (int e = wv * 32; e < wv * 32 + 32; ++e) {
        int   idx = widx[base + e];
        float wgt = wcoef[base + e];
        const unsigned short* row = wdu + (size_t)idx * 1024;
        // both halves of the 2 KB expert record issued back-to-back (same DRAM page)
        uint4 dv = *(const uint4*)&row[ln * 8];
        uint4 uv = *(const uint4*)&row[512 + ln * 8];
        float part = bflo(dv.x) * xr[0] + bfhi(dv.x) * xr[1]
                   + bflo(dv.y) * xr[2] + bfhi(dv.y) * xr[3]
                   + bflo(dv.z) * xr[4] + bfhi(dv.z) * xr[5]
                   + bflo(dv.w) * xr[6] + bfhi(dv.w) * xr[7];
        for (int s = 1; s < 64; s <<= 1) part += __shfl_xor(part, s);
        float hv = part;
        float coef = 0.5f * hv * (1.f + erff(hv * 0.70710678118654752f)) * wgt;
        oacc[0] += coef * bflo(uv.x); oacc[1] += coef * bfhi(uv.x);
        oacc[2] += coef * bflo(uv.y); oacc[3] += coef * bfhi(uv.y);
        oacc[4] += coef * bflo(uv.z); oacc[5] += coef * bfhi(uv.z);
        oacc[6] += coef * bflo(uv.w); oacc[7] += coef * bfhi(uv.w);
    }

#pragma unroll
    for (int j = 0; j < 8; ++j) wacc[wv][ln * 8 + j] = oacc[j];
    __syncthreads();

    float* orow = &out[(c * 1024 + n) * 512];
    for (int d = t; d < 512; d += 256)
        orow[d] = wacc[0][d] + wacc[1][d] + wacc[2][d] + wacc[3][d];
}

// ---------------- Kernel 3 (f32 fallback) ----------------
__global__ __launch_bounds__(256) void k3_experts_f32(const float* __restrict__ x,
                                                      const float* __restrict__ w_down,
                                                      const float* __restrict__ w_up,
                                                      const int* __restrict__ widx,
                                                      const float* __restrict__ wcoef,
                                                      float* __restrict__ out) {
    int bid = blockIdx.x;
    int c = bid >> 10, n = bid & 1023;
    int t = threadIdx.x, wv = t >> 6, ln = t & 63;
    __shared__ float wacc[4][512];

    const float* xrow = &x[(c * 1024 + n) * 512];
    float xr[8], oacc[8];
    {
        float4 xa = *(const float4*)&xrow[ln * 8];
        float4 xb = *(const float4*)&xrow[ln * 8 + 4];
        xr[0] = xa.x; xr[1] = xa.y; xr[2] = xa.z; xr[3] = xa.w;
        xr[4] = xb.x; xr[5] = xb.y; xr[6] = xb.z; xr[7] = xb.w;
    }
#pragma unroll
    for (int j = 0; j < 8; ++j) oacc[j] = 0.f;

    const int base = (c * 1024 + n) * 128;
    for (int e = wv * 32; e < wv * 32 + 32; ++e) {
        int   idx = widx[base + e];
        float wgt = wcoef[base + e];
        const float* dr = &w_down[(long)idx * 512 + ln * 8];
        float4 da = *(const float4*)&dr[0];
        float4 db = *(const float4*)&dr[4];
        float part = da.x * xr[0] + da.y * xr[1] + da.z * xr[2] + da.w * xr[3]
                   + db.x * xr[4] + db.y * xr[5] + db.z * xr[6] + db.w * xr[7];
        for (int s = 1; s < 64; s <<= 1) part += __shfl_xor(part, s);
        float hv = part;
        float coef = 0.5f * hv * (1.f + erff(hv * 0.70710678118654752f)) * wgt;
        const float* ur = &w_up[(long)idx * 512 + ln * 8];
        float4 ua = *(const float4*)&ur[0];
        float4 ub = *(const float4*)&ur[4];
        oacc[0] += coef * ua.x; oacc[1] += coef * ua.y; oacc[2] += coef * ua.z; oacc[3] += coef * ua.w;
        oacc[4] += coef * ub.x; oacc[5] += coef * ub.y; oacc[6] += coef * ub.z; oacc[7] += coef * ub.w;
    }
#pragma unroll
    for (int j = 0; j < 8; ++j) wacc[wv][ln * 8 + j] = oacc[j];
    __syncthreads();

    float* orow = &out[(c * 1024 + n) * 512];
    for (int d = t; d < 512; d += 256)
        orow[d] = wacc[0][d] + wacc[1][d] + wacc[2][d] + wacc[3][d];
}

extern "C" void kernel_launch(void* const* d_in, const int* in_sizes, int n_in,
                              void* d_out, int out_size, void* d_ws, size_t ws_size,
                              hipStream_t stream) {
    const float* x      = (const float*)d_in[0];
    const float* Wq     = (const float*)d_in[1];
    const float* keys   = (const float*)d_in[2];
    const float* w_down = (const float*)d_in[3];
    const float* w_up   = (const float*)d_in[4];
    float* out = (float*)d_out;

    char* ws = (char*)d_ws;
    size_t off = 0;
    float* S     = (float*)(ws + off); off += 2048UL * 4096 * 4;        // 32 MiB
    int*   widx  = (int*)(ws + off);   off += 262144UL * 4;             // 1 MiB
    float* wcoef = (float*)(ws + off); off += 262144UL * 4;             // 1 MiB
    unsigned short* K2b = (unsigned short*)(ws + off); off += 2UL * 4096 * 512 * 2; // 8 MiB
    unsigned short* xb  = (unsigned short*)(ws + off); off += 2048UL * 512 * 2;     // 2 MiB
    unsigned short* wdu = (unsigned short*)(ws + off); off += 65536UL * 1024 * 2;   // 128 MiB
    bool use_bf16 = (ws_size >= off);

    k_conv<<<512, 256, 0, stream>>>(x, xb, 2048 * 512 / 8);
    kK2<<<dim3(4, 32, 2), 256, 0, stream>>>(keys, Wq, K2b);
    kS_mfma<<<dim3(64, 8, 2), 256, 0, stream>>>(xb, K2b, S);
    k2_topk<<<4096, 256, 0, stream>>>(S, widx, wcoef);
    if (use_bf16) {
        k_convi<<<2048, 256, 0, stream>>>(w_down, w_up, wdu);
        k3_experts_bf16<<<2048, 256, 0, stream>>>(x, wdu, widx, wcoef, out);
    } else {
        k3_experts_f32<<<2048, 256, 0, stream>>>(x, w_down, w_up, widx, wcoef, out);
    }
}

// Round 20
// 293.248 us; speedup vs baseline: 1.4629x; 1.0017x over previous
//
#include <hip/hip_runtime.h>
#include <hip/hip_bf16.h>
#include <math.h>

typedef __attribute__((ext_vector_type(8))) short bf16x8;
typedef __attribute__((ext_vector_type(4))) float f32x4;

__device__ __forceinline__ unsigned f2u(float f) {
    unsigned b = __float_as_uint(f);
    return b ^ ((unsigned)((int)b >> 31) | 0x80000000u);
}
__device__ __forceinline__ float u2f(unsigned u) {
    unsigned b = (u & 0x80000000u) ? (u ^ 0x80000000u) : ~u;
    return __uint_as_float(b);
}
__device__ __forceinline__ unsigned short f2bf(float f) {   // round-to-nearest-even
    unsigned b = __float_as_uint(f);
    return (unsigned short)((b + 0x7FFFu + ((b >> 16) & 1u)) >> 16);
}
__device__ __forceinline__ float bflo(unsigned u) { return __uint_as_float(u << 16); }
__device__ __forceinline__ float bfhi(unsigned u) { return __uint_as_float(u & 0xFFFF0000u); }

// wave-level exact k=16 radix select over 256 values (4 per lane).
__device__ __forceinline__ void radix16(unsigned u0, unsigned u1, unsigned u2, unsigned u3,
                                        unsigned& T, int& kk) {
    unsigned prefix = 0; int k = 16;
    for (int b = 31; b >= 0; --b) {
        unsigned hi = (prefix >> b) | 1u;
        int cnt = __popcll(__ballot((u0 >> b) == hi))
                + __popcll(__ballot((u1 >> b) == hi))
                + __popcll(__ballot((u2 >> b) == hi))
                + __popcll(__ballot((u3 >> b) == hi));
        if (cnt >= k) prefix |= (1u << b); else k -= cnt;
    }
    T = prefix; kk = k;
}

// ---------------- Kernel: f32 -> bf16 conversion (streaming, for x) ----------------
__global__ __launch_bounds__(256) void k_conv(const float* __restrict__ src,
                                              unsigned short* __restrict__ dst, int n8) {
    int tid = blockIdx.x * 256 + threadIdx.x;
    int stride = gridDim.x * 256;
    for (int i = tid; i < n8; i += stride) {
        float4 a = *(const float4*)&src[(size_t)i * 8];
        float4 b = *(const float4*)&src[(size_t)i * 8 + 4];
        uint4 o;
        o.x = (unsigned)f2bf(a.x) | ((unsigned)f2bf(a.y) << 16);
        o.y = (unsigned)f2bf(a.z) | ((unsigned)f2bf(a.w) << 16);
        o.z = (unsigned)f2bf(b.x) | ((unsigned)f2bf(b.y) << 16);
        o.w = (unsigned)f2bf(b.z) | ((unsigned)f2bf(b.w) << 16);
        *(uint4*)&dst[(size_t)i * 8] = o;
    }
}

// ---------------- Kernel: interleaved bf16 expert table (dst-order streaming) ----------------
// wdu[e] = [ bf16(w_down[e]) (512) | bf16(w_up[e]) (512) ]  -> 2 KB per expert.
// Chunk i (8 floats) -> wdu[i*8 .. i*8+7] (perfectly linear writes);
// source: e = i>>7, sub = (i>>6)&1 selects wd/wu, d8 = i&63.
__global__ __launch_bounds__(256) void k_convi2(const float* __restrict__ wd,
                                                const float* __restrict__ wu,
                                                unsigned short* __restrict__ wdu) {
    const int N8 = 2 * 65536 * 512 / 8;   // 8388608 chunks
    int tid = blockIdx.x * 256 + threadIdx.x;
    int stride = gridDim.x * 256;
    for (int i = tid; i < N8; i += stride) {
        int e   = i >> 7;
        int sub = (i >> 6) & 1;
        int d8  = i & 63;
        const float* s = (sub ? wu : wd) + (size_t)e * 512 + d8 * 8;
        float4 a = *(const float4*)&s[0];
        float4 b = *(const float4*)&s[4];
        uint4 o;
        o.x = (unsigned)f2bf(a.x) | ((unsigned)f2bf(a.y) << 16);
        o.y = (unsigned)f2bf(a.z) | ((unsigned)f2bf(a.w) << 16);
        o.z = (unsigned)f2bf(b.x) | ((unsigned)f2bf(b.y) << 16);
        o.w = (unsigned)f2bf(b.z) | ((unsigned)f2bf(b.w) << 16);
        *(uint4*)&wdu[(size_t)i * 8] = o;
    }
}

// ---------------- Kernel K2: fold keys into Wq, output bf16 ----------------
__global__ __launch_bounds__(256) void kK2(const float* __restrict__ keys,
                                           const float* __restrict__ Wq,
                                           unsigned short* __restrict__ K2b) {
    __shared__ float As[16][128];
    __shared__ float Bs[16][128];
    int t  = threadIdx.x;
    int tx = t & 15, ty = t >> 4;
    int p = blockIdx.z;
    int ktile = blockIdx.y & 1, ch = blockIdx.y >> 1;
    int h = ch & 7, c = ch >> 3;
    int m0 = ktile * 128;
    int n0 = blockIdx.x * 128;
    const float* kb = keys + ((size_t)(h * 256 + m0) * 2 + p) * 256;
    const float* wb = Wq + (size_t)(c * 2048 + h * 256) * 512;
    float acc[8][8] = {};
    for (int k0 = 0; k0 < 256; k0 += 16) {
#pragma unroll
        for (int i = 0; i < 2; ++i) {
            int u   = t * 2 + i;
            int row = u >> 2;
            int kc  = (u & 3) << 2;
            float4 av = *(const float4*)&kb[(size_t)row * 512 + k0 + kc];
            As[kc + 0][row] = av.x; As[kc + 1][row] = av.y; As[kc + 2][row] = av.z; As[kc + 3][row] = av.w;
            int v = u;
            int dkrow = v >> 5;
            int dcol  = (v & 31) << 2;
            float4 bv = *(const float4*)&wb[(size_t)(k0 + dkrow) * 512 + n0 + dcol];
            *(float4*)&Bs[dkrow][dcol] = bv;
        }
        __syncthreads();
#pragma unroll
        for (int kk = 0; kk < 16; ++kk) {
            float4 a0 = *(const float4*)&As[kk][ty * 8];
            float4 a1 = *(const float4*)&As[kk][ty * 8 + 4];
            float4 b0 = *(const float4*)&Bs[kk][tx * 4];
            float4 b1 = *(const float4*)&Bs[kk][tx * 4 + 64];
            float a[8] = {a0.x, a0.y, a0.z, a0.w, a1.x, a1.y, a1.z, a1.w};
            float b[8] = {b0.x, b0.y, b0.z, b0.w, b1.x, b1.y, b1.z, b1.w};
#pragma unroll
            for (int i = 0; i < 8; ++i)
#pragma unroll
                for (int j = 0; j < 8; ++j) acc[i][j] += a[i] * b[j];
        }
        __syncthreads();
    }
    unsigned short* Cp = K2b + (size_t)p * 4096 * 512;
#pragma unroll
    for (int i = 0; i < 8; ++i) {
        int r = c * 2048 + h * 256 + m0 + ty * 8 + i;
        uint2 o0, o1;
        o0.x = (unsigned)f2bf(acc[i][0]) | ((unsigned)f2bf(acc[i][1]) << 16);
        o0.y = (unsigned)f2bf(acc[i][2]) | ((unsigned)f2bf(acc[i][3]) << 16);
        o1.x = (unsigned)f2bf(acc[i][4]) | ((unsigned)f2bf(acc[i][5]) << 16);
        o1.y = (unsigned)f2bf(acc[i][6]) | ((unsigned)f2bf(acc[i][7]) << 16);
        *(uint2*)&Cp[(size_t)r * 512 + n0 + tx * 4]      = o0;
        *(uint2*)&Cp[(size_t)r * 512 + n0 + 64 + tx * 4] = o1;
    }
}

// ---------------- Kernel S (MFMA): S[p] = xb[p] @ K2b[p]^T ----------------
__global__ __launch_bounds__(256) void kS_mfma(const unsigned short* __restrict__ xb,
                                               const unsigned short* __restrict__ k2b,
                                               float* __restrict__ S) {
    int t = threadIdx.x;
    int wv = t >> 6, ln = t & 63;
    int p  = blockIdx.z;
    int n0 = blockIdx.y * 128 + wv * 32;
    int e0 = blockIdx.x * 64;
    const unsigned short* A = xb  + (size_t)p * 1024 * 512;
    const unsigned short* B = k2b + (size_t)p * 4096 * 512;
    int lr = ln & 15;
    int lk = (ln >> 4) * 8;

    f32x4 acc00 = {}, acc01 = {}, acc02 = {}, acc03 = {};
    f32x4 acc10 = {}, acc11 = {}, acc12 = {}, acc13 = {};

    for (int k0 = 0; k0 < 512; k0 += 32) {
        bf16x8 a0 = *(const bf16x8*)&A[(size_t)(n0 + lr) * 512 + k0 + lk];
        bf16x8 a1 = *(const bf16x8*)&A[(size_t)(n0 + 16 + lr) * 512 + k0 + lk];
        bf16x8 b0 = *(const bf16x8*)&B[(size_t)(e0 + lr) * 512 + k0 + lk];
        bf16x8 b1 = *(const bf16x8*)&B[(size_t)(e0 + 16 + lr) * 512 + k0 + lk];
        bf16x8 b2 = *(const bf16x8*)&B[(size_t)(e0 + 32 + lr) * 512 + k0 + lk];
        bf16x8 b3 = *(const bf16x8*)&B[(size_t)(e0 + 48 + lr) * 512 + k0 + lk];
        acc00 = __builtin_amdgcn_mfma_f32_16x16x32_bf16(a0, b0, acc00, 0, 0, 0);
        acc01 = __builtin_amdgcn_mfma_f32_16x16x32_bf16(a0, b1, acc01, 0, 0, 0);
        acc02 = __builtin_amdgcn_mfma_f32_16x16x32_bf16(a0, b2, acc02, 0, 0, 0);
        acc03 = __builtin_amdgcn_mfma_f32_16x16x32_bf16(a0, b3, acc03, 0, 0, 0);
        acc10 = __builtin_amdgcn_mfma_f32_16x16x32_bf16(a1, b0, acc10, 0, 0, 0);
        acc11 = __builtin_amdgcn_mfma_f32_16x16x32_bf16(a1, b1, acc11, 0, 0, 0);
        acc12 = __builtin_amdgcn_mfma_f32_16x16x32_bf16(a1, b2, acc12, 0, 0, 0);
        acc13 = __builtin_amdgcn_mfma_f32_16x16x32_bf16(a1, b3, acc13, 0, 0, 0);
    }

    // C/D layout (verified m89): col = lane&15, row = (lane>>4)*4 + reg
    float* C = S + (size_t)p * 1024 * 4096;
    int rbase = (ln >> 4) * 4;
    int cw = ln & 15;
#define STORE_FRAG(ACC, AF, BF)                                                   \
    {                                                                             \
        _Pragma("unroll")                                                         \
        for (int r = 0; r < 4; ++r)                                               \
            C[(size_t)(n0 + (AF)*16 + rbase + r) * 4096 + e0 + (BF)*16 + cw] = ACC[r]; \
    }
    STORE_FRAG(acc00, 0, 0); STORE_FRAG(acc01, 0, 1); STORE_FRAG(acc02, 0, 2); STORE_FRAG(acc03, 0, 3);
    STORE_FRAG(acc10, 1, 0); STORE_FRAG(acc11, 1, 1); STORE_FRAG(acc12, 1, 2); STORE_FRAG(acc13, 1, 3);
#undef STORE_FRAG
}

// ---------------- Kernel topk: radix top16 x2 + combine + top16 + softmax ----------------
__global__ __launch_bounds__(256) void k2_topk(const float* __restrict__ S,
                                               int* __restrict__ widx,
                                               float* __restrict__ wcoef) {
    __shared__ float sx_s[4][2][16];
    __shared__ int   ix_s[4][2][16];

    int t = threadIdx.x;
    int wv = t >> 6, ln = t & 63;
    int task = blockIdx.x * 4 + wv;
    int c = task >> 13;
    int n = (task >> 3) & 1023;
    int h = task & 7;
    unsigned long long lt = (1ull << ln) - 1ull;

    const float* s0p = S + (size_t)n * 4096 + c * 2048 + h * 256 + ln * 4;
    float4 s0 = *(const float4*)&s0p[0];
    float4 s1 = *(const float4*)&s0p[1024UL * 4096];

#define TK_HALF(PIDX, V)                                                          \
    {                                                                             \
        unsigned u0 = f2u(V.x), u1 = f2u(V.y), u2 = f2u(V.z), u3 = f2u(V.w);      \
        unsigned T; int kk;                                                       \
        radix16(u0, u1, u2, u3, T, kk);                                           \
        int base = 0;                                                             \
        { unsigned long long m = __ballot(u0 > T);                                \
          if (u0 > T) { int pos = base + __popcll(m & lt);                        \
              sx_s[wv][PIDX][pos] = V.x; ix_s[wv][PIDX][pos] = ln * 4 + 0; }      \
          base += __popcll(m); }                                                  \
        { unsigned long long m = __ballot(u1 > T);                                \
          if (u1 > T) { int pos = base + __popcll(m & lt);                        \
              sx_s[wv][PIDX][pos] = V.y; ix_s[wv][PIDX][pos] = ln * 4 + 1; }      \
          base += __popcll(m); }                                                  \
        { unsigned long long m = __ballot(u2 > T);                                \
          if (u2 > T) { int pos = base + __popcll(m & lt);                        \
              sx_s[wv][PIDX][pos] = V.z; ix_s[wv][PIDX][pos] = ln * 4 + 2; }      \
          base += __popcll(m); }                                                  \
        { unsigned long long m = __ballot(u3 > T);                                \
          if (u3 > T) { int pos = base + __popcll(m & lt);                        \
              sx_s[wv][PIDX][pos] = V.w; ix_s[wv][PIDX][pos] = ln * 4 + 3; }      \
          base += __popcll(m); }                                                  \
        { unsigned long long m = __ballot(u0 == T); int r = __popcll(m & lt);     \
          if ((u0 == T) && r < kk) { sx_s[wv][PIDX][base + r] = V.x;              \
              ix_s[wv][PIDX][base + r] = ln * 4 + 0; }                            \
          int cn2 = __popcll(m); int tk = cn2 < kk ? cn2 : kk; base += tk; kk -= tk; } \
        { unsigned long long m = __ballot(u1 == T); int r = __popcll(m & lt);     \
          if ((u1 == T) && r < kk) { sx_s[wv][PIDX][base + r] = V.y;              \
              ix_s[wv][PIDX][base + r] = ln * 4 + 1; }                            \
          int cn2 = __popcll(m); int tk = cn2 < kk ? cn2 : kk; base += tk; kk -= tk; } \
        { unsigned long long m = __ballot(u2 == T); int r = __popcll(m & lt);     \
          if ((u2 == T) && r < kk) { sx_s[wv][PIDX][base + r] = V.z;              \
              ix_s[wv][PIDX][base + r] = ln * 4 + 2; }                            \
          int cn2 = __popcll(m); int tk = cn2 < kk ? cn2 : kk; base += tk; kk -= tk; } \
        { unsigned long long m = __ballot(u3 == T); int r = __popcll(m & lt);     \
          if ((u3 == T) && r < kk) { sx_s[wv][PIDX][base + r] = V.w;              \
              ix_s[wv][PIDX][base + r] = ln * 4 + 3; }                            \
          int cn2 = __popcll(m); int tk = cn2 < kk ? cn2 : kk; base += tk; kk -= tk; } \
    }
    TK_HALF(0, s0);
    TK_HALF(1, s1);
#undef TK_HALF
    __syncthreads();

    int t0 = ln, t1 = ln + 64, t2 = ln + 128, t3 = ln + 192;
    float vc0 = sx_s[wv][0][t0 >> 4] + sx_s[wv][1][t0 & 15];
    float vc1 = sx_s[wv][0][t1 >> 4] + sx_s[wv][1][t1 & 15];
    float vc2 = sx_s[wv][0][t2 >> 4] + sx_s[wv][1][t2 & 15];
    float vc3 = sx_s[wv][0][t3 >> 4] + sx_s[wv][1][t3 & 15];
    unsigned u0 = f2u(vc0), u1 = f2u(vc1), u2 = f2u(vc2), u3 = f2u(vc3);
    unsigned T; int kk;
    radix16(u0, u1, u2, u3, T, kk);
    float Tf = u2f(T);

    bool w0 = u0 > T, w1 = u1 > T, w2 = u2 > T, w3 = u3 > T;
    int q0 = 0, q1 = 0, q2 = 0, q3 = 0;
    int base = 0;
    { unsigned long long m = __ballot(w0); q0 = base + __popcll(m & lt); base += __popcll(m); }
    { unsigned long long m = __ballot(w1); q1 = base + __popcll(m & lt); base += __popcll(m); }
    { unsigned long long m = __ballot(w2); q2 = base + __popcll(m & lt); base += __popcll(m); }
    { unsigned long long m = __ballot(w3); q3 = base + __popcll(m & lt); base += __popcll(m); }
#define CMB_EQ(UJ, WJ, QJ) { unsigned long long m = __ballot(UJ == T);          \
    int r = __popcll(m & lt);                                                   \
    if ((UJ == T) && r < kk) { WJ = true; QJ = base + r; }                      \
    int cn2 = __popcll(m); int tk = cn2 < kk ? cn2 : kk;                        \
    base += tk; kk -= tk; }
    CMB_EQ(u0, w0, q0); CMB_EQ(u1, w1, q1); CMB_EQ(u2, w2, q2); CMB_EQ(u3, w3, q3);
#undef CMB_EQ

    float e0 = 0.f, e1 = 0.f, e2 = 0.f, e3 = 0.f;
    int id0 = 0, id1 = 0, id2 = 0, id3 = 0;
    float es = 0.f;
    if (w0) { e0 = __expf(vc0 - Tf); es += e0; id0 = ix_s[wv][0][t0 >> 4] * 256 + ix_s[wv][1][t0 & 15]; }
    if (w1) { e1 = __expf(vc1 - Tf); es += e1; id1 = ix_s[wv][0][t1 >> 4] * 256 + ix_s[wv][1][t1 & 15]; }
    if (w2) { e2 = __expf(vc2 - Tf); es += e2; id2 = ix_s[wv][0][t2 >> 4] * 256 + ix_s[wv][1][t2 & 15]; }
    if (w3) { e3 = __expf(vc3 - Tf); es += e3; id3 = ix_s[wv][0][t3 >> 4] * 256 + ix_s[wv][1][t3 & 15]; }
    for (int s = 1; s < 64; s <<= 1) es += __shfl_xor(es, s);
    float inv = 1.f / es;

    int off = ((c * 1024 + n) * 8 + h) * 16;
    if (w0) { wcoef[off + q0] = e0 * inv; widx[off + q0] = id0; }
    if (w1) { wcoef[off + q1] = e1 * inv; widx[off + q1] = id1; }
    if (w2) { wcoef[off + q2] = e2 * inv; widx[off + q2] = id2; }
    if (w3) { wcoef[off + q3] = e3 * inv; widx[off + q3] = id3; }
}

// ---------------- Kernel 3 (interleaved bf16 table): gather, gelu, mix ----------------
__global__ __launch_bounds__(256) void k3_experts_bf16(const float* __restrict__ x,
                                                       const unsigned short* __restrict__ wdu,
                                                       const int* __restrict__ widx,
                                                       const float* __restrict__ wcoef,
                                                       float* __restrict__ out) {
    int bid = blockIdx.x;
    int c = bid >> 10, n = bid & 1023;
    int t = threadIdx.x, wv = t >> 6, ln = t & 63;
    __shared__ float wacc[4][512];

    const float* xrow = &x[(c * 1024 + n) * 512];
    float xr[8], oacc[8];
    {
        float4 xa = *(const float4*)&xrow[ln * 8];
        float4 xb = *(const float4*)&xrow[ln * 8 + 4];
        xr[0] = xa.x; xr[1] = xa.y; xr[2] = xa.z; xr[3] = xa.w;
        xr[4] = xb.x; xr[5] = xb.y; xr[6] = xb.z; xr[7] = xb.w;
    }
#pragma unroll
    for (int j = 0; j < 8; ++j) oacc[j] = 0.f;

    const int base = (c * 1024 + n) * 128;
    for (int e = wv * 32; e < wv * 32 + 32; ++e) {
        int   idx = widx[base + e];
        float wgt = wcoef[base + e];
        const unsigned short* row = wdu + (size_t)idx * 1024;
        uint4 dv = *(const uint4*)&row[ln * 8];
        uint4 uv = *(const uint4*)&row[512 + ln * 8];
        float part = bflo(dv.x) * xr[0] + bfhi(dv.x) * xr[1]
                   + bflo(dv.y) * xr[2] + bfhi(dv.y) * xr[3]
                   + bflo(dv.z) * xr[4] + bfhi(dv.z) * xr[5]
                   + bflo(dv.w) * xr[6] + bfhi(dv.w) * xr[7];
        for (int s = 1; s < 64; s <<= 1) part += __shfl_xor(part, s);
        float hv = part;
        float coef = 0.5f * hv * (1.f + erff(hv * 0.70710678118654752f)) * wgt;
        oacc[0] += coef * bflo(uv.x); oacc[1] += coef * bfhi(uv.x);
        oacc[2] += coef * bflo(uv.y); oacc[3] += coef * bfhi(uv.y);
        oacc[4] += coef * bflo(uv.z); oacc[5] += coef * bfhi(uv.z);
        oacc[6] += coef * bflo(uv.w); oacc[7] += coef * bfhi(uv.w);
    }

#pragma unroll
    for (int j = 0; j < 8; ++j) wacc[wv][ln * 8 + j] = oacc[j];
    __syncthreads();

    float* orow = &out[(c * 1024 + n) * 512];
    for (int d = t; d < 512; d += 256)
        orow[d] = wacc[0][d] + wacc[1][d] + wacc[2][d] + wacc[3][d];
}

// ---------------- Kernel 3 (f32 fallback) ----------------
__global__ __launch_bounds__(256) void k3_experts_f32(const float* __restrict__ x,
                                                      const float* __restrict__ w_down,
                                                      const float* __restrict__ w_up,
                                                      const int* __restrict__ widx,
                                                      const float* __restrict__ wcoef,
                                                      float* __restrict__ out) {
    int bid = blockIdx.x;
    int c = bid >> 10, n = bid & 1023;
    int t = threadIdx.x, wv = t >> 6, ln = t & 63;
    __shared__ float wacc[4][512];

    const float* xrow = &x[(c * 1024 + n) * 512];
    float xr[8], oacc[8];
    {
        float4 xa = *(const float4*)&xrow[ln * 8];
        float4 xb = *(const float4*)&xrow[ln * 8 + 4];
        xr[0] = xa.x; xr[1] = xa.y; xr[2] = xa.z; xr[3] = xa.w;
        xr[4] = xb.x; xr[5] = xb.y; xr[6] = xb.z; xr[7] = xb.w;
    }
#pragma unroll
    for (int j = 0; j < 8; ++j) oacc[j] = 0.f;

    const int base = (c * 1024 + n) * 128;
    for (int e = wv * 32; e < wv * 32 + 32; ++e) {
        int   idx = widx[base + e];
        float wgt = wcoef[base + e];
        const float* dr = &w_down[(long)idx * 512 + ln * 8];
        float4 da = *(const float4*)&dr[0];
        float4 db = *(const float4*)&dr[4];
        float part = da.x * xr[0] + da.y * xr[1] + da.z * xr[2] + da.w * xr[3]
                   + db.x * xr[4] + db.y * xr[5] + db.z * xr[6] + db.w * xr[7];
        for (int s = 1; s < 64; s <<= 1) part += __shfl_xor(part, s);
        float hv = part;
        float coef = 0.5f * hv * (1.f + erff(hv * 0.70710678118654752f)) * wgt;
        const float* ur = &w_up[(long)idx * 512 + ln * 8];
        float4 ua = *(const float4*)&ur[0];
        float4 ub = *(const float4*)&ur[4];
        oacc[0] += coef * ua.x; oacc[1] += coef * ua.y; oacc[2] += coef * ua.z; oacc[3] += coef * ua.w;
        oacc[4] += coef * ub.x; oacc[5] += coef * ub.y; oacc[6] += coef * ub.z; oacc[7] += coef * ub.w;
    }
#pragma unroll
    for (int j = 0; j < 8; ++j) wacc[wv][ln * 8 + j] = oacc[j];
    __syncthreads();

    float* orow = &out[(c * 1024 + n) * 512];
    for (int d = t; d < 512; d += 256)
        orow[d] = wacc[0][d] + wacc[1][d] + wacc[2][d] + wacc[3][d];
}

extern "C" void kernel_launch(void* const* d_in, const int* in_sizes, int n_in,
                              void* d_out, int out_size, void* d_ws, size_t ws_size,
                              hipStream_t stream) {
    const float* x      = (const float*)d_in[0];
    const float* Wq     = (const float*)d_in[1];
    const float* keys   = (const float*)d_in[2];
    const float* w_down = (const float*)d_in[3];
    const float* w_up   = (const float*)d_in[4];
    float* out = (float*)d_out;

    char* ws = (char*)d_ws;
    size_t off = 0;
    float* S     = (float*)(ws + off); off += 2048UL * 4096 * 4;        // 32 MiB
    int*   widx  = (int*)(ws + off);   off += 262144UL * 4;             // 1 MiB
    float* wcoef = (float*)(ws + off); off += 262144UL * 4;             // 1 MiB
    unsigned short* K2b = (unsigned short*)(ws + off); off += 2UL * 4096 * 512 * 2; // 8 MiB
    unsigned short* xb  = (unsigned short*)(ws + off); off += 2048UL * 512 * 2;     // 2 MiB
    unsigned short* wdu = (unsigned short*)(ws + off); off += 65536UL * 1024 * 2;   // 128 MiB
    bool use_bf16 = (ws_size >= off);

    k_conv<<<512, 256, 0, stream>>>(x, xb, 2048 * 512 / 8);
    kK2<<<dim3(4, 32, 2), 256, 0, stream>>>(keys, Wq, K2b);
    kS_mfma<<<dim3(64, 8, 2), 256, 0, stream>>>(xb, K2b, S);
    k2_topk<<<4096, 256, 0, stream>>>(S, widx, wcoef);
    if (use_bf16) {
        k_convi2<<<4096, 256, 0, stream>>>(w_down, w_up, wdu);
        k3_experts_bf16<<<2048, 256, 0, stream>>>(x, wdu, widx, wcoef, out);
    } else {
        k3_experts_f32<<<2048, 256, 0, stream>>>(x, w_down, w_up, widx, wcoef, out);
    }
}